// Round 13
// baseline (372.365 us; speedup 1.0000x reference)
//
#include <hip/hip_runtime.h>
#include <hip/hip_bf16.h>
#include <cstddef>

#define Bb 8
#define Tt 512
#define NM 128
#define DM 512
#define DI 1024
#define DS 32
#define DR 32
#define DC 4
#define NC 100
#define BT (Bb*Tt)     // 4096
#define NCH 8          // scan chunks
#define CL  64         // chunk length

typedef unsigned short ushort_t;
typedef unsigned int uint_t;
typedef __attribute__((ext_vector_type(8))) short bf8;    // 8 bf16 in 4 VGPRs
typedef __attribute__((ext_vector_type(4))) float f4;
typedef __attribute__((ext_vector_type(4))) unsigned short us4;

__device__ __forceinline__ float softplus_f(float x) {
    return fmaxf(x, 0.f) + log1pf(expf(-fabsf(x)));
}
__device__ __forceinline__ float silu_fast(float x) {
    return __fdividef(x, 1.f + __expf(-x));
}
__device__ __forceinline__ ushort_t bf16_rne(float x) {
    uint_t u = __float_as_uint(x);
    uint_t r = u + 0x7FFFu + ((u >> 16) & 1u);
    return (ushort_t)(r >> 16);
}
__device__ __forceinline__ float bf16_tof(ushort_t h) {
    return __uint_as_float(((uint_t)h) << 16);
}
// pack fp32 -> {hi bf16 in [31:16], lo bf16 in [15:0]}
__device__ __forceinline__ uint_t packf(float v) {
    ushort_t h = bf16_rne(v);
    ushort_t l = bf16_rne(v - bf16_tof(h));
    return ((uint_t)h << 16) | (uint_t)l;
}
// cross-lane: quad_perm DPP (VALU pipe) and ds_swizzle (DS pipe)
template<int CTRL>
__device__ __forceinline__ float qperm(float x) {
    return __int_as_float(__builtin_amdgcn_mov_dpp(__float_as_int(x), CTRL, 0xF, 0xF, true));
}
template<int PAT>
__device__ __forceinline__ float swz(float x) {
    return __int_as_float(__builtin_amdgcn_ds_swizzle(__float_as_int(x), PAT));
}

// ---- split fp32 (K,N) row-major into bf16 hi/lo, TRANSPOSED to (N,K) --------
// Optionally zeroes zcount float4s at zbase (fused init, saves a launch).
__global__ __launch_bounds__(256) void split_tr_kernel(
    const float* __restrict__ src, ushort_t* __restrict__ hi,
    ushort_t* __restrict__ lo, int K, int N,
    float4* __restrict__ zbase, int zcount)
{
    __shared__ ushort_t th[32][34], tl[32][34];
    const int k0 = blockIdx.y * 32, n0 = blockIdx.x * 32;
    if (zbase) {
        const int zi = (blockIdx.y * gridDim.x + blockIdx.x) * 256 + threadIdx.x;
        if (zi < zcount) zbase[zi] = make_float4(0.f, 0.f, 0.f, 0.f);
    }
    #pragma unroll
    for (int it = 0; it < 4; ++it) {
        const int idx = it * 256 + threadIdx.x;
        const int r = idx >> 5, c = idx & 31;
        const float v = src[(size_t)(k0 + r) * N + n0 + c];
        const ushort_t h = bf16_rne(v);
        th[c][r] = h;
        tl[c][r] = bf16_rne(v - bf16_tof(h));
    }
    __syncthreads();
    #pragma unroll
    for (int it = 0; it < 4; ++it) {
        const int idx = it * 256 + threadIdx.x;
        const int r = idx >> 5, c = idx & 31;
        hi[(size_t)(n0 + r) * K + k0 + c] = th[r][c];
        lo[(size_t)(n0 + r) * K + k0 + c] = tl[r][c];
    }
}

// ---- split-bf16 MFMA GEMM, 512 thr / 8 waves, 128x128 tile, C write ---------
__global__ __launch_bounds__(512) void gemm_mfma_big(
    const uint_t* __restrict__ Apk, int lda,
    const ushort_t* __restrict__ Bhi, const ushort_t* __restrict__ Blo,
    float* __restrict__ C, int N, int K)
{
    constexpr int BM = 128, BN = 128;
    constexpr int FM = 2, FN = 4;         // wave tile 32x64
    __shared__ ushort_t sA[2][BM][40];
    __shared__ ushort_t sB[2][BN][40];
    const int tid = threadIdx.x;
    const int wid = tid >> 6, l = tid & 63, l15 = l & 15, g = l >> 4;
    const int wm = (wid >> 1) * 32, wn = (wid & 1) * 64;
    const int bm0 = blockIdx.y * BM, bn0 = blockIdx.x * BN;

    f4 acc[FM][FN] = {};
    uint4 aR[2], bRh, bRl;

    auto loadG = [&](int k0) {
        #pragma unroll
        for (int r = 0; r < 2; ++r) {
            const int idx = r * 2048 + tid * 4;
            const int m = idx >> 5, k = idx & 31;
            aR[r] = *(const uint4*)(Apk + (size_t)(bm0 + m) * lda + k0 + k);
        }
        {
            const int idx = tid * 8;
            const int n = idx >> 5, k = idx & 31;
            const size_t o = (size_t)(bn0 + n) * K + k0 + k;
            bRh = *(const uint4*)(Bhi + o);
            bRl = *(const uint4*)(Blo + o);
        }
    };
    auto stoL = [&]() {
        #pragma unroll
        for (int r = 0; r < 2; ++r) {
            const int idx = r * 2048 + tid * 4;
            const int m = idx >> 5, k = idx & 31;
            const uint_t u0 = aR[r].x, u1 = aR[r].y, u2 = aR[r].z, u3 = aR[r].w;
            uint2 hh, ll;
            hh.x = (u0 >> 16) | (u1 & 0xFFFF0000u);
            hh.y = (u2 >> 16) | (u3 & 0xFFFF0000u);
            ll.x = (u0 & 0xFFFFu) | (u1 << 16);
            ll.y = (u2 & 0xFFFFu) | (u3 << 16);
            *(uint2*)&sA[0][m][k] = hh;
            *(uint2*)&sA[1][m][k] = ll;
        }
        {
            const int idx = tid * 8;
            const int n = idx >> 5, k = idx & 31;
            *(uint4*)&sB[0][n][k] = bRh;
            *(uint4*)&sB[1][n][k] = bRl;
        }
    };

    loadG(0);
    for (int k0 = 0; k0 < K; k0 += 32) {
        stoL();
        __syncthreads();
        if (k0 + 32 < K) loadG(k0 + 32);
        bf8 ah[FM], al_[FM], bh[FN], bl_[FN];
        #pragma unroll
        for (int i = 0; i < FM; ++i) {
            ah[i]  = *(bf8*)&sA[0][wm + i * 16 + l15][g * 8];
            al_[i] = *(bf8*)&sA[1][wm + i * 16 + l15][g * 8];
        }
        #pragma unroll
        for (int j = 0; j < FN; ++j) {
            bh[j]  = *(bf8*)&sB[0][wn + j * 16 + l15][g * 8];
            bl_[j] = *(bf8*)&sB[1][wn + j * 16 + l15][g * 8];
        }
        #pragma unroll
        for (int i = 0; i < FM; ++i)
            #pragma unroll
            for (int j = 0; j < FN; ++j)
                acc[i][j] = __builtin_amdgcn_mfma_f32_16x16x32_bf16(ah[i], bh[j], acc[i][j], 0, 0, 0);
        #pragma unroll
        for (int i = 0; i < FM; ++i)
            #pragma unroll
            for (int j = 0; j < FN; ++j)
                acc[i][j] = __builtin_amdgcn_mfma_f32_16x16x32_bf16(al_[i], bh[j], acc[i][j], 0, 0, 0);
        #pragma unroll
        for (int i = 0; i < FM; ++i)
            #pragma unroll
            for (int j = 0; j < FN; ++j)
                acc[i][j] = __builtin_amdgcn_mfma_f32_16x16x32_bf16(ah[i], bl_[j], acc[i][j], 0, 0, 0);
        __syncthreads();
    }
    #pragma unroll
    for (int i = 0; i < FM; ++i)
        #pragma unroll
        for (int j = 0; j < FN; ++j)
            #pragma unroll
            for (int r = 0; r < 4; ++r) {
                const int m = bm0 + wm + i * 16 + g * 4 + r;
                const int n = bn0 + wn + j * 16 + l15;
                C[(size_t)m * N + n] = acc[i][j][r];
            }
}

// ---- split-bf16 MFMA GEMM, 64x64 tile, split-K, fused mean-pool -------------
__global__ __launch_bounds__(256) void gemm_mfma_pool(
    const uint_t* __restrict__ Apk, int lda,
    const ushort_t* __restrict__ Bhi, const ushort_t* __restrict__ Blo,
    float* __restrict__ pooled, float pscale,
    int N, int K, int kseg)
{
    constexpr int BM = 64, BN = 64;
    constexpr int FM = 2, FN = 2;
    __shared__ ushort_t sA[2][BM][40];
    __shared__ ushort_t sB[2][BN][40];
    const int tid = threadIdx.x;
    const int wid = tid >> 6, l = tid & 63, l15 = l & 15, g = l >> 4;
    const int wm = (wid >> 1) * 32, wn = (wid & 1) * 32;
    const int bm0 = blockIdx.y * BM, bn0 = blockIdx.x * BN;
    const int kbeg = blockIdx.z * kseg;

    f4 acc[FM][FN] = {};
    uint4 aR[2], bRh, bRl;

    auto loadG = [&](int k0) {
        #pragma unroll
        for (int r = 0; r < 2; ++r) {
            const int idx = r * 1024 + tid * 4;
            const int m = idx >> 5, k = idx & 31;
            aR[r] = *(const uint4*)(Apk + (size_t)(bm0 + m) * lda + k0 + k);
        }
        {
            const int idx = tid * 8;
            const int n = idx >> 5, k = idx & 31;
            const size_t o = (size_t)(bn0 + n) * K + k0 + k;
            bRh = *(const uint4*)(Bhi + o);
            bRl = *(const uint4*)(Blo + o);
        }
    };
    auto stoL = [&]() {
        #pragma unroll
        for (int r = 0; r < 2; ++r) {
            const int idx = r * 1024 + tid * 4;
            const int m = idx >> 5, k = idx & 31;
            const uint_t u0 = aR[r].x, u1 = aR[r].y, u2 = aR[r].z, u3 = aR[r].w;
            uint2 hh, ll;
            hh.x = (u0 >> 16) | (u1 & 0xFFFF0000u);
            hh.y = (u2 >> 16) | (u3 & 0xFFFF0000u);
            ll.x = (u0 & 0xFFFFu) | (u1 << 16);
            ll.y = (u2 & 0xFFFFu) | (u3 << 16);
            *(uint2*)&sA[0][m][k] = hh;
            *(uint2*)&sA[1][m][k] = ll;
        }
        {
            const int idx = tid * 8;
            const int n = idx >> 5, k = idx & 31;
            *(uint4*)&sB[0][n][k] = bRh;
            *(uint4*)&sB[1][n][k] = bRl;
        }
    };

    loadG(kbeg);
    for (int k0 = kbeg; k0 < kbeg + kseg; k0 += 32) {
        stoL();
        __syncthreads();
        if (k0 + 32 < kbeg + kseg) loadG(k0 + 32);
        bf8 ah[FM], al_[FM], bh[FN], bl_[FN];
        #pragma unroll
        for (int i = 0; i < FM; ++i) {
            ah[i]  = *(bf8*)&sA[0][wm + i * 16 + l15][g * 8];
            al_[i] = *(bf8*)&sA[1][wm + i * 16 + l15][g * 8];
        }
        #pragma unroll
        for (int j = 0; j < FN; ++j) {
            bh[j]  = *(bf8*)&sB[0][wn + j * 16 + l15][g * 8];
            bl_[j] = *(bf8*)&sB[1][wn + j * 16 + l15][g * 8];
        }
        #pragma unroll
        for (int i = 0; i < FM; ++i)
            #pragma unroll
            for (int j = 0; j < FN; ++j)
                acc[i][j] = __builtin_amdgcn_mfma_f32_16x16x32_bf16(ah[i], bh[j], acc[i][j], 0, 0, 0);
        #pragma unroll
        for (int i = 0; i < FM; ++i)
            #pragma unroll
            for (int j = 0; j < FN; ++j)
                acc[i][j] = __builtin_amdgcn_mfma_f32_16x16x32_bf16(al_[i], bh[j], acc[i][j], 0, 0, 0);
        #pragma unroll
        for (int i = 0; i < FM; ++i)
            #pragma unroll
            for (int j = 0; j < FN; ++j)
                acc[i][j] = __builtin_amdgcn_mfma_f32_16x16x32_bf16(ah[i], bl_[j], acc[i][j], 0, 0, 0);
        __syncthreads();
    }
    #pragma unroll
    for (int i = 0; i < FM; ++i)
        #pragma unroll
        for (int r = 0; r < 4; ++r) {
            float sum = acc[i][0][r];
            #pragma unroll
            for (int j = 1; j < FN; ++j) sum += acc[i][j][r];
            sum += __shfl_xor(sum, 1);
            sum += __shfl_xor(sum, 2);
            sum += __shfl_xor(sum, 4);
            sum += __shfl_xor(sum, 8);
            if (l15 == 0)
                unsafeAtomicAdd(pooled + bm0 + wm + i * 16 + g * 4 + r, sum * pscale);
        }
}

// ---------------- generic 64x64 tiled fp32 GEMM: C = epi(A@B) -----------------
template<int EPI, int TSTORE>
__global__ __launch_bounds__(256) void gemm64(
    const float* __restrict__ A, int lda,
    const float* __restrict__ B,
    const float* __restrict__ bias,
    float* __restrict__ C,
    int M, int N, int K)
{
    __shared__ float As[16][68];
    __shared__ float Bs[16][64];
    const int tid = threadIdx.x;
    const int bm = blockIdx.y * 64;
    const int bn = blockIdx.x * 64;
    const int tx = tid & 15;
    const int ty = tid >> 4;
    const int la_m = tid >> 2;
    const int la_k = (tid & 3) << 2;
    const int lb_k = tid >> 4;
    const int lb_n = (tid & 15) << 2;

    float acc[4][4] = {};
    for (int k0 = 0; k0 < K; k0 += 16) {
        float4 av = *(const float4*)(A + (size_t)(bm + la_m) * lda + k0 + la_k);
        As[la_k + 0][la_m] = av.x;
        As[la_k + 1][la_m] = av.y;
        As[la_k + 2][la_m] = av.z;
        As[la_k + 3][la_m] = av.w;
        const int gn = bn + lb_n;
        const float* bp = B + (size_t)(k0 + lb_k) * N + gn;
        float4 bv = *(const float4*)bp;
        *(float4*)&Bs[lb_k][lb_n] = bv;
        __syncthreads();
        #pragma unroll
        for (int k = 0; k < 16; ++k) {
            float4 a = *(const float4*)&As[k][ty << 2];
            float4 b = *(const float4*)&Bs[k][tx << 2];
            float ar[4] = {a.x, a.y, a.z, a.w};
            float br[4] = {b.x, b.y, b.z, b.w};
            #pragma unroll
            for (int i = 0; i < 4; ++i)
                #pragma unroll
                for (int j = 0; j < 4; ++j)
                    acc[i][j] = fmaf(ar[i], br[j], acc[i][j]);
        }
        __syncthreads();
    }
    if (TSTORE == 0) {
        #pragma unroll
        for (int i = 0; i < 4; ++i) {
            const int gm = bm + (ty << 2) + i;
            #pragma unroll
            for (int j = 0; j < 4; ++j) {
                const int gn = bn + (tx << 2) + j;
                float v = acc[i][j];
                if (EPI == 1) v += bias[gn];
                else if (EPI == 2) v = softplus_f(v + bias[gn]);
                C[(size_t)gm * N + gn] = v;
            }
        }
    } else {
        const int bq = bm >> 9;
        const int tt0 = (bm & (Tt - 1)) + (ty << 2);
        #pragma unroll
        for (int j = 0; j < 4; ++j) {
            const int gn = bn + (tx << 2) + j;
            float4 v;
            float* vv = (float*)&v;
            #pragma unroll
            for (int i = 0; i < 4; ++i) {
                float t = acc[i][j];
                if (EPI == 2) t = softplus_f(t + bias[gn]);
                vv[i] = t;
            }
            *(float4*)(C + ((size_t)bq * N + gn) * Tt + tt0) = v;
        }
    }
}

// --------- split-K GEMM, per-batch-transposed A, atomic accumulate ------------
template<int KS>
__global__ __launch_bounds__(256) void gemm_at_sk(
    const float* __restrict__ A_T,
    const float* __restrict__ B,
    float* __restrict__ C,
    int N, int K)
{
    __shared__ float As[16][68];
    __shared__ float Bs[16][64];
    const int tid = threadIdx.x;
    const int bm = blockIdx.y * 64;
    const int bn = blockIdx.x * 64;
    const int tx = tid & 15;
    const int ty = tid >> 4;
    const int lb_k = tid >> 4;
    const int lb_n = (tid & 15) << 2;
    const int bq = bm >> 9;
    const int tt0 = bm & (Tt - 1);
    const int kseg = K / KS;
    const int kbeg = blockIdx.z * kseg;

    float acc[4][4] = {};
    for (int k0 = kbeg; k0 < kbeg + kseg; k0 += 16) {
        float4 av = *(const float4*)(A_T + ((size_t)bq * K + k0 + lb_k) * Tt + tt0 + lb_n);
        *(float4*)&As[lb_k][lb_n] = av;
        const int gn = bn + lb_n;
        const float* bp = B + (size_t)(k0 + lb_k) * N + gn;
        float4 bv;
        if (gn + 3 < N) {
            bv = *(const float4*)bp;
        } else {
            bv.x = (gn + 0 < N) ? bp[0] : 0.f;
            bv.y = (gn + 1 < N) ? bp[1] : 0.f;
            bv.z = (gn + 2 < N) ? bp[2] : 0.f;
            bv.w = (gn + 3 < N) ? bp[3] : 0.f;
        }
        *(float4*)&Bs[lb_k][lb_n] = bv;
        __syncthreads();
        #pragma unroll
        for (int k = 0; k < 16; ++k) {
            float4 a = *(const float4*)&As[k][ty << 2];
            float4 b = *(const float4*)&Bs[k][tx << 2];
            float ar[4] = {a.x, a.y, a.z, a.w};
            float br[4] = {b.x, b.y, b.z, b.w};
            #pragma unroll
            for (int i = 0; i < 4; ++i)
                #pragma unroll
                for (int j = 0; j < 4; ++j)
                    acc[i][j] = fmaf(ar[i], br[j], acc[i][j]);
        }
        __syncthreads();
    }
    #pragma unroll
    for (int i = 0; i < 4; ++i) {
        const int gm = bm + (ty << 2) + i;
        #pragma unroll
        for (int j = 0; j < 4; ++j) {
            const int gn = bn + (tx << 2) + j;
            if (gn < N)
                unsafeAtomicAdd(&C[(size_t)gm * N + gn], acc[i][j]);
        }
    }
}

// ------- RMSNorm: writes packed hi/lo bf16 xn; adds h0 row-sums to pooled -----
__global__ __launch_bounds__(256) void rms_kernel(
    const float* __restrict__ h0, const float* __restrict__ w,
    uint_t* __restrict__ xn_pk, float* __restrict__ pooled)
{
    const int row = blockIdx.x;
    const float* p = h0 + (size_t)row * DM;
    const int tid = threadIdx.x;
    float v0 = p[tid], v1 = p[tid + 256];
    float ss = v0 * v0 + v1 * v1;
    float sm = v0 + v1;
    #pragma unroll
    for (int m = 32; m; m >>= 1) {
        ss += __shfl_xor(ss, m);
        sm += __shfl_xor(sm, m);
    }
    __shared__ float wss[4], wsm[4];
    if ((tid & 63) == 0) { wss[tid >> 6] = ss; wsm[tid >> 6] = sm; }
    __syncthreads();
    const float tot = wss[0] + wss[1] + wss[2] + wss[3];
    if (tid == 0)
        unsafeAtomicAdd(pooled + row, (wsm[0] + wsm[1] + wsm[2] + wsm[3]) * (1.0f / DM));
    const float scale = rsqrtf(tot * (1.0f / DM) + 1e-5f);
    xn_pk[(size_t)row * DM + tid]       = packf(v0 * scale * w[tid]);
    xn_pk[(size_t)row * DM + tid + 256] = packf(v1 * scale * w[tid + 256]);
}

// -------- causal depthwise conv (DC=4) + SiLU, outputs TRANSPOSED (b,di,t) ----
__global__ __launch_bounds__(256) void conv_tr_kernel(
    const float* __restrict__ xr, const float* __restrict__ cw,
    const float* __restrict__ cb, float* __restrict__ xpT, float* __restrict__ resT)
{
    __shared__ float tp[64][65];
    __shared__ float tr[64][65];
    const int di0 = blockIdx.x * 64;
    const int t0  = blockIdx.y * 64;
    const int b   = blockIdx.z;
    const int c  = threadIdx.x & 63;
    const int r4 = threadIdx.x >> 6;
    const int di = di0 + c;
    const float bias = cb[di];
    float w0 = cw[di * DC + 0], w1 = cw[di * DC + 1],
          w2 = cw[di * DC + 2], w3 = cw[di * DC + 3];
    #pragma unroll
    for (int rr = 0; rr < 64; rr += 4) {
        const int t = t0 + rr + r4;
        const int bt = b * Tt + t;
        float acc = bias;
        if (t >= 3) {
            acc = fmaf(w0, xr[(size_t)(bt - 3) * (2 * DI) + di], acc);
            acc = fmaf(w1, xr[(size_t)(bt - 2) * (2 * DI) + di], acc);
            acc = fmaf(w2, xr[(size_t)(bt - 1) * (2 * DI) + di], acc);
        } else {
            if (t >= 1) acc = fmaf(w2, xr[(size_t)(bt - 1) * (2 * DI) + di], acc);
            if (t >= 2) acc = fmaf(w1, xr[(size_t)(bt - 2) * (2 * DI) + di], acc);
        }
        acc = fmaf(w3, xr[(size_t)bt * (2 * DI) + di], acc);
        tp[rr + r4][c] = silu_fast(acc);
        tr[rr + r4][c] = xr[(size_t)bt * (2 * DI) + DI + di];
    }
    __syncthreads();
    #pragma unroll
    for (int dd = 0; dd < 64; dd += 4) {
        const int dw = dd + r4;
        const size_t o = ((size_t)b * DI + di0 + dw) * Tt + t0 + c;
        xpT[o]  = tp[c][dw];
        resT[o] = tr[c][dw];
    }
}

// ============= fused single-pass selective scan (256 thr, 8 di/block) =========
// Rolling 1-ahead register prefetch over the tq loop hides ds_read latency.
__global__ __launch_bounds__(256, 4) void scan_fused(
    const float* __restrict__ deltaT, const float* __restrict__ xdbl,
    const float* __restrict__ xpT, const float* __restrict__ resT,
    const float* __restrict__ A_log, const float* __restrict__ Dvec,
    uint_t* __restrict__ y_pk)
{
    __shared__ uint_t   sBC[2][DS][68];   // [buf][s][t]: {C bf16 hi | B bf16 lo}
    __shared__ float    sD [2][8][68];    // fp32 d (exponent path)
    __shared__ float    sDU[2][8][68];    // fp32 d*u
    __shared__ ushort_t sU [2][8][68];    // bf16 u (D-skip)
    __shared__ ushort_t sR [2][8][68];    // bf16 res (gate)
    __shared__ float ylds[CL][9];
    const int tid = threadIdx.x;
    const int grp = tid >> 5;            // 0..7 : di within block
    const int l5 = tid & 31;
    const int s = ((l5 & 1) << 4) | (l5 >> 1);   // lane remap: s^16 <-> l^1 (quad DPP)
    const int b = blockIdx.x >> 7;
    const int di0 = (blockIdx.x & 127) << 3;
    const int sd_r = tid >> 5;           // 0..7
    const int sd_t = (tid & 31) << 1;    // 0..62
    const int bc_t = tid >> 2;           // 0..63
    const int bc_s = (tid & 3) << 3;     // 0,8,16,24

    float2 rd2, ru2, rr2;
    float4 rB[2], rC[2];
    auto stage_regs = [&](int c) {
        const size_t rb = ((size_t)(b * DI + di0 + sd_r)) * Tt + c * CL + sd_t;
        rd2 = *(const float2*)(deltaT + rb);
        ru2 = *(const float2*)(xpT + rb);
        rr2 = *(const float2*)(resT + rb);
        const float* src = xdbl + ((size_t)b * Tt + c * CL + bc_t) * 96;
        rB[0] = *(const float4*)(src + 32 + bc_s);
        rB[1] = *(const float4*)(src + 32 + bc_s + 4);
        rC[0] = *(const float4*)(src + 64 + bc_s);
        rC[1] = *(const float4*)(src + 64 + bc_s + 4);
    };
    auto write_lds = [&](int bb) {
        *(float2*)&sD[bb][sd_r][sd_t] = rd2;
        float2 du2;
        du2.x = rd2.x * ru2.x;
        du2.y = rd2.y * ru2.y;
        *(float2*)&sDU[bb][sd_r][sd_t] = du2;
        *(uint_t*)&sU[bb][sd_r][sd_t] =
            (uint_t)bf16_rne(ru2.x) | ((uint_t)bf16_rne(ru2.y) << 16);
        *(uint_t*)&sR[bb][sd_r][sd_t] =
            (uint_t)bf16_rne(rr2.x) | ((uint_t)bf16_rne(rr2.y) << 16);
        const float bv[8] = {rB[0].x, rB[0].y, rB[0].z, rB[0].w,
                             rB[1].x, rB[1].y, rB[1].z, rB[1].w};
        const float cv[8] = {rC[0].x, rC[0].y, rC[0].z, rC[0].w,
                             rC[1].x, rC[1].y, rC[1].z, rC[1].w};
        #pragma unroll
        for (int j = 0; j < 8; ++j)
            sBC[bb][bc_s + j][bc_t] =
                ((uint_t)bf16_rne(cv[j]) << 16) | (uint_t)bf16_rne(bv[j]);
    };

    const bool s4b = (l5 & 1) != 0;
    const bool s0b = (l5 & 2) != 0;
    const bool s1b = (l5 & 4) != 0;
    const bool s2b = (l5 & 8) != 0;
    const bool s3b = (l5 & 16) != 0;
    const int di = di0 + grp;
    const float Ads2 = -expf(A_log[di * DS + s]) * 1.44269504f;
    const float Dv = Dvec[di];
    float h = 0.f;

    stage_regs(0);
    write_lds(0);
    #pragma unroll 1
    for (int c = 0; c < NCH; ++c) {
        const int bb = c & 1;
        __syncthreads();
        if (c < NCH - 1) stage_regs(c + 1);
        #pragma unroll 1
        for (int t0 = 0; t0 < CL; t0 += 32) {
            float buf[16] = {};
            // rolling 1-ahead prefetch across the 8 tq sub-blocks
            uint4 bc_c = *(const uint4*)&sBC[bb][s][t0];
            float4 dv_c = *(const float4*)&sD[bb][grp][t0];
            float4 du_c = *(const float4*)&sDU[bb][grp][t0];
            #pragma unroll
            for (int tq = 0; tq < 8; ++tq) {
                uint4 bc_n;
                float4 dv_n, du_n;
                if (tq < 7) {
                    const int tb = t0 + tq * 4 + 4;
                    bc_n = *(const uint4*)&sBC[bb][s][tb];
                    dv_n = *(const float4*)&sD[bb][grp][tb];
                    du_n = *(const float4*)&sDU[bb][grp][tb];
                }
                const uint_t bcv[4] = {bc_c.x, bc_c.y, bc_c.z, bc_c.w};
                const float dv[4] = {dv_c.x, dv_c.y, dv_c.z, dv_c.w};
                const float duv[4] = {du_c.x, du_c.y, du_c.z, du_c.w};
                #pragma unroll
                for (int q = 0; q < 4; ++q) {
                    const int tl = tq * 4 + q;
                    const float Bq = __uint_as_float(bcv[q] << 16);
                    const float Cq = __uint_as_float(bcv[q] & 0xFFFF0000u);
                    h = fmaf(__builtin_amdgcn_exp2f(dv[q] * Ads2), h, duv[q] * Bq);
                    const float ps = h * Cq;
                    const float pr = ps + qperm<0xB1>(ps);
                    const bool keep = ((tl & 16) != 0) == s4b;
                    buf[tl & 15] = keep ? pr : buf[tl & 15];
                }
                if (tq < 7) { bc_c = bc_n; dv_c = dv_n; du_c = du_n; }
            }
            #pragma unroll
            for (int i = 0; i < 16; ++i) buf[i] += qperm<0x4E>(buf[i]);
            float r8[8];
            #pragma unroll
            for (int i = 0; i < 8; ++i) r8[i] = s0b ? buf[2 * i + 1] : buf[2 * i];
            #pragma unroll
            for (int i = 0; i < 8; ++i) r8[i] += swz<0x101F>(r8[i]);
            float w4[4];
            #pragma unroll
            for (int i = 0; i < 4; ++i) w4[i] = s1b ? r8[2 * i + 1] : r8[2 * i];
            #pragma unroll
            for (int i = 0; i < 4; ++i) w4[i] += swz<0x201F>(w4[i]);
            float v2[2];
            v2[0] = s2b ? w4[1] : w4[0];
            v2[1] = s2b ? w4[3] : w4[2];
            v2[0] += swz<0x401F>(v2[0]);
            v2[1] += swz<0x401F>(v2[1]);
            const float yv = s3b ? v2[1] : v2[0];
            const float uself = bf16_tof(sU[bb][grp][t0 + s]);
            const float rself = bf16_tof(sR[bb][grp][t0 + s]);
            ylds[t0 + s][grp] = fmaf(uself, Dv, yv) * silu_fast(rself);
        }
        __syncthreads();
        {
            const int row = tid >> 2;
            const int q2 = (tid & 3) << 1;
            uint2 o;
            o.x = packf(ylds[row][q2 + 0]);
            o.y = packf(ylds[row][q2 + 1]);
            *(uint2*)(y_pk + ((size_t)b * Tt + c * CL + row) * DI + di0 + q2) = o;
        }
        if (c < NCH - 1) write_lds(bb ^ 1);
    }
}

// ---------------- classifier ---------------------------------------------------
__global__ __launch_bounds__(256) void cls_kernel(
    const float* __restrict__ pooled, const float* __restrict__ w_cls,
    const float* __restrict__ b_cls, float* __restrict__ out)
{
    const int idx = blockIdx.x * 256 + threadIdx.x;
    if (idx >= Bb * NC) return;
    const int b = idx / NC, c = idx % NC;
    float acc = b_cls[c];
    for (int t = 0; t < DM; ++t)
        acc = fmaf(pooled[b * DM + t], w_cls[t * NC + c], acc);
    out[idx] = acc;
}

extern "C" void kernel_launch(void* const* d_in, const int* in_sizes, int n_in,
                              void* d_out, int out_size, void* d_ws, size_t ws_size,
                              hipStream_t stream) {
    const float* x      = (const float*)d_in[0];
    const float* w_proj = (const float*)d_in[1];
    const float* b_proj = (const float*)d_in[2];
    const float* rms_w  = (const float*)d_in[3];
    const float* w_in   = (const float*)d_in[4];
    const float* conv_w = (const float*)d_in[5];
    const float* conv_b = (const float*)d_in[6];
    const float* w_xprj = (const float*)d_in[7];
    const float* w_dt   = (const float*)d_in[8];
    const float* b_dt   = (const float*)d_in[9];
    const float* A_log  = (const float*)d_in[10];
    const float* Dvec   = (const float*)d_in[11];
    const float* w_out  = (const float*)d_in[12];
    const float* w_cls  = (const float*)d_in[13];
    const float* b_cls  = (const float*)d_in[14];
    float* out = (float*)d_out;

    float* ws = (float*)d_ws;
    float* h0     = ws;
    float* xn     = h0 + (size_t)BT * DM;          // holds xn_pk (uint)
    float* xr     = xn + (size_t)BT * DM;
    float* xpT    = xr + (size_t)BT * 2 * DI;
    float* resT   = xpT + (size_t)Bb * DI * Tt;
    float* xdbl   = resT + (size_t)Bb * DI * Tt;
    float* pooled = xdbl + (size_t)BT * 96;
    float* wsplit = pooled + 4096;                 // weight-split scratch
    float* deltaT = xr;                            // alias: xr dead after conv_tr
    uint_t* y_pk  = (uint_t*)(xr + (size_t)Bb * DI * Tt);  // upper half of xr
    uint_t* xn_pk = (uint_t*)xn;

    // weight splits (bf16 hi/lo, transposed to [n][k]) — all own scratch:
    ushort_t* w_in_hi  = (ushort_t*)wsplit;
    ushort_t* w_in_lo  = w_in_hi + (size_t)(2 * DI) * DM;
    ushort_t* w_out_hi = w_in_lo + (size_t)(2 * DI) * DM;
    ushort_t* w_out_lo = w_out_hi + (size_t)DM * DI;

    // 0) split+transpose w_in; fused zero of xdbl+pooled (contiguous region)
    split_tr_kernel<<<dim3(2 * DI / 32, DM / 32), 256, 0, stream>>>(
        w_in, w_in_hi, w_in_lo, DM, 2 * DI,
        (float4*)xdbl, (BT * 96 + 4096) / 4);
    // 0b) split+transpose w_out (no zero)
    split_tr_kernel<<<dim3(DM / 32, DI / 32), 256, 0, stream>>>(
        w_out, w_out_hi, w_out_lo, DI, DM, nullptr, 0);
    // 1) h0 = x @ w_proj + b_proj
    gemm64<1,0><<<dim3(DM / 64, BT / 64), 256, 0, stream>>>(
        x, NM, w_proj, b_proj, h0, BT, DM, NM);
    // 2) xn_pk = pack(rmsnorm(h0) * rms_w); pooled += rowsum(h0)/DM
    rms_kernel<<<BT, 256, 0, stream>>>(h0, rms_w, xn_pk, pooled);
    // 3) xr = xn @ w_in    (split-bf16 MFMA, 8-wave blocks)
    gemm_mfma_big<<<dim3(2 * DI / 128, BT / 128), 512, 0, stream>>>(
        xn_pk, DM, w_in_hi, w_in_lo, xr, 2 * DI, DM);
    // 4) xpT = silu(causal_dwconv(xr[:, :DI]))^T ; resT = xr[:, DI:]^T
    conv_tr_kernel<<<dim3(DI / 64, Tt / 64, Bb), 256, 0, stream>>>(
        xr, conv_w, conv_b, xpT, resT);
    // 5) xdbl += xp @ w_xproj   (split-K=4, atomic accumulate)
    gemm_at_sk<4><<<dim3(2, BT / 64, 4), 256, 0, stream>>>(
        xpT, w_xprj, xdbl, 96, DI);
    // 6) deltaT = softplus(dt @ w_dt + b_dt)^T
    gemm64<2,1><<<dim3(DI / 64, BT / 64), 256, 0, stream>>>(
        xdbl, 96, w_dt, b_dt, deltaT, BT, DI, DR);
    // 7) fused single-pass selective scan (h in registers across chunks)
    scan_fused<<<Bb * (DI / 8), 256, 0, stream>>>(
        deltaT, xdbl, xpT, resT, A_log, Dvec, y_pk);
    // 8) pooled += rowsum(y @ w_out)/DM   (MFMA + split-K=4 + fused mean-pool)
    gemm_mfma_pool<<<dim3(DM / 64, BT / 64, 4), 256, 0, stream>>>(
        y_pk, DI, w_out_hi, w_out_lo, pooled, 1.0f / DM, DM, DI, DI / 4);
    // 9) out = pooled @ w_cls + b_cls
    cls_kernel<<<(Bb * NC + 255) / 256, 256, 0, stream>>>(pooled, w_cls, b_cls, out);
}

// Round 14
// 288.319 us; speedup vs baseline: 1.2915x; 1.2915x over previous
//
#include <hip/hip_runtime.h>
#include <hip/hip_bf16.h>
#include <cstddef>

#define Bb 8
#define Tt 512
#define NM 128
#define DM 512
#define DI 1024
#define DS 32
#define DR 32
#define DC 4
#define NC 100
#define BT (Bb*Tt)     // 4096
#define NCH 8          // scan chunks
#define CL  64         // chunk length

typedef unsigned short ushort_t;
typedef unsigned int uint_t;
typedef __attribute__((ext_vector_type(8))) short bf8;    // 8 bf16 in 4 VGPRs
typedef __attribute__((ext_vector_type(4))) float f4;
typedef __attribute__((ext_vector_type(4))) unsigned short us4;

__device__ __forceinline__ float softplus_f(float x) {
    return fmaxf(x, 0.f) + log1pf(expf(-fabsf(x)));
}
__device__ __forceinline__ float silu_fast(float x) {
    return __fdividef(x, 1.f + __expf(-x));
}
__device__ __forceinline__ ushort_t bf16_rne(float x) {
    uint_t u = __float_as_uint(x);
    uint_t r = u + 0x7FFFu + ((u >> 16) & 1u);
    return (ushort_t)(r >> 16);
}
__device__ __forceinline__ float bf16_tof(ushort_t h) {
    return __uint_as_float(((uint_t)h) << 16);
}
// pack fp32 -> {hi bf16 in [31:16], lo bf16 in [15:0]}
__device__ __forceinline__ uint_t packf(float v) {
    ushort_t h = bf16_rne(v);
    ushort_t l = bf16_rne(v - bf16_tof(h));
    return ((uint_t)h << 16) | (uint_t)l;
}
// cross-lane: quad_perm DPP (VALU pipe) and ds_swizzle (DS pipe)
template<int CTRL>
__device__ __forceinline__ float qperm(float x) {
    return __int_as_float(__builtin_amdgcn_mov_dpp(__float_as_int(x), CTRL, 0xF, 0xF, true));
}
template<int PAT>
__device__ __forceinline__ float swz(float x) {
    return __int_as_float(__builtin_amdgcn_ds_swizzle(__float_as_int(x), PAT));
}

// ---- split fp32 (K,N) row-major into bf16 hi/lo, TRANSPOSED to (N,K) --------
// Optionally zeroes zcount float4s at zbase (fused init, saves a launch).
__global__ __launch_bounds__(256) void split_tr_kernel(
    const float* __restrict__ src, ushort_t* __restrict__ hi,
    ushort_t* __restrict__ lo, int K, int N,
    float4* __restrict__ zbase, int zcount)
{
    __shared__ ushort_t th[32][34], tl[32][34];
    const int k0 = blockIdx.y * 32, n0 = blockIdx.x * 32;
    if (zbase) {
        const int zi = (blockIdx.y * gridDim.x + blockIdx.x) * 256 + threadIdx.x;
        if (zi < zcount) zbase[zi] = make_float4(0.f, 0.f, 0.f, 0.f);
    }
    #pragma unroll
    for (int it = 0; it < 4; ++it) {
        const int idx = it * 256 + threadIdx.x;
        const int r = idx >> 5, c = idx & 31;
        const float v = src[(size_t)(k0 + r) * N + n0 + c];
        const ushort_t h = bf16_rne(v);
        th[c][r] = h;
        tl[c][r] = bf16_rne(v - bf16_tof(h));
    }
    __syncthreads();
    #pragma unroll
    for (int it = 0; it < 4; ++it) {
        const int idx = it * 256 + threadIdx.x;
        const int r = idx >> 5, c = idx & 31;
        hi[(size_t)(n0 + r) * K + k0 + c] = th[r][c];
        lo[(size_t)(n0 + r) * K + k0 + c] = tl[r][c];
    }
}

// ---- split-bf16 MFMA GEMM, 512 thr / 8 waves, 128x128 tile, C write ---------
__global__ __launch_bounds__(512) void gemm_mfma_big(
    const uint_t* __restrict__ Apk, int lda,
    const ushort_t* __restrict__ Bhi, const ushort_t* __restrict__ Blo,
    float* __restrict__ C, int N, int K)
{
    constexpr int BM = 128, BN = 128;
    constexpr int FM = 2, FN = 4;         // wave tile 32x64
    __shared__ ushort_t sA[2][BM][40];
    __shared__ ushort_t sB[2][BN][40];
    const int tid = threadIdx.x;
    const int wid = tid >> 6, l = tid & 63, l15 = l & 15, g = l >> 4;
    const int wm = (wid >> 1) * 32, wn = (wid & 1) * 64;
    const int bm0 = blockIdx.y * BM, bn0 = blockIdx.x * BN;

    f4 acc[FM][FN] = {};
    uint4 aR[2], bRh, bRl;

    auto loadG = [&](int k0) {
        #pragma unroll
        for (int r = 0; r < 2; ++r) {
            const int idx = r * 2048 + tid * 4;
            const int m = idx >> 5, k = idx & 31;
            aR[r] = *(const uint4*)(Apk + (size_t)(bm0 + m) * lda + k0 + k);
        }
        {
            const int idx = tid * 8;
            const int n = idx >> 5, k = idx & 31;
            const size_t o = (size_t)(bn0 + n) * K + k0 + k;
            bRh = *(const uint4*)(Bhi + o);
            bRl = *(const uint4*)(Blo + o);
        }
    };
    auto stoL = [&]() {
        #pragma unroll
        for (int r = 0; r < 2; ++r) {
            const int idx = r * 2048 + tid * 4;
            const int m = idx >> 5, k = idx & 31;
            const uint_t u0 = aR[r].x, u1 = aR[r].y, u2 = aR[r].z, u3 = aR[r].w;
            uint2 hh, ll;
            hh.x = (u0 >> 16) | (u1 & 0xFFFF0000u);
            hh.y = (u2 >> 16) | (u3 & 0xFFFF0000u);
            ll.x = (u0 & 0xFFFFu) | (u1 << 16);
            ll.y = (u2 & 0xFFFFu) | (u3 << 16);
            *(uint2*)&sA[0][m][k] = hh;
            *(uint2*)&sA[1][m][k] = ll;
        }
        {
            const int idx = tid * 8;
            const int n = idx >> 5, k = idx & 31;
            *(uint4*)&sB[0][n][k] = bRh;
            *(uint4*)&sB[1][n][k] = bRl;
        }
    };

    loadG(0);
    for (int k0 = 0; k0 < K; k0 += 32) {
        stoL();
        __syncthreads();
        if (k0 + 32 < K) loadG(k0 + 32);
        bf8 ah[FM], al_[FM], bh[FN], bl_[FN];
        #pragma unroll
        for (int i = 0; i < FM; ++i) {
            ah[i]  = *(bf8*)&sA[0][wm + i * 16 + l15][g * 8];
            al_[i] = *(bf8*)&sA[1][wm + i * 16 + l15][g * 8];
        }
        #pragma unroll
        for (int j = 0; j < FN; ++j) {
            bh[j]  = *(bf8*)&sB[0][wn + j * 16 + l15][g * 8];
            bl_[j] = *(bf8*)&sB[1][wn + j * 16 + l15][g * 8];
        }
        #pragma unroll
        for (int i = 0; i < FM; ++i)
            #pragma unroll
            for (int j = 0; j < FN; ++j)
                acc[i][j] = __builtin_amdgcn_mfma_f32_16x16x32_bf16(ah[i], bh[j], acc[i][j], 0, 0, 0);
        #pragma unroll
        for (int i = 0; i < FM; ++i)
            #pragma unroll
            for (int j = 0; j < FN; ++j)
                acc[i][j] = __builtin_amdgcn_mfma_f32_16x16x32_bf16(al_[i], bh[j], acc[i][j], 0, 0, 0);
        #pragma unroll
        for (int i = 0; i < FM; ++i)
            #pragma unroll
            for (int j = 0; j < FN; ++j)
                acc[i][j] = __builtin_amdgcn_mfma_f32_16x16x32_bf16(ah[i], bl_[j], acc[i][j], 0, 0, 0);
        __syncthreads();
    }
    #pragma unroll
    for (int i = 0; i < FM; ++i)
        #pragma unroll
        for (int j = 0; j < FN; ++j)
            #pragma unroll
            for (int r = 0; r < 4; ++r) {
                const int m = bm0 + wm + i * 16 + g * 4 + r;
                const int n = bn0 + wn + j * 16 + l15;
                C[(size_t)m * N + n] = acc[i][j][r];
            }
}

// ---- split-bf16 MFMA GEMM, 64x64 tile, split-K, fused mean-pool -------------
__global__ __launch_bounds__(256) void gemm_mfma_pool(
    const uint_t* __restrict__ Apk, int lda,
    const ushort_t* __restrict__ Bhi, const ushort_t* __restrict__ Blo,
    float* __restrict__ pooled, float pscale,
    int N, int K, int kseg)
{
    constexpr int BM = 64, BN = 64;
    constexpr int FM = 2, FN = 2;
    __shared__ ushort_t sA[2][BM][40];
    __shared__ ushort_t sB[2][BN][40];
    const int tid = threadIdx.x;
    const int wid = tid >> 6, l = tid & 63, l15 = l & 15, g = l >> 4;
    const int wm = (wid >> 1) * 32, wn = (wid & 1) * 32;
    const int bm0 = blockIdx.y * BM, bn0 = blockIdx.x * BN;
    const int kbeg = blockIdx.z * kseg;

    f4 acc[FM][FN] = {};
    uint4 aR[2], bRh, bRl;

    auto loadG = [&](int k0) {
        #pragma unroll
        for (int r = 0; r < 2; ++r) {
            const int idx = r * 1024 + tid * 4;
            const int m = idx >> 5, k = idx & 31;
            aR[r] = *(const uint4*)(Apk + (size_t)(bm0 + m) * lda + k0 + k);
        }
        {
            const int idx = tid * 8;
            const int n = idx >> 5, k = idx & 31;
            const size_t o = (size_t)(bn0 + n) * K + k0 + k;
            bRh = *(const uint4*)(Bhi + o);
            bRl = *(const uint4*)(Blo + o);
        }
    };
    auto stoL = [&]() {
        #pragma unroll
        for (int r = 0; r < 2; ++r) {
            const int idx = r * 1024 + tid * 4;
            const int m = idx >> 5, k = idx & 31;
            const uint_t u0 = aR[r].x, u1 = aR[r].y, u2 = aR[r].z, u3 = aR[r].w;
            uint2 hh, ll;
            hh.x = (u0 >> 16) | (u1 & 0xFFFF0000u);
            hh.y = (u2 >> 16) | (u3 & 0xFFFF0000u);
            ll.x = (u0 & 0xFFFFu) | (u1 << 16);
            ll.y = (u2 & 0xFFFFu) | (u3 << 16);
            *(uint2*)&sA[0][m][k] = hh;
            *(uint2*)&sA[1][m][k] = ll;
        }
        {
            const int idx = tid * 8;
            const int n = idx >> 5, k = idx & 31;
            *(uint4*)&sB[0][n][k] = bRh;
            *(uint4*)&sB[1][n][k] = bRl;
        }
    };

    loadG(kbeg);
    for (int k0 = kbeg; k0 < kbeg + kseg; k0 += 32) {
        stoL();
        __syncthreads();
        if (k0 + 32 < kbeg + kseg) loadG(k0 + 32);
        bf8 ah[FM], al_[FM], bh[FN], bl_[FN];
        #pragma unroll
        for (int i = 0; i < FM; ++i) {
            ah[i]  = *(bf8*)&sA[0][wm + i * 16 + l15][g * 8];
            al_[i] = *(bf8*)&sA[1][wm + i * 16 + l15][g * 8];
        }
        #pragma unroll
        for (int j = 0; j < FN; ++j) {
            bh[j]  = *(bf8*)&sB[0][wn + j * 16 + l15][g * 8];
            bl_[j] = *(bf8*)&sB[1][wn + j * 16 + l15][g * 8];
        }
        #pragma unroll
        for (int i = 0; i < FM; ++i)
            #pragma unroll
            for (int j = 0; j < FN; ++j)
                acc[i][j] = __builtin_amdgcn_mfma_f32_16x16x32_bf16(ah[i], bh[j], acc[i][j], 0, 0, 0);
        #pragma unroll
        for (int i = 0; i < FM; ++i)
            #pragma unroll
            for (int j = 0; j < FN; ++j)
                acc[i][j] = __builtin_amdgcn_mfma_f32_16x16x32_bf16(al_[i], bh[j], acc[i][j], 0, 0, 0);
        #pragma unroll
        for (int i = 0; i < FM; ++i)
            #pragma unroll
            for (int j = 0; j < FN; ++j)
                acc[i][j] = __builtin_amdgcn_mfma_f32_16x16x32_bf16(ah[i], bl_[j], acc[i][j], 0, 0, 0);
        __syncthreads();
    }
    #pragma unroll
    for (int i = 0; i < FM; ++i)
        #pragma unroll
        for (int r = 0; r < 4; ++r) {
            float sum = acc[i][0][r];
            #pragma unroll
            for (int j = 1; j < FN; ++j) sum += acc[i][j][r];
            sum += __shfl_xor(sum, 1);
            sum += __shfl_xor(sum, 2);
            sum += __shfl_xor(sum, 4);
            sum += __shfl_xor(sum, 8);
            if (l15 == 0)
                unsafeAtomicAdd(pooled + bm0 + wm + i * 16 + g * 4 + r, sum * pscale);
        }
}

// ---------------- generic 64x64 tiled fp32 GEMM: C = epi(A@B) -----------------
template<int EPI, int TSTORE>
__global__ __launch_bounds__(256) void gemm64(
    const float* __restrict__ A, int lda,
    const float* __restrict__ B,
    const float* __restrict__ bias,
    float* __restrict__ C,
    int M, int N, int K)
{
    __shared__ float As[16][68];
    __shared__ float Bs[16][64];
    const int tid = threadIdx.x;
    const int bm = blockIdx.y * 64;
    const int bn = blockIdx.x * 64;
    const int tx = tid & 15;
    const int ty = tid >> 4;
    const int la_m = tid >> 2;
    const int la_k = (tid & 3) << 2;
    const int lb_k = tid >> 4;
    const int lb_n = (tid & 15) << 2;

    float acc[4][4] = {};
    for (int k0 = 0; k0 < K; k0 += 16) {
        float4 av = *(const float4*)(A + (size_t)(bm + la_m) * lda + k0 + la_k);
        As[la_k + 0][la_m] = av.x;
        As[la_k + 1][la_m] = av.y;
        As[la_k + 2][la_m] = av.z;
        As[la_k + 3][la_m] = av.w;
        const int gn = bn + lb_n;
        const float* bp = B + (size_t)(k0 + lb_k) * N + gn;
        float4 bv = *(const float4*)bp;
        *(float4*)&Bs[lb_k][lb_n] = bv;
        __syncthreads();
        #pragma unroll
        for (int k = 0; k < 16; ++k) {
            float4 a = *(const float4*)&As[k][ty << 2];
            float4 b = *(const float4*)&Bs[k][tx << 2];
            float ar[4] = {a.x, a.y, a.z, a.w};
            float br[4] = {b.x, b.y, b.z, b.w};
            #pragma unroll
            for (int i = 0; i < 4; ++i)
                #pragma unroll
                for (int j = 0; j < 4; ++j)
                    acc[i][j] = fmaf(ar[i], br[j], acc[i][j]);
        }
        __syncthreads();
    }
    if (TSTORE == 0) {
        #pragma unroll
        for (int i = 0; i < 4; ++i) {
            const int gm = bm + (ty << 2) + i;
            #pragma unroll
            for (int j = 0; j < 4; ++j) {
                const int gn = bn + (tx << 2) + j;
                float v = acc[i][j];
                if (EPI == 1) v += bias[gn];
                else if (EPI == 2) v = softplus_f(v + bias[gn]);
                C[(size_t)gm * N + gn] = v;
            }
        }
    } else {
        const int bq = bm >> 9;
        const int tt0 = (bm & (Tt - 1)) + (ty << 2);
        #pragma unroll
        for (int j = 0; j < 4; ++j) {
            const int gn = bn + (tx << 2) + j;
            float4 v;
            float* vv = (float*)&v;
            #pragma unroll
            for (int i = 0; i < 4; ++i) {
                float t = acc[i][j];
                if (EPI == 2) t = softplus_f(t + bias[gn]);
                vv[i] = t;
            }
            *(float4*)(C + ((size_t)bq * N + gn) * Tt + tt0) = v;
        }
    }
}

// --------- split-K GEMM, per-batch-transposed A, atomic accumulate ------------
template<int KS>
__global__ __launch_bounds__(256) void gemm_at_sk(
    const float* __restrict__ A_T,
    const float* __restrict__ B,
    float* __restrict__ C,
    int N, int K)
{
    __shared__ float As[16][68];
    __shared__ float Bs[16][64];
    const int tid = threadIdx.x;
    const int bm = blockIdx.y * 64;
    const int bn = blockIdx.x * 64;
    const int tx = tid & 15;
    const int ty = tid >> 4;
    const int lb_k = tid >> 4;
    const int lb_n = (tid & 15) << 2;
    const int bq = bm >> 9;
    const int tt0 = bm & (Tt - 1);
    const int kseg = K / KS;
    const int kbeg = blockIdx.z * kseg;

    float acc[4][4] = {};
    for (int k0 = kbeg; k0 < kbeg + kseg; k0 += 16) {
        float4 av = *(const float4*)(A_T + ((size_t)bq * K + k0 + lb_k) * Tt + tt0 + lb_n);
        *(float4*)&As[lb_k][lb_n] = av;
        const int gn = bn + lb_n;
        const float* bp = B + (size_t)(k0 + lb_k) * N + gn;
        float4 bv;
        if (gn + 3 < N) {
            bv = *(const float4*)bp;
        } else {
            bv.x = (gn + 0 < N) ? bp[0] : 0.f;
            bv.y = (gn + 1 < N) ? bp[1] : 0.f;
            bv.z = (gn + 2 < N) ? bp[2] : 0.f;
            bv.w = (gn + 3 < N) ? bp[3] : 0.f;
        }
        *(float4*)&Bs[lb_k][lb_n] = bv;
        __syncthreads();
        #pragma unroll
        for (int k = 0; k < 16; ++k) {
            float4 a = *(const float4*)&As[k][ty << 2];
            float4 b = *(const float4*)&Bs[k][tx << 2];
            float ar[4] = {a.x, a.y, a.z, a.w};
            float br[4] = {b.x, b.y, b.z, b.w};
            #pragma unroll
            for (int i = 0; i < 4; ++i)
                #pragma unroll
                for (int j = 0; j < 4; ++j)
                    acc[i][j] = fmaf(ar[i], br[j], acc[i][j]);
        }
        __syncthreads();
    }
    #pragma unroll
    for (int i = 0; i < 4; ++i) {
        const int gm = bm + (ty << 2) + i;
        #pragma unroll
        for (int j = 0; j < 4; ++j) {
            const int gn = bn + (tx << 2) + j;
            if (gn < N)
                unsafeAtomicAdd(&C[(size_t)gm * N + gn], acc[i][j]);
        }
    }
}

// ------- RMSNorm: writes packed hi/lo bf16 xn; adds h0 row-sums to pooled -----
__global__ __launch_bounds__(256) void rms_kernel(
    const float* __restrict__ h0, const float* __restrict__ w,
    uint_t* __restrict__ xn_pk, float* __restrict__ pooled)
{
    const int row = blockIdx.x;
    const float* p = h0 + (size_t)row * DM;
    const int tid = threadIdx.x;
    float v0 = p[tid], v1 = p[tid + 256];
    float ss = v0 * v0 + v1 * v1;
    float sm = v0 + v1;
    #pragma unroll
    for (int m = 32; m; m >>= 1) {
        ss += __shfl_xor(ss, m);
        sm += __shfl_xor(sm, m);
    }
    __shared__ float wss[4], wsm[4];
    if ((tid & 63) == 0) { wss[tid >> 6] = ss; wsm[tid >> 6] = sm; }
    __syncthreads();
    const float tot = wss[0] + wss[1] + wss[2] + wss[3];
    if (tid == 0)
        unsafeAtomicAdd(pooled + row, (wsm[0] + wsm[1] + wsm[2] + wsm[3]) * (1.0f / DM));
    const float scale = rsqrtf(tot * (1.0f / DM) + 1e-5f);
    xn_pk[(size_t)row * DM + tid]       = packf(v0 * scale * w[tid]);
    xn_pk[(size_t)row * DM + tid + 256] = packf(v1 * scale * w[tid + 256]);
}

// -------- causal depthwise conv (DC=4) + SiLU, outputs TRANSPOSED (b,di,t) ----
__global__ __launch_bounds__(256) void conv_tr_kernel(
    const float* __restrict__ xr, const float* __restrict__ cw,
    const float* __restrict__ cb, float* __restrict__ xpT, float* __restrict__ resT)
{
    __shared__ float tp[64][65];
    __shared__ float tr[64][65];
    const int di0 = blockIdx.x * 64;
    const int t0  = blockIdx.y * 64;
    const int b   = blockIdx.z;
    const int c  = threadIdx.x & 63;
    const int r4 = threadIdx.x >> 6;
    const int di = di0 + c;
    const float bias = cb[di];
    float w0 = cw[di * DC + 0], w1 = cw[di * DC + 1],
          w2 = cw[di * DC + 2], w3 = cw[di * DC + 3];
    #pragma unroll
    for (int rr = 0; rr < 64; rr += 4) {
        const int t = t0 + rr + r4;
        const int bt = b * Tt + t;
        float acc = bias;
        if (t >= 3) {
            acc = fmaf(w0, xr[(size_t)(bt - 3) * (2 * DI) + di], acc);
            acc = fmaf(w1, xr[(size_t)(bt - 2) * (2 * DI) + di], acc);
            acc = fmaf(w2, xr[(size_t)(bt - 1) * (2 * DI) + di], acc);
        } else {
            if (t >= 1) acc = fmaf(w2, xr[(size_t)(bt - 1) * (2 * DI) + di], acc);
            if (t >= 2) acc = fmaf(w1, xr[(size_t)(bt - 2) * (2 * DI) + di], acc);
        }
        acc = fmaf(w3, xr[(size_t)bt * (2 * DI) + di], acc);
        tp[rr + r4][c] = silu_fast(acc);
        tr[rr + r4][c] = xr[(size_t)bt * (2 * DI) + DI + di];
    }
    __syncthreads();
    #pragma unroll
    for (int dd = 0; dd < 64; dd += 4) {
        const int dw = dd + r4;
        const size_t o = ((size_t)b * DI + di0 + dw) * Tt + t0 + c;
        xpT[o]  = tp[c][dw];
        resT[o] = tr[c][dw];
    }
}

// ============= fused single-pass selective scan (256 thr, 8 di/block) =========
// Rolling 1-ahead LDS prefetch; NO launch-bounds pin (avoid register spill).
__global__ __launch_bounds__(256) void scan_fused(
    const float* __restrict__ deltaT, const float* __restrict__ xdbl,
    const float* __restrict__ xpT, const float* __restrict__ resT,
    const float* __restrict__ A_log, const float* __restrict__ Dvec,
    uint_t* __restrict__ y_pk)
{
    __shared__ uint_t   sBC[2][DS][68];   // [buf][s][t]: {C bf16 hi | B bf16 lo}
    __shared__ float    sD [2][8][68];    // fp32 d (exponent path)
    __shared__ float    sDU[2][8][68];    // fp32 d*u
    __shared__ ushort_t sU [2][8][68];    // bf16 u (D-skip)
    __shared__ ushort_t sR [2][8][68];    // bf16 res (gate)
    __shared__ float ylds[CL][9];
    const int tid = threadIdx.x;
    const int grp = tid >> 5;            // 0..7 : di within block
    const int l5 = tid & 31;
    const int s = ((l5 & 1) << 4) | (l5 >> 1);   // lane remap: s^16 <-> l^1 (quad DPP)
    const int b = blockIdx.x >> 7;
    const int di0 = (blockIdx.x & 127) << 3;
    const int sd_r = tid >> 5;           // 0..7
    const int sd_t = (tid & 31) << 1;    // 0..62
    const int bc_t = tid >> 2;           // 0..63
    const int bc_s = (tid & 3) << 3;     // 0,8,16,24

    float2 rd2, ru2, rr2;
    float4 rB[2], rC[2];
    auto stage_regs = [&](int c) {
        const size_t rb = ((size_t)(b * DI + di0 + sd_r)) * Tt + c * CL + sd_t;
        rd2 = *(const float2*)(deltaT + rb);
        ru2 = *(const float2*)(xpT + rb);
        rr2 = *(const float2*)(resT + rb);
        const float* src = xdbl + ((size_t)b * Tt + c * CL + bc_t) * 96;
        rB[0] = *(const float4*)(src + 32 + bc_s);
        rB[1] = *(const float4*)(src + 32 + bc_s + 4);
        rC[0] = *(const float4*)(src + 64 + bc_s);
        rC[1] = *(const float4*)(src + 64 + bc_s + 4);
    };
    auto write_lds = [&](int bb) {
        *(float2*)&sD[bb][sd_r][sd_t] = rd2;
        float2 du2;
        du2.x = rd2.x * ru2.x;
        du2.y = rd2.y * ru2.y;
        *(float2*)&sDU[bb][sd_r][sd_t] = du2;
        *(uint_t*)&sU[bb][sd_r][sd_t] =
            (uint_t)bf16_rne(ru2.x) | ((uint_t)bf16_rne(ru2.y) << 16);
        *(uint_t*)&sR[bb][sd_r][sd_t] =
            (uint_t)bf16_rne(rr2.x) | ((uint_t)bf16_rne(rr2.y) << 16);
        const float bv[8] = {rB[0].x, rB[0].y, rB[0].z, rB[0].w,
                             rB[1].x, rB[1].y, rB[1].z, rB[1].w};
        const float cv[8] = {rC[0].x, rC[0].y, rC[0].z, rC[0].w,
                             rC[1].x, rC[1].y, rC[1].z, rC[1].w};
        #pragma unroll
        for (int j = 0; j < 8; ++j)
            sBC[bb][bc_s + j][bc_t] =
                ((uint_t)bf16_rne(cv[j]) << 16) | (uint_t)bf16_rne(bv[j]);
    };

    const bool s4b = (l5 & 1) != 0;
    const bool s0b = (l5 & 2) != 0;
    const bool s1b = (l5 & 4) != 0;
    const bool s2b = (l5 & 8) != 0;
    const bool s3b = (l5 & 16) != 0;
    const int di = di0 + grp;
    const float Ads2 = -expf(A_log[di * DS + s]) * 1.44269504f;
    const float Dv = Dvec[di];
    float h = 0.f;

    stage_regs(0);
    write_lds(0);
    #pragma unroll 1
    for (int c = 0; c < NCH; ++c) {
        const int bb = c & 1;
        __syncthreads();
        if (c < NCH - 1) stage_regs(c + 1);
        #pragma unroll 1
        for (int t0 = 0; t0 < CL; t0 += 32) {
            float buf[16] = {};
            // rolling 1-ahead LDS prefetch across the 8 tq sub-blocks
            uint4 bc_c = *(const uint4*)&sBC[bb][s][t0];
            float4 dv_c = *(const float4*)&sD[bb][grp][t0];
            float4 du_c = *(const float4*)&sDU[bb][grp][t0];
            #pragma unroll
            for (int tq = 0; tq < 8; ++tq) {
                uint4 bc_n;
                float4 dv_n, du_n;
                if (tq < 7) {
                    const int tb = t0 + tq * 4 + 4;
                    bc_n = *(const uint4*)&sBC[bb][s][tb];
                    dv_n = *(const float4*)&sD[bb][grp][tb];
                    du_n = *(const float4*)&sDU[bb][grp][tb];
                }
                const uint_t bcv[4] = {bc_c.x, bc_c.y, bc_c.z, bc_c.w};
                const float dv[4] = {dv_c.x, dv_c.y, dv_c.z, dv_c.w};
                const float duv[4] = {du_c.x, du_c.y, du_c.z, du_c.w};
                #pragma unroll
                for (int q = 0; q < 4; ++q) {
                    const int tl = tq * 4 + q;
                    const float Bq = __uint_as_float(bcv[q] << 16);
                    const float Cq = __uint_as_float(bcv[q] & 0xFFFF0000u);
                    h = fmaf(__builtin_amdgcn_exp2f(dv[q] * Ads2), h, duv[q] * Bq);
                    const float ps = h * Cq;
                    const float pr = ps + qperm<0xB1>(ps);
                    const bool keep = ((tl & 16) != 0) == s4b;
                    buf[tl & 15] = keep ? pr : buf[tl & 15];
                }
                if (tq < 7) { bc_c = bc_n; dv_c = dv_n; du_c = du_n; }
            }
            #pragma unroll
            for (int i = 0; i < 16; ++i) buf[i] += qperm<0x4E>(buf[i]);
            float r8[8];
            #pragma unroll
            for (int i = 0; i < 8; ++i) r8[i] = s0b ? buf[2 * i + 1] : buf[2 * i];
            #pragma unroll
            for (int i = 0; i < 8; ++i) r8[i] += swz<0x101F>(r8[i]);
            float w4[4];
            #pragma unroll
            for (int i = 0; i < 4; ++i) w4[i] = s1b ? r8[2 * i + 1] : r8[2 * i];
            #pragma unroll
            for (int i = 0; i < 4; ++i) w4[i] += swz<0x201F>(w4[i]);
            float v2[2];
            v2[0] = s2b ? w4[1] : w4[0];
            v2[1] = s2b ? w4[3] : w4[2];
            v2[0] += swz<0x401F>(v2[0]);
            v2[1] += swz<0x401F>(v2[1]);
            const float yv = s3b ? v2[1] : v2[0];
            const float uself = bf16_tof(sU[bb][grp][t0 + s]);
            const float rself = bf16_tof(sR[bb][grp][t0 + s]);
            ylds[t0 + s][grp] = fmaf(uself, Dv, yv) * silu_fast(rself);
        }
        __syncthreads();
        {
            const int row = tid >> 2;
            const int q2 = (tid & 3) << 1;
            uint2 o;
            o.x = packf(ylds[row][q2 + 0]);
            o.y = packf(ylds[row][q2 + 1]);
            *(uint2*)(y_pk + ((size_t)b * Tt + c * CL + row) * DI + di0 + q2) = o;
        }
        if (c < NCH - 1) write_lds(bb ^ 1);
    }
}

// ---------------- classifier ---------------------------------------------------
__global__ __launch_bounds__(256) void cls_kernel(
    const float* __restrict__ pooled, const float* __restrict__ w_cls,
    const float* __restrict__ b_cls, float* __restrict__ out)
{
    const int idx = blockIdx.x * 256 + threadIdx.x;
    if (idx >= Bb * NC) return;
    const int b = idx / NC, c = idx % NC;
    float acc = b_cls[c];
    for (int t = 0; t < DM; ++t)
        acc = fmaf(pooled[b * DM + t], w_cls[t * NC + c], acc);
    out[idx] = acc;
}

extern "C" void kernel_launch(void* const* d_in, const int* in_sizes, int n_in,
                              void* d_out, int out_size, void* d_ws, size_t ws_size,
                              hipStream_t stream) {
    const float* x      = (const float*)d_in[0];
    const float* w_proj = (const float*)d_in[1];
    const float* b_proj = (const float*)d_in[2];
    const float* rms_w  = (const float*)d_in[3];
    const float* w_in   = (const float*)d_in[4];
    const float* conv_w = (const float*)d_in[5];
    const float* conv_b = (const float*)d_in[6];
    const float* w_xprj = (const float*)d_in[7];
    const float* w_dt   = (const float*)d_in[8];
    const float* b_dt   = (const float*)d_in[9];
    const float* A_log  = (const float*)d_in[10];
    const float* Dvec   = (const float*)d_in[11];
    const float* w_out  = (const float*)d_in[12];
    const float* w_cls  = (const float*)d_in[13];
    const float* b_cls  = (const float*)d_in[14];
    float* out = (float*)d_out;

    float* ws = (float*)d_ws;
    float* h0     = ws;
    float* xn     = h0 + (size_t)BT * DM;          // holds xn_pk (uint)
    float* xr     = xn + (size_t)BT * DM;
    float* xpT    = xr + (size_t)BT * 2 * DI;
    float* resT   = xpT + (size_t)Bb * DI * Tt;
    float* xdbl   = resT + (size_t)Bb * DI * Tt;
    float* pooled = xdbl + (size_t)BT * 96;
    float* wsplit = pooled + 4096;                 // weight-split scratch
    float* deltaT = xr;                            // alias: xr dead after conv_tr
    uint_t* y_pk  = (uint_t*)(xr + (size_t)Bb * DI * Tt);  // upper half of xr
    uint_t* xn_pk = (uint_t*)xn;

    // weight splits (bf16 hi/lo, transposed to [n][k]) — all own scratch:
    ushort_t* w_in_hi  = (ushort_t*)wsplit;
    ushort_t* w_in_lo  = w_in_hi + (size_t)(2 * DI) * DM;
    ushort_t* w_out_hi = w_in_lo + (size_t)(2 * DI) * DM;
    ushort_t* w_out_lo = w_out_hi + (size_t)DM * DI;

    // 0) split+transpose w_in; fused zero of xdbl+pooled (contiguous region)
    split_tr_kernel<<<dim3(2 * DI / 32, DM / 32), 256, 0, stream>>>(
        w_in, w_in_hi, w_in_lo, DM, 2 * DI,
        (float4*)xdbl, (BT * 96 + 4096) / 4);
    // 0b) split+transpose w_out (no zero)
    split_tr_kernel<<<dim3(DM / 32, DI / 32), 256, 0, stream>>>(
        w_out, w_out_hi, w_out_lo, DI, DM, nullptr, 0);
    // 1) h0 = x @ w_proj + b_proj
    gemm64<1,0><<<dim3(DM / 64, BT / 64), 256, 0, stream>>>(
        x, NM, w_proj, b_proj, h0, BT, DM, NM);
    // 2) xn_pk = pack(rmsnorm(h0) * rms_w); pooled += rowsum(h0)/DM
    rms_kernel<<<BT, 256, 0, stream>>>(h0, rms_w, xn_pk, pooled);
    // 3) xr = xn @ w_in    (split-bf16 MFMA, 8-wave blocks)
    gemm_mfma_big<<<dim3(2 * DI / 128, BT / 128), 512, 0, stream>>>(
        xn_pk, DM, w_in_hi, w_in_lo, xr, 2 * DI, DM);
    // 4) xpT = silu(causal_dwconv(xr[:, :DI]))^T ; resT = xr[:, DI:]^T
    conv_tr_kernel<<<dim3(DI / 64, Tt / 64, Bb), 256, 0, stream>>>(
        xr, conv_w, conv_b, xpT, resT);
    // 5) xdbl += xp @ w_xproj   (split-K=4, atomic accumulate)
    gemm_at_sk<4><<<dim3(2, BT / 64, 4), 256, 0, stream>>>(
        xpT, w_xprj, xdbl, 96, DI);
    // 6) deltaT = softplus(dt @ w_dt + b_dt)^T
    gemm64<2,1><<<dim3(DI / 64, BT / 64), 256, 0, stream>>>(
        xdbl, 96, w_dt, b_dt, deltaT, BT, DI, DR);
    // 7) fused single-pass selective scan (h in registers across chunks)
    scan_fused<<<Bb * (DI / 8), 256, 0, stream>>>(
        deltaT, xdbl, xpT, resT, A_log, Dvec, y_pk);
    // 8) pooled += rowsum(y @ w_out)/DM   (MFMA + split-K=4 + fused mean-pool)
    gemm_mfma_pool<<<dim3(DM / 64, BT / 64, 4), 256, 0, stream>>>(
        y_pk, DI, w_out_hi, w_out_lo, pooled, 1.0f / DM, DM, DI, DI / 4);
    // 9) out = pooled @ w_cls + b_cls
    cls_kernel<<<(Bb * NC + 255) / 256, 256, 0, stream>>>(pooled, w_cls, b_cls, out);
}

// Round 15
// 258.318 us; speedup vs baseline: 1.4415x; 1.1161x over previous
//
#include <hip/hip_runtime.h>
#include <hip/hip_bf16.h>
#include <cstddef>

#define Bb 8
#define Tt 512
#define NM 128
#define DM 512
#define DI 1024
#define DS 32
#define DR 32
#define DC 4
#define NC 100
#define BT (Bb*Tt)     // 4096
#define NCH 8          // scan chunks
#define CL  64         // chunk length

typedef unsigned short ushort_t;
typedef unsigned int uint_t;
typedef __attribute__((ext_vector_type(8))) short bf8;    // 8 bf16 in 4 VGPRs
typedef __attribute__((ext_vector_type(4))) float f4;

__device__ __forceinline__ float softplus_f(float x) {
    return fmaxf(x, 0.f) + log1pf(expf(-fabsf(x)));
}
__device__ __forceinline__ float silu_fast(float x) {
    return __fdividef(x, 1.f + __expf(-x));
}
__device__ __forceinline__ ushort_t bf16_rne(float x) {
    uint_t u = __float_as_uint(x);
    uint_t r = u + 0x7FFFu + ((u >> 16) & 1u);
    return (ushort_t)(r >> 16);
}
__device__ __forceinline__ float bf16_tof(ushort_t h) {
    return __uint_as_float(((uint_t)h) << 16);
}
// pack fp32 -> {hi bf16 in [31:16], lo bf16 in [15:0]}
__device__ __forceinline__ uint_t packf(float v) {
    ushort_t h = bf16_rne(v);
    ushort_t l = bf16_rne(v - bf16_tof(h));
    return ((uint_t)h << 16) | (uint_t)l;
}
// cross-lane: quad_perm DPP (VALU pipe) and ds_swizzle (DS pipe)
template<int CTRL>
__device__ __forceinline__ float qperm(float x) {
    return __int_as_float(__builtin_amdgcn_mov_dpp(__float_as_int(x), CTRL, 0xF, 0xF, true));
}
template<int PAT>
__device__ __forceinline__ float swz(float x) {
    return __int_as_float(__builtin_amdgcn_ds_swizzle(__float_as_int(x), PAT));
}

// ---- split fp32 (K,N) row-major into bf16 hi/lo, TRANSPOSED to (N,K) --------
// Optionally zeroes zcount float4s at zbase (fused init, saves a launch).
__global__ __launch_bounds__(256) void split_tr_kernel(
    const float* __restrict__ src, ushort_t* __restrict__ hi,
    ushort_t* __restrict__ lo, int K, int N,
    float4* __restrict__ zbase, int zcount)
{
    __shared__ ushort_t th[32][34], tl[32][34];
    const int k0 = blockIdx.y * 32, n0 = blockIdx.x * 32;
    if (zbase) {
        const int zi = (blockIdx.y * gridDim.x + blockIdx.x) * 256 + threadIdx.x;
        if (zi < zcount) zbase[zi] = make_float4(0.f, 0.f, 0.f, 0.f);
    }
    #pragma unroll
    for (int it = 0; it < 4; ++it) {
        const int idx = it * 256 + threadIdx.x;
        const int r = idx >> 5, c = idx & 31;
        const float v = src[(size_t)(k0 + r) * N + n0 + c];
        const ushort_t h = bf16_rne(v);
        th[c][r] = h;
        tl[c][r] = bf16_rne(v - bf16_tof(h));
    }
    __syncthreads();
    #pragma unroll
    for (int it = 0; it < 4; ++it) {
        const int idx = it * 256 + threadIdx.x;
        const int r = idx >> 5, c = idx & 31;
        hi[(size_t)(n0 + r) * K + k0 + c] = th[r][c];
        lo[(size_t)(n0 + r) * K + k0 + c] = tl[r][c];
    }
}

// ---- split-bf16 MFMA GEMM, 512 thr / 8 waves, 128x128 tile, bf16 C write ----
__global__ __launch_bounds__(512) void gemm_mfma_big(
    const uint_t* __restrict__ Apk, int lda,
    const ushort_t* __restrict__ Bhi, const ushort_t* __restrict__ Blo,
    ushort_t* __restrict__ C, int N, int K)
{
    constexpr int BM = 128, BN = 128;
    constexpr int FM = 2, FN = 4;         // wave tile 32x64
    __shared__ ushort_t sA[2][BM][40];
    __shared__ ushort_t sB[2][BN][40];
    const int tid = threadIdx.x;
    const int wid = tid >> 6, l = tid & 63, l15 = l & 15, g = l >> 4;
    const int wm = (wid >> 1) * 32, wn = (wid & 1) * 64;
    const int bm0 = blockIdx.y * BM, bn0 = blockIdx.x * BN;

    f4 acc[FM][FN] = {};
    uint4 aR[2], bRh, bRl;

    auto loadG = [&](int k0) {
        #pragma unroll
        for (int r = 0; r < 2; ++r) {
            const int idx = r * 2048 + tid * 4;
            const int m = idx >> 5, k = idx & 31;
            aR[r] = *(const uint4*)(Apk + (size_t)(bm0 + m) * lda + k0 + k);
        }
        {
            const int idx = tid * 8;
            const int n = idx >> 5, k = idx & 31;
            const size_t o = (size_t)(bn0 + n) * K + k0 + k;
            bRh = *(const uint4*)(Bhi + o);
            bRl = *(const uint4*)(Blo + o);
        }
    };
    auto stoL = [&]() {
        #pragma unroll
        for (int r = 0; r < 2; ++r) {
            const int idx = r * 2048 + tid * 4;
            const int m = idx >> 5, k = idx & 31;
            const uint_t u0 = aR[r].x, u1 = aR[r].y, u2 = aR[r].z, u3 = aR[r].w;
            uint2 hh, ll;
            hh.x = (u0 >> 16) | (u1 & 0xFFFF0000u);
            hh.y = (u2 >> 16) | (u3 & 0xFFFF0000u);
            ll.x = (u0 & 0xFFFFu) | (u1 << 16);
            ll.y = (u2 & 0xFFFFu) | (u3 << 16);
            *(uint2*)&sA[0][m][k] = hh;
            *(uint2*)&sA[1][m][k] = ll;
        }
        {
            const int idx = tid * 8;
            const int n = idx >> 5, k = idx & 31;
            *(uint4*)&sB[0][n][k] = bRh;
            *(uint4*)&sB[1][n][k] = bRl;
        }
    };

    loadG(0);
    for (int k0 = 0; k0 < K; k0 += 32) {
        stoL();
        __syncthreads();
        if (k0 + 32 < K) loadG(k0 + 32);
        bf8 ah[FM], al_[FM], bh[FN], bl_[FN];
        #pragma unroll
        for (int i = 0; i < FM; ++i) {
            ah[i]  = *(bf8*)&sA[0][wm + i * 16 + l15][g * 8];
            al_[i] = *(bf8*)&sA[1][wm + i * 16 + l15][g * 8];
        }
        #pragma unroll
        for (int j = 0; j < FN; ++j) {
            bh[j]  = *(bf8*)&sB[0][wn + j * 16 + l15][g * 8];
            bl_[j] = *(bf8*)&sB[1][wn + j * 16 + l15][g * 8];
        }
        #pragma unroll
        for (int i = 0; i < FM; ++i)
            #pragma unroll
            for (int j = 0; j < FN; ++j)
                acc[i][j] = __builtin_amdgcn_mfma_f32_16x16x32_bf16(ah[i], bh[j], acc[i][j], 0, 0, 0);
        #pragma unroll
        for (int i = 0; i < FM; ++i)
            #pragma unroll
            for (int j = 0; j < FN; ++j)
                acc[i][j] = __builtin_amdgcn_mfma_f32_16x16x32_bf16(al_[i], bh[j], acc[i][j], 0, 0, 0);
        #pragma unroll
        for (int i = 0; i < FM; ++i)
            #pragma unroll
            for (int j = 0; j < FN; ++j)
                acc[i][j] = __builtin_amdgcn_mfma_f32_16x16x32_bf16(ah[i], bl_[j], acc[i][j], 0, 0, 0);
        __syncthreads();
    }
    #pragma unroll
    for (int i = 0; i < FM; ++i)
        #pragma unroll
        for (int j = 0; j < FN; ++j)
            #pragma unroll
            for (int r = 0; r < 4; ++r) {
                const int m = bm0 + wm + i * 16 + g * 4 + r;
                const int n = bn0 + wn + j * 16 + l15;
                C[(size_t)m * N + n] = bf16_rne(acc[i][j][r]);
            }
}

// ---- step5: xdbl += xp_bf @ w_xproj  (A bf16 single plane, B split hi/lo) ---
// BM=64, BN=96, 4 waves (2x2, wave tile 32x48), split-K with atomics.
__global__ __launch_bounds__(256) void gemm_mfma_x(
    const ushort_t* __restrict__ Abf,
    const ushort_t* __restrict__ Bhi, const ushort_t* __restrict__ Blo,
    float* __restrict__ C, int K, int kseg)
{
    constexpr int BM = 64, BN = 96;
    constexpr int FM = 2, FN = 3;
    __shared__ ushort_t sAx[BM][40];
    __shared__ ushort_t sBx[2][BN][40];
    const int tid = threadIdx.x;
    const int wid = tid >> 6, l = tid & 63, l15 = l & 15, g = l >> 4;
    const int wm = (wid >> 1) * 32, wn = (wid & 1) * 48;
    const int bm0 = blockIdx.y * BM;
    const int kbeg = blockIdx.z * kseg;

    f4 acc[FM][FN] = {};
    uint4 aR;
    uint2 bRh[3], bRl[3];

    auto loadG = [&](int k0) {
        {
            const int idx = tid * 8;
            const int m = idx >> 5, k = idx & 31;
            aR = *(const uint4*)(Abf + (size_t)(bm0 + m) * K + k0 + k);
        }
        #pragma unroll
        for (int r = 0; r < 3; ++r) {
            const int idx = r * 1024 + tid * 4;
            const int n = idx >> 5, k = idx & 31;
            const size_t o = (size_t)n * K + k0 + k;
            bRh[r] = *(const uint2*)(Bhi + o);
            bRl[r] = *(const uint2*)(Blo + o);
        }
    };
    auto stoL = [&]() {
        {
            const int idx = tid * 8;
            const int m = idx >> 5, k = idx & 31;
            *(uint4*)&sAx[m][k] = aR;
        }
        #pragma unroll
        for (int r = 0; r < 3; ++r) {
            const int idx = r * 1024 + tid * 4;
            const int n = idx >> 5, k = idx & 31;
            *(uint2*)&sBx[0][n][k] = bRh[r];
            *(uint2*)&sBx[1][n][k] = bRl[r];
        }
    };

    loadG(kbeg);
    for (int k0 = kbeg; k0 < kbeg + kseg; k0 += 32) {
        stoL();
        __syncthreads();
        if (k0 + 32 < kbeg + kseg) loadG(k0 + 32);
        bf8 ah[FM], bh[FN], bl_[FN];
        #pragma unroll
        for (int i = 0; i < FM; ++i)
            ah[i] = *(bf8*)&sAx[wm + i * 16 + l15][g * 8];
        #pragma unroll
        for (int j = 0; j < FN; ++j) {
            bh[j]  = *(bf8*)&sBx[0][wn + j * 16 + l15][g * 8];
            bl_[j] = *(bf8*)&sBx[1][wn + j * 16 + l15][g * 8];
        }
        #pragma unroll
        for (int i = 0; i < FM; ++i)
            #pragma unroll
            for (int j = 0; j < FN; ++j)
                acc[i][j] = __builtin_amdgcn_mfma_f32_16x16x32_bf16(ah[i], bh[j], acc[i][j], 0, 0, 0);
        #pragma unroll
        for (int i = 0; i < FM; ++i)
            #pragma unroll
            for (int j = 0; j < FN; ++j)
                acc[i][j] = __builtin_amdgcn_mfma_f32_16x16x32_bf16(ah[i], bl_[j], acc[i][j], 0, 0, 0);
        __syncthreads();
    }
    #pragma unroll
    for (int i = 0; i < FM; ++i)
        #pragma unroll
        for (int j = 0; j < FN; ++j)
            #pragma unroll
            for (int r = 0; r < 4; ++r) {
                const int m = bm0 + wm + i * 16 + g * 4 + r;
                const int n = wn + j * 16 + l15;
                unsafeAtomicAdd(&C[(size_t)m * 96 + n], acc[i][j][r]);
            }
}

// ---- split-bf16 MFMA GEMM, 64x64 tile, split-K, fused mean-pool -------------
__global__ __launch_bounds__(256) void gemm_mfma_pool(
    const uint_t* __restrict__ Apk, int lda,
    const ushort_t* __restrict__ Bhi, const ushort_t* __restrict__ Blo,
    float* __restrict__ pooled, float pscale,
    int N, int K, int kseg)
{
    constexpr int BM = 64, BN = 64;
    constexpr int FM = 2, FN = 2;
    __shared__ ushort_t sA[2][BM][40];
    __shared__ ushort_t sB[2][BN][40];
    const int tid = threadIdx.x;
    const int wid = tid >> 6, l = tid & 63, l15 = l & 15, g = l >> 4;
    const int wm = (wid >> 1) * 32, wn = (wid & 1) * 32;
    const int bm0 = blockIdx.y * BM, bn0 = blockIdx.x * BN;
    const int kbeg = blockIdx.z * kseg;

    f4 acc[FM][FN] = {};
    uint4 aR[2], bRh, bRl;

    auto loadG = [&](int k0) {
        #pragma unroll
        for (int r = 0; r < 2; ++r) {
            const int idx = r * 1024 + tid * 4;
            const int m = idx >> 5, k = idx & 31;
            aR[r] = *(const uint4*)(Apk + (size_t)(bm0 + m) * lda + k0 + k);
        }
        {
            const int idx = tid * 8;
            const int n = idx >> 5, k = idx & 31;
            const size_t o = (size_t)(bn0 + n) * K + k0 + k;
            bRh = *(const uint4*)(Bhi + o);
            bRl = *(const uint4*)(Blo + o);
        }
    };
    auto stoL = [&]() {
        #pragma unroll
        for (int r = 0; r < 2; ++r) {
            const int idx = r * 1024 + tid * 4;
            const int m = idx >> 5, k = idx & 31;
            const uint_t u0 = aR[r].x, u1 = aR[r].y, u2 = aR[r].z, u3 = aR[r].w;
            uint2 hh, ll;
            hh.x = (u0 >> 16) | (u1 & 0xFFFF0000u);
            hh.y = (u2 >> 16) | (u3 & 0xFFFF0000u);
            ll.x = (u0 & 0xFFFFu) | (u1 << 16);
            ll.y = (u2 & 0xFFFFu) | (u3 << 16);
            *(uint2*)&sA[0][m][k] = hh;
            *(uint2*)&sA[1][m][k] = ll;
        }
        {
            const int idx = tid * 8;
            const int n = idx >> 5, k = idx & 31;
            *(uint4*)&sB[0][n][k] = bRh;
            *(uint4*)&sB[1][n][k] = bRl;
        }
    };

    loadG(kbeg);
    for (int k0 = kbeg; k0 < kbeg + kseg; k0 += 32) {
        stoL();
        __syncthreads();
        if (k0 + 32 < kbeg + kseg) loadG(k0 + 32);
        bf8 ah[FM], al_[FM], bh[FN], bl_[FN];
        #pragma unroll
        for (int i = 0; i < FM; ++i) {
            ah[i]  = *(bf8*)&sA[0][wm + i * 16 + l15][g * 8];
            al_[i] = *(bf8*)&sA[1][wm + i * 16 + l15][g * 8];
        }
        #pragma unroll
        for (int j = 0; j < FN; ++j) {
            bh[j]  = *(bf8*)&sB[0][wn + j * 16 + l15][g * 8];
            bl_[j] = *(bf8*)&sB[1][wn + j * 16 + l15][g * 8];
        }
        #pragma unroll
        for (int i = 0; i < FM; ++i)
            #pragma unroll
            for (int j = 0; j < FN; ++j)
                acc[i][j] = __builtin_amdgcn_mfma_f32_16x16x32_bf16(ah[i], bh[j], acc[i][j], 0, 0, 0);
        #pragma unroll
        for (int i = 0; i < FM; ++i)
            #pragma unroll
            for (int j = 0; j < FN; ++j)
                acc[i][j] = __builtin_amdgcn_mfma_f32_16x16x32_bf16(al_[i], bh[j], acc[i][j], 0, 0, 0);
        #pragma unroll
        for (int i = 0; i < FM; ++i)
            #pragma unroll
            for (int j = 0; j < FN; ++j)
                acc[i][j] = __builtin_amdgcn_mfma_f32_16x16x32_bf16(ah[i], bl_[j], acc[i][j], 0, 0, 0);
        __syncthreads();
    }
    #pragma unroll
    for (int i = 0; i < FM; ++i)
        #pragma unroll
        for (int r = 0; r < 4; ++r) {
            float sum = acc[i][0][r];
            #pragma unroll
            for (int j = 1; j < FN; ++j) sum += acc[i][j][r];
            sum += __shfl_xor(sum, 1);
            sum += __shfl_xor(sum, 2);
            sum += __shfl_xor(sum, 4);
            sum += __shfl_xor(sum, 8);
            if (l15 == 0)
                unsafeAtomicAdd(pooled + bm0 + wm + i * 16 + g * 4 + r, sum * pscale);
        }
}

// ---------------- generic 64x64 tiled fp32 GEMM: C = epi(A@B) -----------------
template<int EPI, int TSTORE>
__global__ __launch_bounds__(256) void gemm64(
    const float* __restrict__ A, int lda,
    const float* __restrict__ B,
    const float* __restrict__ bias,
    float* __restrict__ C,
    int M, int N, int K)
{
    __shared__ float As[16][68];
    __shared__ float Bs[16][64];
    const int tid = threadIdx.x;
    const int bm = blockIdx.y * 64;
    const int bn = blockIdx.x * 64;
    const int tx = tid & 15;
    const int ty = tid >> 4;
    const int la_m = tid >> 2;
    const int la_k = (tid & 3) << 2;
    const int lb_k = tid >> 4;
    const int lb_n = (tid & 15) << 2;

    float acc[4][4] = {};
    for (int k0 = 0; k0 < K; k0 += 16) {
        float4 av = *(const float4*)(A + (size_t)(bm + la_m) * lda + k0 + la_k);
        As[la_k + 0][la_m] = av.x;
        As[la_k + 1][la_m] = av.y;
        As[la_k + 2][la_m] = av.z;
        As[la_k + 3][la_m] = av.w;
        const int gn = bn + lb_n;
        const float* bp = B + (size_t)(k0 + lb_k) * N + gn;
        float4 bv = *(const float4*)bp;
        *(float4*)&Bs[lb_k][lb_n] = bv;
        __syncthreads();
        #pragma unroll
        for (int k = 0; k < 16; ++k) {
            float4 a = *(const float4*)&As[k][ty << 2];
            float4 b = *(const float4*)&Bs[k][tx << 2];
            float ar[4] = {a.x, a.y, a.z, a.w};
            float br[4] = {b.x, b.y, b.z, b.w};
            #pragma unroll
            for (int i = 0; i < 4; ++i)
                #pragma unroll
                for (int j = 0; j < 4; ++j)
                    acc[i][j] = fmaf(ar[i], br[j], acc[i][j]);
        }
        __syncthreads();
    }
    if (TSTORE == 0) {
        #pragma unroll
        for (int i = 0; i < 4; ++i) {
            const int gm = bm + (ty << 2) + i;
            #pragma unroll
            for (int j = 0; j < 4; ++j) {
                const int gn = bn + (tx << 2) + j;
                float v = acc[i][j];
                if (EPI == 1) v += bias[gn];
                else if (EPI == 2) v = softplus_f(v + bias[gn]);
                C[(size_t)gm * N + gn] = v;
            }
        }
    } else {
        const int bq = bm >> 9;
        const int tt0 = (bm & (Tt - 1)) + (ty << 2);
        #pragma unroll
        for (int j = 0; j < 4; ++j) {
            const int gn = bn + (tx << 2) + j;
            float4 v;
            float* vv = (float*)&v;
            #pragma unroll
            for (int i = 0; i < 4; ++i) {
                float t = acc[i][j];
                if (EPI == 2) t = softplus_f(t + bias[gn]);
                vv[i] = t;
            }
            *(float4*)(C + ((size_t)bq * N + gn) * Tt + tt0) = v;
        }
    }
}

// ------- RMSNorm: writes packed hi/lo bf16 xn; adds h0 row-sums to pooled -----
__global__ __launch_bounds__(256) void rms_kernel(
    const float* __restrict__ h0, const float* __restrict__ w,
    uint_t* __restrict__ xn_pk, float* __restrict__ pooled)
{
    const int row = blockIdx.x;
    const float* p = h0 + (size_t)row * DM;
    const int tid = threadIdx.x;
    float v0 = p[tid], v1 = p[tid + 256];
    float ss = v0 * v0 + v1 * v1;
    float sm = v0 + v1;
    #pragma unroll
    for (int m = 32; m; m >>= 1) {
        ss += __shfl_xor(ss, m);
        sm += __shfl_xor(sm, m);
    }
    __shared__ float wss[4], wsm[4];
    if ((tid & 63) == 0) { wss[tid >> 6] = ss; wsm[tid >> 6] = sm; }
    __syncthreads();
    const float tot = wss[0] + wss[1] + wss[2] + wss[3];
    if (tid == 0)
        unsafeAtomicAdd(pooled + row, (wsm[0] + wsm[1] + wsm[2] + wsm[3]) * (1.0f / DM));
    const float scale = rsqrtf(tot * (1.0f / DM) + 1e-5f);
    xn_pk[(size_t)row * DM + tid]       = packf(v0 * scale * w[tid]);
    xn_pk[(size_t)row * DM + tid + 256] = packf(v1 * scale * w[tid + 256]);
}

// -------- causal depthwise conv (DC=4) + SiLU, bf16 in / bf16 out, transposed -
__global__ __launch_bounds__(256) void conv_tr_kernel(
    const ushort_t* __restrict__ xr, const float* __restrict__ cw,
    const float* __restrict__ cb, ushort_t* __restrict__ xp_bf,
    ushort_t* __restrict__ res_bf)
{
    __shared__ float tp[64][65];
    __shared__ float tr[64][65];
    const int di0 = blockIdx.x * 64;
    const int t0  = blockIdx.y * 64;
    const int b   = blockIdx.z;
    const int c  = threadIdx.x & 63;
    const int r4 = threadIdx.x >> 6;
    const int di = di0 + c;
    const float bias = cb[di];
    float w0 = cw[di * DC + 0], w1 = cw[di * DC + 1],
          w2 = cw[di * DC + 2], w3 = cw[di * DC + 3];
    #pragma unroll
    for (int rr = 0; rr < 64; rr += 4) {
        const int t = t0 + rr + r4;
        const int bt = b * Tt + t;
        float acc = bias;
        if (t >= 3) {
            acc = fmaf(w0, bf16_tof(xr[(size_t)(bt - 3) * (2 * DI) + di]), acc);
            acc = fmaf(w1, bf16_tof(xr[(size_t)(bt - 2) * (2 * DI) + di]), acc);
            acc = fmaf(w2, bf16_tof(xr[(size_t)(bt - 1) * (2 * DI) + di]), acc);
        } else {
            if (t >= 1) acc = fmaf(w2, bf16_tof(xr[(size_t)(bt - 1) * (2 * DI) + di]), acc);
            if (t >= 2) acc = fmaf(w1, bf16_tof(xr[(size_t)(bt - 2) * (2 * DI) + di]), acc);
        }
        acc = fmaf(w3, bf16_tof(xr[(size_t)bt * (2 * DI) + di]), acc);
        tp[rr + r4][c] = silu_fast(acc);
        tr[rr + r4][c] = bf16_tof(xr[(size_t)bt * (2 * DI) + DI + di]);
    }
    __syncthreads();
    #pragma unroll
    for (int dd = 0; dd < 64; dd += 4) {
        const int dw = dd + r4;
        const size_t o = ((size_t)b * DI + di0 + dw) * Tt + t0 + c;
        xp_bf[o]  = bf16_rne(tp[c][dw]);
        res_bf[o] = bf16_rne(tr[c][dw]);
    }
}

// ============= fused single-pass selective scan (256 thr, 8 di/block) =========
__global__ __launch_bounds__(256) void scan_fused(
    const float* __restrict__ deltaT, const float* __restrict__ xdbl,
    const ushort_t* __restrict__ xp_bf, const ushort_t* __restrict__ res_bf,
    const float* __restrict__ A_log, const float* __restrict__ Dvec,
    uint_t* __restrict__ y_pk)
{
    __shared__ uint_t   sBC[2][DS][68];   // [buf][s][t]: {C bf16 hi | B bf16 lo}
    __shared__ float    sD [2][8][68];    // fp32 d (exponent path)
    __shared__ float    sDU[2][8][68];    // fp32 d*u
    __shared__ ushort_t sU [2][8][68];    // bf16 u (D-skip)
    __shared__ ushort_t sR [2][8][68];    // bf16 res (gate)
    __shared__ float ylds[CL][9];
    const int tid = threadIdx.x;
    const int grp = tid >> 5;            // 0..7 : di within block
    const int l5 = tid & 31;
    const int s = ((l5 & 1) << 4) | (l5 >> 1);   // lane remap: s^16 <-> l^1 (quad DPP)
    const int b = blockIdx.x >> 7;
    const int di0 = (blockIdx.x & 127) << 3;
    const int sd_r = tid >> 5;           // 0..7
    const int sd_t = (tid & 31) << 1;    // 0..62
    const int bc_t = tid >> 2;           // 0..63
    const int bc_s = (tid & 3) << 3;     // 0,8,16,24

    float2 rd2;
    uint_t ru, rr_;
    float4 rB[2], rC[2];
    auto stage_regs = [&](int c) {
        const size_t rb = ((size_t)(b * DI + di0 + sd_r)) * Tt + c * CL + sd_t;
        rd2 = *(const float2*)(deltaT + rb);
        ru  = *(const uint_t*)(xp_bf + rb);
        rr_ = *(const uint_t*)(res_bf + rb);
        const float* src = xdbl + ((size_t)b * Tt + c * CL + bc_t) * 96;
        rB[0] = *(const float4*)(src + 32 + bc_s);
        rB[1] = *(const float4*)(src + 32 + bc_s + 4);
        rC[0] = *(const float4*)(src + 64 + bc_s);
        rC[1] = *(const float4*)(src + 64 + bc_s + 4);
    };
    auto write_lds = [&](int bb) {
        *(float2*)&sD[bb][sd_r][sd_t] = rd2;
        const float u0 = bf16_tof((ushort_t)(ru & 0xFFFFu));
        const float u1 = bf16_tof((ushort_t)(ru >> 16));
        float2 du2;
        du2.x = rd2.x * u0;
        du2.y = rd2.y * u1;
        *(float2*)&sDU[bb][sd_r][sd_t] = du2;
        *(uint_t*)&sU[bb][sd_r][sd_t] = ru;
        *(uint_t*)&sR[bb][sd_r][sd_t] = rr_;
        const float bv[8] = {rB[0].x, rB[0].y, rB[0].z, rB[0].w,
                             rB[1].x, rB[1].y, rB[1].z, rB[1].w};
        const float cv[8] = {rC[0].x, rC[0].y, rC[0].z, rC[0].w,
                             rC[1].x, rC[1].y, rC[1].z, rC[1].w};
        #pragma unroll
        for (int j = 0; j < 8; ++j)
            sBC[bb][bc_s + j][bc_t] =
                ((uint_t)bf16_rne(cv[j]) << 16) | (uint_t)bf16_rne(bv[j]);
    };

    const bool s4b = (l5 & 1) != 0;
    const bool s0b = (l5 & 2) != 0;
    const bool s1b = (l5 & 4) != 0;
    const bool s2b = (l5 & 8) != 0;
    const bool s3b = (l5 & 16) != 0;
    const int di = di0 + grp;
    const float Ads2 = -expf(A_log[di * DS + s]) * 1.44269504f;
    const float Dv = Dvec[di];
    float h = 0.f;

    stage_regs(0);
    write_lds(0);
    #pragma unroll 1
    for (int c = 0; c < NCH; ++c) {
        const int bb = c & 1;
        __syncthreads();
        if (c < NCH - 1) stage_regs(c + 1);
        #pragma unroll 1
        for (int t0 = 0; t0 < CL; t0 += 32) {
            float buf[16] = {};
            uint4 bc_c = *(const uint4*)&sBC[bb][s][t0];
            float4 dv_c = *(const float4*)&sD[bb][grp][t0];
            float4 du_c = *(const float4*)&sDU[bb][grp][t0];
            #pragma unroll
            for (int tq = 0; tq < 8; ++tq) {
                uint4 bc_n;
                float4 dv_n, du_n;
                if (tq < 7) {
                    const int tb = t0 + tq * 4 + 4;
                    bc_n = *(const uint4*)&sBC[bb][s][tb];
                    dv_n = *(const float4*)&sD[bb][grp][tb];
                    du_n = *(const float4*)&sDU[bb][grp][tb];
                }
                const uint_t bcv[4] = {bc_c.x, bc_c.y, bc_c.z, bc_c.w};
                const float dv[4] = {dv_c.x, dv_c.y, dv_c.z, dv_c.w};
                const float duv[4] = {du_c.x, du_c.y, du_c.z, du_c.w};
                #pragma unroll
                for (int q = 0; q < 4; ++q) {
                    const int tl = tq * 4 + q;
                    const float Bq = __uint_as_float(bcv[q] << 16);
                    const float Cq = __uint_as_float(bcv[q] & 0xFFFF0000u);
                    h = fmaf(__builtin_amdgcn_exp2f(dv[q] * Ads2), h, duv[q] * Bq);
                    const float ps = h * Cq;
                    const float pr = ps + qperm<0xB1>(ps);
                    const bool keep = ((tl & 16) != 0) == s4b;
                    buf[tl & 15] = keep ? pr : buf[tl & 15];
                }
                if (tq < 7) { bc_c = bc_n; dv_c = dv_n; du_c = du_n; }
            }
            #pragma unroll
            for (int i = 0; i < 16; ++i) buf[i] += qperm<0x4E>(buf[i]);
            float r8[8];
            #pragma unroll
            for (int i = 0; i < 8; ++i) r8[i] = s0b ? buf[2 * i + 1] : buf[2 * i];
            #pragma unroll
            for (int i = 0; i < 8; ++i) r8[i] += swz<0x101F>(r8[i]);
            float w4[4];
            #pragma unroll
            for (int i = 0; i < 4; ++i) w4[i] = s1b ? r8[2 * i + 1] : r8[2 * i];
            #pragma unroll
            for (int i = 0; i < 4; ++i) w4[i] += swz<0x201F>(w4[i]);
            float v2[2];
            v2[0] = s2b ? w4[1] : w4[0];
            v2[1] = s2b ? w4[3] : w4[2];
            v2[0] += swz<0x401F>(v2[0]);
            v2[1] += swz<0x401F>(v2[1]);
            const float yv = s3b ? v2[1] : v2[0];
            const float uself = bf16_tof(sU[bb][grp][t0 + s]);
            const float rself = bf16_tof(sR[bb][grp][t0 + s]);
            ylds[t0 + s][grp] = fmaf(uself, Dv, yv) * silu_fast(rself);
        }
        __syncthreads();
        {
            const int row = tid >> 2;
            const int q2 = (tid & 3) << 1;
            uint2 o;
            o.x = packf(ylds[row][q2 + 0]);
            o.y = packf(ylds[row][q2 + 1]);
            *(uint2*)(y_pk + ((size_t)b * Tt + c * CL + row) * DI + di0 + q2) = o;
        }
        if (c < NCH - 1) write_lds(bb ^ 1);
    }
}

// ---------------- classifier ---------------------------------------------------
__global__ __launch_bounds__(256) void cls_kernel(
    const float* __restrict__ pooled, const float* __restrict__ w_cls,
    const float* __restrict__ b_cls, float* __restrict__ out)
{
    const int idx = blockIdx.x * 256 + threadIdx.x;
    if (idx >= Bb * NC) return;
    const int b = idx / NC, c = idx % NC;
    float acc = b_cls[c];
    for (int t = 0; t < DM; ++t)
        acc = fmaf(pooled[b * DM + t], w_cls[t * NC + c], acc);
    out[idx] = acc;
}

extern "C" void kernel_launch(void* const* d_in, const int* in_sizes, int n_in,
                              void* d_out, int out_size, void* d_ws, size_t ws_size,
                              hipStream_t stream) {
    const float* x      = (const float*)d_in[0];
    const float* w_proj = (const float*)d_in[1];
    const float* b_proj = (const float*)d_in[2];
    const float* rms_w  = (const float*)d_in[3];
    const float* w_in   = (const float*)d_in[4];
    const float* conv_w = (const float*)d_in[5];
    const float* conv_b = (const float*)d_in[6];
    const float* w_xprj = (const float*)d_in[7];
    const float* w_dt   = (const float*)d_in[8];
    const float* b_dt   = (const float*)d_in[9];
    const float* A_log  = (const float*)d_in[10];
    const float* Dvec   = (const float*)d_in[11];
    const float* w_out  = (const float*)d_in[12];
    const float* w_cls  = (const float*)d_in[13];
    const float* b_cls  = (const float*)d_in[14];
    float* out = (float*)d_out;

    float* ws = (float*)d_ws;
    float* h0     = ws;
    float* xn     = h0 + (size_t)BT * DM;          // holds xn_pk (uint)
    float* xr     = xn + (size_t)BT * DM;          // region reused: xr_bf16 -> deltaT
    float* xpT    = xr + (size_t)BT * 2 * DI;      // holds xp_bf (ushort)
    float* resT   = xpT + (size_t)Bb * DI * Tt;    // holds res_bf (ushort)
    float* xdbl   = resT + (size_t)Bb * DI * Tt;
    float* pooled = xdbl + (size_t)BT * 96;
    float* wsplit = pooled + 4096;                 // weight-split scratch
    float* deltaT = xr;                            // alias: xr_bf dead after conv_tr
    uint_t* y_pk  = (uint_t*)(xr + (size_t)Bb * DI * Tt);  // upper half of xr region
    uint_t* xn_pk = (uint_t*)xn;
    ushort_t* xr_bf  = (ushort_t*)xr;
    ushort_t* xp_bf  = (ushort_t*)xpT;
    ushort_t* res_bf = (ushort_t*)resT;

    // weight splits (bf16 hi/lo, transposed to [n][k]) — all own scratch:
    ushort_t* w_in_hi  = (ushort_t*)wsplit;
    ushort_t* w_in_lo  = w_in_hi + (size_t)(2 * DI) * DM;
    ushort_t* w_out_hi = w_in_lo + (size_t)(2 * DI) * DM;
    ushort_t* w_out_lo = w_out_hi + (size_t)DM * DI;
    ushort_t* w_xp_hi  = w_out_lo + (size_t)DM * DI;
    ushort_t* w_xp_lo  = w_xp_hi + (size_t)96 * DI;

    // 0) split+transpose w_in; fused zero of xdbl+pooled (contiguous region)
    split_tr_kernel<<<dim3(2 * DI / 32, DM / 32), 256, 0, stream>>>(
        w_in, w_in_hi, w_in_lo, DM, 2 * DI,
        (float4*)xdbl, (BT * 96 + 4096) / 4);
    // 0b) split+transpose w_out
    split_tr_kernel<<<dim3(DM / 32, DI / 32), 256, 0, stream>>>(
        w_out, w_out_hi, w_out_lo, DI, DM, nullptr, 0);
    // 0c) split+transpose w_xproj (1024,96) -> [96][1024]
    split_tr_kernel<<<dim3(96 / 32, DI / 32), 256, 0, stream>>>(
        w_xprj, w_xp_hi, w_xp_lo, DI, 96, nullptr, 0);
    // 1) h0 = x @ w_proj + b_proj
    gemm64<1,0><<<dim3(DM / 64, BT / 64), 256, 0, stream>>>(
        x, NM, w_proj, b_proj, h0, BT, DM, NM);
    // 2) xn_pk = pack(rmsnorm(h0) * rms_w); pooled += rowsum(h0)/DM
    rms_kernel<<<BT, 256, 0, stream>>>(h0, rms_w, xn_pk, pooled);
    // 3) xr_bf = bf16(xn @ w_in)    (split-bf16 MFMA, 8-wave blocks)
    gemm_mfma_big<<<dim3(2 * DI / 128, BT / 128), 512, 0, stream>>>(
        xn_pk, DM, w_in_hi, w_in_lo, xr_bf, 2 * DI, DM);
    // 4) xp_bf = bf16(silu(causal_dwconv(xr[:, :DI])))^T ; res_bf = xr[:, DI:]^T
    conv_tr_kernel<<<dim3(DI / 64, Tt / 64, Bb), 256, 0, stream>>>(
        xr_bf, conv_w, conv_b, xp_bf, res_bf);
    // 5) xdbl += xp @ w_xproj   (bf16-A MFMA, split-K=8, atomics)
    gemm_mfma_x<<<dim3(1, BT / 64, 8), 256, 0, stream>>>(
        xp_bf, w_xp_hi, w_xp_lo, xdbl, DI, DI / 8);
    // 6) deltaT = softplus(dt @ w_dt + b_dt)^T
    gemm64<2,1><<<dim3(DI / 64, BT / 64), 256, 0, stream>>>(
        xdbl, 96, w_dt, b_dt, deltaT, BT, DI, DR);
    // 7) fused single-pass selective scan (h in registers across chunks)
    scan_fused<<<Bb * (DI / 8), 256, 0, stream>>>(
        deltaT, xdbl, xp_bf, res_bf, A_log, Dvec, y_pk);
    // 8) pooled += rowsum(y @ w_out)/DM   (MFMA + split-K=4 + fused mean-pool)
    gemm_mfma_pool<<<dim3(DM / 64, BT / 64, 4), 256, 0, stream>>>(
        y_pk, DI, w_out_hi, w_out_lo, pooled, 1.0f / DM, DM, DI, DI / 4);
    // 9) out = pooled @ w_cls + b_cls
    cls_kernel<<<(Bb * NC + 255) / 256, 256, 0, stream>>>(pooled, w_cls, b_cls, out);
}

// Round 16
// 242.462 us; speedup vs baseline: 1.5358x; 1.0654x over previous
//
#include <hip/hip_runtime.h>
#include <hip/hip_bf16.h>
#include <cstddef>

#define Bb 8
#define Tt 512
#define NM 128
#define DM 512
#define DI 1024
#define DS 32
#define DR 32
#define DC 4
#define NC 100
#define BT (Bb*Tt)     // 4096
#define NCH 8          // scan chunks
#define CL  64         // chunk length

typedef unsigned short ushort_t;
typedef unsigned int uint_t;
typedef __attribute__((ext_vector_type(8))) short bf8;    // 8 bf16 in 4 VGPRs
typedef __attribute__((ext_vector_type(4))) float f4;

__device__ __forceinline__ float softplus_f(float x) {
    return fmaxf(x, 0.f) + log1pf(expf(-fabsf(x)));
}
__device__ __forceinline__ float silu_fast(float x) {
    return __fdividef(x, 1.f + __expf(-x));
}
__device__ __forceinline__ ushort_t bf16_rne(float x) {
    uint_t u = __float_as_uint(x);
    uint_t r = u + 0x7FFFu + ((u >> 16) & 1u);
    return (ushort_t)(r >> 16);
}
__device__ __forceinline__ float bf16_tof(ushort_t h) {
    return __uint_as_float(((uint_t)h) << 16);
}
// pack fp32 -> {hi bf16 in [31:16], lo bf16 in [15:0]}
__device__ __forceinline__ uint_t packf(float v) {
    ushort_t h = bf16_rne(v);
    ushort_t l = bf16_rne(v - bf16_tof(h));
    return ((uint_t)h << 16) | (uint_t)l;
}
// cross-lane: quad_perm DPP (VALU pipe) and ds_swizzle (DS pipe)
template<int CTRL>
__device__ __forceinline__ float qperm(float x) {
    return __int_as_float(__builtin_amdgcn_mov_dpp(__float_as_int(x), CTRL, 0xF, 0xF, true));
}
template<int PAT>
__device__ __forceinline__ float swz(float x) {
    return __int_as_float(__builtin_amdgcn_ds_swizzle(__float_as_int(x), PAT));
}

// ---- split fp32 (K,N) row-major into bf16 hi/lo, TRANSPOSED to (N,K) --------
// Optionally zeroes zcount float4s at zbase (fused init, saves a launch).
__global__ __launch_bounds__(256) void split_tr_kernel(
    const float* __restrict__ src, ushort_t* __restrict__ hi,
    ushort_t* __restrict__ lo, int K, int N,
    float4* __restrict__ zbase, int zcount)
{
    __shared__ ushort_t th[32][34], tl[32][34];
    const int k0 = blockIdx.y * 32, n0 = blockIdx.x * 32;
    if (zbase) {
        const int zi = (blockIdx.y * gridDim.x + blockIdx.x) * 256 + threadIdx.x;
        if (zi < zcount) zbase[zi] = make_float4(0.f, 0.f, 0.f, 0.f);
    }
    #pragma unroll
    for (int it = 0; it < 4; ++it) {
        const int idx = it * 256 + threadIdx.x;
        const int r = idx >> 5, c = idx & 31;
        const float v = src[(size_t)(k0 + r) * N + n0 + c];
        const ushort_t h = bf16_rne(v);
        th[c][r] = h;
        tl[c][r] = bf16_rne(v - bf16_tof(h));
    }
    __syncthreads();
    #pragma unroll
    for (int it = 0; it < 4; ++it) {
        const int idx = it * 256 + threadIdx.x;
        const int r = idx >> 5, c = idx & 31;
        hi[(size_t)(n0 + r) * K + k0 + c] = th[r][c];
        lo[(size_t)(n0 + r) * K + k0 + c] = tl[r][c];
    }
}

// ---- single-pass bf16 MFMA GEMM, 512 thr / 8 waves, 128x128 tile, bf16 C ----
// A packed {hi,lo} uint (M,K): hi plane used. B: hi plane only, (N,K).
__global__ __launch_bounds__(512) void gemm_mfma_big(
    const uint_t* __restrict__ Apk, int lda,
    const ushort_t* __restrict__ Bhi,
    ushort_t* __restrict__ C, int N, int K)
{
    constexpr int BM = 128, BN = 128;
    constexpr int FM = 2, FN = 4;         // wave tile 32x64
    __shared__ ushort_t sA[BM][40];
    __shared__ ushort_t sB[BN][40];
    const int tid = threadIdx.x;
    const int wid = tid >> 6, l = tid & 63, l15 = l & 15, g = l >> 4;
    const int wm = (wid >> 1) * 32, wn = (wid & 1) * 64;
    const int bm0 = blockIdx.y * BM, bn0 = blockIdx.x * BN;

    f4 acc[FM][FN] = {};
    uint4 aR[2], bRh;

    auto loadG = [&](int k0) {
        #pragma unroll
        for (int r = 0; r < 2; ++r) {
            const int idx = r * 2048 + tid * 4;
            const int m = idx >> 5, k = idx & 31;
            aR[r] = *(const uint4*)(Apk + (size_t)(bm0 + m) * lda + k0 + k);
        }
        {
            const int idx = tid * 8;
            const int n = idx >> 5, k = idx & 31;
            bRh = *(const uint4*)(Bhi + (size_t)(bn0 + n) * K + k0 + k);
        }
    };
    auto stoL = [&]() {
        #pragma unroll
        for (int r = 0; r < 2; ++r) {
            const int idx = r * 2048 + tid * 4;
            const int m = idx >> 5, k = idx & 31;
            uint2 hh;
            hh.x = (aR[r].x >> 16) | (aR[r].y & 0xFFFF0000u);
            hh.y = (aR[r].z >> 16) | (aR[r].w & 0xFFFF0000u);
            *(uint2*)&sA[m][k] = hh;
        }
        {
            const int idx = tid * 8;
            const int n = idx >> 5, k = idx & 31;
            *(uint4*)&sB[n][k] = bRh;
        }
    };

    loadG(0);
    for (int k0 = 0; k0 < K; k0 += 32) {
        stoL();
        __syncthreads();
        if (k0 + 32 < K) loadG(k0 + 32);
        bf8 ah[FM], bh[FN];
        #pragma unroll
        for (int i = 0; i < FM; ++i)
            ah[i] = *(bf8*)&sA[wm + i * 16 + l15][g * 8];
        #pragma unroll
        for (int j = 0; j < FN; ++j)
            bh[j] = *(bf8*)&sB[wn + j * 16 + l15][g * 8];
        #pragma unroll
        for (int i = 0; i < FM; ++i)
            #pragma unroll
            for (int j = 0; j < FN; ++j)
                acc[i][j] = __builtin_amdgcn_mfma_f32_16x16x32_bf16(ah[i], bh[j], acc[i][j], 0, 0, 0);
        __syncthreads();
    }
    #pragma unroll
    for (int i = 0; i < FM; ++i)
        #pragma unroll
        for (int j = 0; j < FN; ++j)
            #pragma unroll
            for (int r = 0; r < 4; ++r) {
                const int m = bm0 + wm + i * 16 + g * 4 + r;
                const int n = bn0 + wn + j * 16 + l15;
                C[(size_t)m * N + n] = bf16_rne(acc[i][j][r]);
            }
}

// ---- step5: xdbl += xp_bf @ w_xproj  (single-pass bf16, split-K atomics) ----
__global__ __launch_bounds__(256) void gemm_mfma_x(
    const ushort_t* __restrict__ Abf,
    const ushort_t* __restrict__ Bhi,
    float* __restrict__ C, int K, int kseg)
{
    constexpr int BM = 64, BN = 96;
    constexpr int FM = 2, FN = 3;
    __shared__ ushort_t sAx[BM][40];
    __shared__ ushort_t sBx[BN][40];
    const int tid = threadIdx.x;
    const int wid = tid >> 6, l = tid & 63, l15 = l & 15, g = l >> 4;
    const int wm = (wid >> 1) * 32, wn = (wid & 1) * 48;
    const int bm0 = blockIdx.y * BM;
    const int kbeg = blockIdx.z * kseg;

    f4 acc[FM][FN] = {};
    uint4 aR;
    uint2 bRh[3];

    auto loadG = [&](int k0) {
        {
            const int idx = tid * 8;
            const int m = idx >> 5, k = idx & 31;
            aR = *(const uint4*)(Abf + (size_t)(bm0 + m) * K + k0 + k);
        }
        #pragma unroll
        for (int r = 0; r < 3; ++r) {
            const int idx = r * 1024 + tid * 4;
            const int n = idx >> 5, k = idx & 31;
            bRh[r] = *(const uint2*)(Bhi + (size_t)n * K + k0 + k);
        }
    };
    auto stoL = [&]() {
        {
            const int idx = tid * 8;
            const int m = idx >> 5, k = idx & 31;
            *(uint4*)&sAx[m][k] = aR;
        }
        #pragma unroll
        for (int r = 0; r < 3; ++r) {
            const int idx = r * 1024 + tid * 4;
            const int n = idx >> 5, k = idx & 31;
            *(uint2*)&sBx[n][k] = bRh[r];
        }
    };

    loadG(kbeg);
    for (int k0 = kbeg; k0 < kbeg + kseg; k0 += 32) {
        stoL();
        __syncthreads();
        if (k0 + 32 < kbeg + kseg) loadG(k0 + 32);
        bf8 ah[FM], bh[FN];
        #pragma unroll
        for (int i = 0; i < FM; ++i)
            ah[i] = *(bf8*)&sAx[wm + i * 16 + l15][g * 8];
        #pragma unroll
        for (int j = 0; j < FN; ++j)
            bh[j] = *(bf8*)&sBx[wn + j * 16 + l15][g * 8];
        #pragma unroll
        for (int i = 0; i < FM; ++i)
            #pragma unroll
            for (int j = 0; j < FN; ++j)
                acc[i][j] = __builtin_amdgcn_mfma_f32_16x16x32_bf16(ah[i], bh[j], acc[i][j], 0, 0, 0);
        __syncthreads();
    }
    #pragma unroll
    for (int i = 0; i < FM; ++i)
        #pragma unroll
        for (int j = 0; j < FN; ++j)
            #pragma unroll
            for (int r = 0; r < 4; ++r) {
                const int m = bm0 + wm + i * 16 + g * 4 + r;
                const int n = wn + j * 16 + l15;
                unsafeAtomicAdd(&C[(size_t)m * 96 + n], acc[i][j][r]);
            }
}

// ---- 2-pass MFMA GEMM (A hi+lo, B hi), 64x64 tile, split-K, fused mean-pool -
__global__ __launch_bounds__(256) void gemm_mfma_pool(
    const uint_t* __restrict__ Apk, int lda,
    const ushort_t* __restrict__ Bhi,
    float* __restrict__ pooled, float pscale,
    int N, int K, int kseg)
{
    constexpr int BM = 64, BN = 64;
    constexpr int FM = 2, FN = 2;
    __shared__ ushort_t sA[2][BM][40];
    __shared__ ushort_t sB[BN][40];
    const int tid = threadIdx.x;
    const int wid = tid >> 6, l = tid & 63, l15 = l & 15, g = l >> 4;
    const int wm = (wid >> 1) * 32, wn = (wid & 1) * 32;
    const int bm0 = blockIdx.y * BM, bn0 = blockIdx.x * BN;
    const int kbeg = blockIdx.z * kseg;

    f4 acc[FM][FN] = {};
    uint4 aR[2], bRh;

    auto loadG = [&](int k0) {
        #pragma unroll
        for (int r = 0; r < 2; ++r) {
            const int idx = r * 1024 + tid * 4;
            const int m = idx >> 5, k = idx & 31;
            aR[r] = *(const uint4*)(Apk + (size_t)(bm0 + m) * lda + k0 + k);
        }
        {
            const int idx = tid * 8;
            const int n = idx >> 5, k = idx & 31;
            bRh = *(const uint4*)(Bhi + (size_t)(bn0 + n) * K + k0 + k);
        }
    };
    auto stoL = [&]() {
        #pragma unroll
        for (int r = 0; r < 2; ++r) {
            const int idx = r * 1024 + tid * 4;
            const int m = idx >> 5, k = idx & 31;
            const uint_t u0 = aR[r].x, u1 = aR[r].y, u2 = aR[r].z, u3 = aR[r].w;
            uint2 hh, ll;
            hh.x = (u0 >> 16) | (u1 & 0xFFFF0000u);
            hh.y = (u2 >> 16) | (u3 & 0xFFFF0000u);
            ll.x = (u0 & 0xFFFFu) | (u1 << 16);
            ll.y = (u2 & 0xFFFFu) | (u3 << 16);
            *(uint2*)&sA[0][m][k] = hh;
            *(uint2*)&sA[1][m][k] = ll;
        }
        {
            const int idx = tid * 8;
            const int n = idx >> 5, k = idx & 31;
            *(uint4*)&sB[n][k] = bRh;
        }
    };

    loadG(kbeg);
    for (int k0 = kbeg; k0 < kbeg + kseg; k0 += 32) {
        stoL();
        __syncthreads();
        if (k0 + 32 < kbeg + kseg) loadG(k0 + 32);
        bf8 ah[FM], al_[FM], bh[FN];
        #pragma unroll
        for (int i = 0; i < FM; ++i) {
            ah[i]  = *(bf8*)&sA[0][wm + i * 16 + l15][g * 8];
            al_[i] = *(bf8*)&sA[1][wm + i * 16 + l15][g * 8];
        }
        #pragma unroll
        for (int j = 0; j < FN; ++j)
            bh[j] = *(bf8*)&sB[wn + j * 16 + l15][g * 8];
        #pragma unroll
        for (int i = 0; i < FM; ++i)
            #pragma unroll
            for (int j = 0; j < FN; ++j)
                acc[i][j] = __builtin_amdgcn_mfma_f32_16x16x32_bf16(ah[i], bh[j], acc[i][j], 0, 0, 0);
        #pragma unroll
        for (int i = 0; i < FM; ++i)
            #pragma unroll
            for (int j = 0; j < FN; ++j)
                acc[i][j] = __builtin_amdgcn_mfma_f32_16x16x32_bf16(al_[i], bh[j], acc[i][j], 0, 0, 0);
        __syncthreads();
    }
    #pragma unroll
    for (int i = 0; i < FM; ++i)
        #pragma unroll
        for (int r = 0; r < 4; ++r) {
            float sum = acc[i][0][r];
            #pragma unroll
            for (int j = 1; j < FN; ++j) sum += acc[i][j][r];
            sum += __shfl_xor(sum, 1);
            sum += __shfl_xor(sum, 2);
            sum += __shfl_xor(sum, 4);
            sum += __shfl_xor(sum, 8);
            if (l15 == 0)
                unsafeAtomicAdd(pooled + bm0 + wm + i * 16 + g * 4 + r, sum * pscale);
        }
}

// ---------------- generic 64x64 tiled fp32 GEMM: C = epi(A@B) -----------------
template<int EPI, int TSTORE>
__global__ __launch_bounds__(256) void gemm64(
    const float* __restrict__ A, int lda,
    const float* __restrict__ B,
    const float* __restrict__ bias,
    float* __restrict__ C,
    int M, int N, int K)
{
    __shared__ float As[16][68];
    __shared__ float Bs[16][64];
    const int tid = threadIdx.x;
    const int bm = blockIdx.y * 64;
    const int bn = blockIdx.x * 64;
    const int tx = tid & 15;
    const int ty = tid >> 4;
    const int la_m = tid >> 2;
    const int la_k = (tid & 3) << 2;
    const int lb_k = tid >> 4;
    const int lb_n = (tid & 15) << 2;

    float acc[4][4] = {};
    for (int k0 = 0; k0 < K; k0 += 16) {
        float4 av = *(const float4*)(A + (size_t)(bm + la_m) * lda + k0 + la_k);
        As[la_k + 0][la_m] = av.x;
        As[la_k + 1][la_m] = av.y;
        As[la_k + 2][la_m] = av.z;
        As[la_k + 3][la_m] = av.w;
        const int gn = bn + lb_n;
        const float* bp = B + (size_t)(k0 + lb_k) * N + gn;
        float4 bv = *(const float4*)bp;
        *(float4*)&Bs[lb_k][lb_n] = bv;
        __syncthreads();
        #pragma unroll
        for (int k = 0; k < 16; ++k) {
            float4 a = *(const float4*)&As[k][ty << 2];
            float4 b = *(const float4*)&Bs[k][tx << 2];
            float ar[4] = {a.x, a.y, a.z, a.w};
            float br[4] = {b.x, b.y, b.z, b.w};
            #pragma unroll
            for (int i = 0; i < 4; ++i)
                #pragma unroll
                for (int j = 0; j < 4; ++j)
                    acc[i][j] = fmaf(ar[i], br[j], acc[i][j]);
        }
        __syncthreads();
    }
    if (TSTORE == 0) {
        #pragma unroll
        for (int i = 0; i < 4; ++i) {
            const int gm = bm + (ty << 2) + i;
            #pragma unroll
            for (int j = 0; j < 4; ++j) {
                const int gn = bn + (tx << 2) + j;
                float v = acc[i][j];
                if (EPI == 1) v += bias[gn];
                else if (EPI == 2) v = softplus_f(v + bias[gn]);
                C[(size_t)gm * N + gn] = v;
            }
        }
    } else {
        const int bq = bm >> 9;
        const int tt0 = (bm & (Tt - 1)) + (ty << 2);
        #pragma unroll
        for (int j = 0; j < 4; ++j) {
            const int gn = bn + (tx << 2) + j;
            float4 v;
            float* vv = (float*)&v;
            #pragma unroll
            for (int i = 0; i < 4; ++i) {
                float t = acc[i][j];
                if (EPI == 2) t = softplus_f(t + bias[gn]);
                vv[i] = t;
            }
            *(float4*)(C + ((size_t)bq * N + gn) * Tt + tt0) = v;
        }
    }
}

// ------- RMSNorm: writes packed hi/lo bf16 xn; adds h0 row-sums to pooled -----
__global__ __launch_bounds__(256) void rms_kernel(
    const float* __restrict__ h0, const float* __restrict__ w,
    uint_t* __restrict__ xn_pk, float* __restrict__ pooled)
{
    const int row = blockIdx.x;
    const float* p = h0 + (size_t)row * DM;
    const int tid = threadIdx.x;
    float v0 = p[tid], v1 = p[tid + 256];
    float ss = v0 * v0 + v1 * v1;
    float sm = v0 + v1;
    #pragma unroll
    for (int m = 32; m; m >>= 1) {
        ss += __shfl_xor(ss, m);
        sm += __shfl_xor(sm, m);
    }
    __shared__ float wss[4], wsm[4];
    if ((tid & 63) == 0) { wss[tid >> 6] = ss; wsm[tid >> 6] = sm; }
    __syncthreads();
    const float tot = wss[0] + wss[1] + wss[2] + wss[3];
    if (tid == 0)
        unsafeAtomicAdd(pooled + row, (wsm[0] + wsm[1] + wsm[2] + wsm[3]) * (1.0f / DM));
    const float scale = rsqrtf(tot * (1.0f / DM) + 1e-5f);
    xn_pk[(size_t)row * DM + tid]       = packf(v0 * scale * w[tid]);
    xn_pk[(size_t)row * DM + tid + 256] = packf(v1 * scale * w[tid + 256]);
}

// -------- causal depthwise conv (DC=4) + SiLU, bf16 in / bf16 out, transposed -
__global__ __launch_bounds__(256) void conv_tr_kernel(
    const ushort_t* __restrict__ xr, const float* __restrict__ cw,
    const float* __restrict__ cb, ushort_t* __restrict__ xp_bf,
    ushort_t* __restrict__ res_bf)
{
    __shared__ float tp[64][65];
    __shared__ float tr[64][65];
    const int di0 = blockIdx.x * 64;
    const int t0  = blockIdx.y * 64;
    const int b   = blockIdx.z;
    const int c  = threadIdx.x & 63;
    const int r4 = threadIdx.x >> 6;
    const int di = di0 + c;
    const float bias = cb[di];
    float w0 = cw[di * DC + 0], w1 = cw[di * DC + 1],
          w2 = cw[di * DC + 2], w3 = cw[di * DC + 3];
    #pragma unroll
    for (int rr = 0; rr < 64; rr += 4) {
        const int t = t0 + rr + r4;
        const int bt = b * Tt + t;
        float acc = bias;
        if (t >= 3) {
            acc = fmaf(w0, bf16_tof(xr[(size_t)(bt - 3) * (2 * DI) + di]), acc);
            acc = fmaf(w1, bf16_tof(xr[(size_t)(bt - 2) * (2 * DI) + di]), acc);
            acc = fmaf(w2, bf16_tof(xr[(size_t)(bt - 1) * (2 * DI) + di]), acc);
        } else {
            if (t >= 1) acc = fmaf(w2, bf16_tof(xr[(size_t)(bt - 1) * (2 * DI) + di]), acc);
            if (t >= 2) acc = fmaf(w1, bf16_tof(xr[(size_t)(bt - 2) * (2 * DI) + di]), acc);
        }
        acc = fmaf(w3, bf16_tof(xr[(size_t)bt * (2 * DI) + di]), acc);
        tp[rr + r4][c] = silu_fast(acc);
        tr[rr + r4][c] = bf16_tof(xr[(size_t)bt * (2 * DI) + DI + di]);
    }
    __syncthreads();
    #pragma unroll
    for (int dd = 0; dd < 64; dd += 4) {
        const int dw = dd + r4;
        const size_t o = ((size_t)b * DI + di0 + dw) * Tt + t0 + c;
        xp_bf[o]  = bf16_rne(tp[c][dw]);
        res_bf[o] = bf16_rne(tr[c][dw]);
    }
}

// ============= fused single-pass selective scan (256 thr, 8 di/block) =========
__global__ __launch_bounds__(256) void scan_fused(
    const float* __restrict__ deltaT, const float* __restrict__ xdbl,
    const ushort_t* __restrict__ xp_bf, const ushort_t* __restrict__ res_bf,
    const float* __restrict__ A_log, const float* __restrict__ Dvec,
    uint_t* __restrict__ y_pk)
{
    __shared__ uint_t   sBC[2][DS][68];   // [buf][s][t]: {C bf16 hi | B bf16 lo}
    __shared__ float    sD [2][8][68];    // fp32 d (exponent path)
    __shared__ float    sDU[2][8][68];    // fp32 d*u
    __shared__ ushort_t sU [2][8][68];    // bf16 u (D-skip)
    __shared__ ushort_t sR [2][8][68];    // bf16 res (gate)
    __shared__ float ylds[CL][9];
    const int tid = threadIdx.x;
    const int grp = tid >> 5;            // 0..7 : di within block
    const int l5 = tid & 31;
    const int s = ((l5 & 1) << 4) | (l5 >> 1);   // lane remap: s^16 <-> l^1 (quad DPP)
    const int b = blockIdx.x >> 7;
    const int di0 = (blockIdx.x & 127) << 3;
    const int sd_r = tid >> 5;           // 0..7
    const int sd_t = (tid & 31) << 1;    // 0..62
    const int bc_t = tid >> 2;           // 0..63
    const int bc_s = (tid & 3) << 3;     // 0,8,16,24

    float2 rd2;
    uint_t ru, rr_;
    float4 rB[2], rC[2];
    auto stage_regs = [&](int c) {
        const size_t rb = ((size_t)(b * DI + di0 + sd_r)) * Tt + c * CL + sd_t;
        rd2 = *(const float2*)(deltaT + rb);
        ru  = *(const uint_t*)(xp_bf + rb);
        rr_ = *(const uint_t*)(res_bf + rb);
        const float* src = xdbl + ((size_t)b * Tt + c * CL + bc_t) * 96;
        rB[0] = *(const float4*)(src + 32 + bc_s);
        rB[1] = *(const float4*)(src + 32 + bc_s + 4);
        rC[0] = *(const float4*)(src + 64 + bc_s);
        rC[1] = *(const float4*)(src + 64 + bc_s + 4);
    };
    auto write_lds = [&](int bb) {
        *(float2*)&sD[bb][sd_r][sd_t] = rd2;
        const float u0 = bf16_tof((ushort_t)(ru & 0xFFFFu));
        const float u1 = bf16_tof((ushort_t)(ru >> 16));
        float2 du2;
        du2.x = rd2.x * u0;
        du2.y = rd2.y * u1;
        *(float2*)&sDU[bb][sd_r][sd_t] = du2;
        *(uint_t*)&sU[bb][sd_r][sd_t] = ru;
        *(uint_t*)&sR[bb][sd_r][sd_t] = rr_;
        const float bv[8] = {rB[0].x, rB[0].y, rB[0].z, rB[0].w,
                             rB[1].x, rB[1].y, rB[1].z, rB[1].w};
        const float cv[8] = {rC[0].x, rC[0].y, rC[0].z, rC[0].w,
                             rC[1].x, rC[1].y, rC[1].z, rC[1].w};
        #pragma unroll
        for (int j = 0; j < 8; ++j)
            sBC[bb][bc_s + j][bc_t] =
                ((uint_t)bf16_rne(cv[j]) << 16) | (uint_t)bf16_rne(bv[j]);
    };

    const bool s4b = (l5 & 1) != 0;
    const bool s0b = (l5 & 2) != 0;
    const bool s1b = (l5 & 4) != 0;
    const bool s2b = (l5 & 8) != 0;
    const bool s3b = (l5 & 16) != 0;
    const int di = di0 + grp;
    const float Ads2 = -expf(A_log[di * DS + s]) * 1.44269504f;
    const float Dv = Dvec[di];
    float h = 0.f;

    stage_regs(0);
    write_lds(0);
    #pragma unroll 1
    for (int c = 0; c < NCH; ++c) {
        const int bb = c & 1;
        __syncthreads();
        if (c < NCH - 1) stage_regs(c + 1);
        #pragma unroll 1
        for (int t0 = 0; t0 < CL; t0 += 32) {
            float buf[16] = {};
            uint4 bc_c = *(const uint4*)&sBC[bb][s][t0];
            float4 dv_c = *(const float4*)&sD[bb][grp][t0];
            float4 du_c = *(const float4*)&sDU[bb][grp][t0];
            #pragma unroll
            for (int tq = 0; tq < 8; ++tq) {
                uint4 bc_n;
                float4 dv_n, du_n;
                if (tq < 7) {
                    const int tb = t0 + tq * 4 + 4;
                    bc_n = *(const uint4*)&sBC[bb][s][tb];
                    dv_n = *(const float4*)&sD[bb][grp][tb];
                    du_n = *(const float4*)&sDU[bb][grp][tb];
                }
                const uint_t bcv[4] = {bc_c.x, bc_c.y, bc_c.z, bc_c.w};
                const float dv[4] = {dv_c.x, dv_c.y, dv_c.z, dv_c.w};
                const float duv[4] = {du_c.x, du_c.y, du_c.z, du_c.w};
                #pragma unroll
                for (int q = 0; q < 4; ++q) {
                    const int tl = tq * 4 + q;
                    const float Bq = __uint_as_float(bcv[q] << 16);
                    const float Cq = __uint_as_float(bcv[q] & 0xFFFF0000u);
                    h = fmaf(__builtin_amdgcn_exp2f(dv[q] * Ads2), h, duv[q] * Bq);
                    const float ps = h * Cq;
                    const float pr = ps + qperm<0xB1>(ps);
                    const bool keep = ((tl & 16) != 0) == s4b;
                    buf[tl & 15] = keep ? pr : buf[tl & 15];
                }
                if (tq < 7) { bc_c = bc_n; dv_c = dv_n; du_c = du_n; }
            }
            #pragma unroll
            for (int i = 0; i < 16; ++i) buf[i] += qperm<0x4E>(buf[i]);
            float r8[8];
            #pragma unroll
            for (int i = 0; i < 8; ++i) r8[i] = s0b ? buf[2 * i + 1] : buf[2 * i];
            #pragma unroll
            for (int i = 0; i < 8; ++i) r8[i] += swz<0x101F>(r8[i]);
            float w4[4];
            #pragma unroll
            for (int i = 0; i < 4; ++i) w4[i] = s1b ? r8[2 * i + 1] : r8[2 * i];
            #pragma unroll
            for (int i = 0; i < 4; ++i) w4[i] += swz<0x201F>(w4[i]);
            float v2[2];
            v2[0] = s2b ? w4[1] : w4[0];
            v2[1] = s2b ? w4[3] : w4[2];
            v2[0] += swz<0x401F>(v2[0]);
            v2[1] += swz<0x401F>(v2[1]);
            const float yv = s3b ? v2[1] : v2[0];
            const float uself = bf16_tof(sU[bb][grp][t0 + s]);
            const float rself = bf16_tof(sR[bb][grp][t0 + s]);
            ylds[t0 + s][grp] = fmaf(uself, Dv, yv) * silu_fast(rself);
        }
        __syncthreads();
        {
            const int row = tid >> 2;
            const int q2 = (tid & 3) << 1;
            uint2 o;
            o.x = packf(ylds[row][q2 + 0]);
            o.y = packf(ylds[row][q2 + 1]);
            *(uint2*)(y_pk + ((size_t)b * Tt + c * CL + row) * DI + di0 + q2) = o;
        }
        if (c < NCH - 1) write_lds(bb ^ 1);
    }
}

// ---------------- classifier ---------------------------------------------------
__global__ __launch_bounds__(256) void cls_kernel(
    const float* __restrict__ pooled, const float* __restrict__ w_cls,
    const float* __restrict__ b_cls, float* __restrict__ out)
{
    const int idx = blockIdx.x * 256 + threadIdx.x;
    if (idx >= Bb * NC) return;
    const int b = idx / NC, c = idx % NC;
    float acc = b_cls[c];
    for (int t = 0; t < DM; ++t)
        acc = fmaf(pooled[b * DM + t], w_cls[t * NC + c], acc);
    out[idx] = acc;
}

extern "C" void kernel_launch(void* const* d_in, const int* in_sizes, int n_in,
                              void* d_out, int out_size, void* d_ws, size_t ws_size,
                              hipStream_t stream) {
    const float* x      = (const float*)d_in[0];
    const float* w_proj = (const float*)d_in[1];
    const float* b_proj = (const float*)d_in[2];
    const float* rms_w  = (const float*)d_in[3];
    const float* w_in   = (const float*)d_in[4];
    const float* conv_w = (const float*)d_in[5];
    const float* conv_b = (const float*)d_in[6];
    const float* w_xprj = (const float*)d_in[7];
    const float* w_dt   = (const float*)d_in[8];
    const float* b_dt   = (const float*)d_in[9];
    const float* A_log  = (const float*)d_in[10];
    const float* Dvec   = (const float*)d_in[11];
    const float* w_out  = (const float*)d_in[12];
    const float* w_cls  = (const float*)d_in[13];
    const float* b_cls  = (const float*)d_in[14];
    float* out = (float*)d_out;

    float* ws = (float*)d_ws;
    float* h0     = ws;
    float* xn     = h0 + (size_t)BT * DM;          // holds xn_pk (uint)
    float* xr     = xn + (size_t)BT * DM;          // region reused: xr_bf16 -> deltaT
    float* xpT    = xr + (size_t)BT * 2 * DI;      // holds xp_bf (ushort)
    float* resT   = xpT + (size_t)Bb * DI * Tt;    // holds res_bf (ushort)
    float* xdbl   = resT + (size_t)Bb * DI * Tt;
    float* pooled = xdbl + (size_t)BT * 96;
    float* wsplit = pooled + 4096;                 // weight-split scratch
    float* deltaT = xr;                            // alias: xr_bf dead after conv_tr
    uint_t* y_pk  = (uint_t*)(xr + (size_t)Bb * DI * Tt);  // upper half of xr region
    uint_t* xn_pk = (uint_t*)xn;
    ushort_t* xr_bf  = (ushort_t*)xr;
    ushort_t* xp_bf  = (ushort_t*)xpT;
    ushort_t* res_bf = (ushort_t*)resT;

    // weight splits (bf16 hi/lo, transposed to [n][k]) — all own scratch:
    ushort_t* w_in_hi  = (ushort_t*)wsplit;
    ushort_t* w_in_lo  = w_in_hi + (size_t)(2 * DI) * DM;
    ushort_t* w_out_hi = w_in_lo + (size_t)(2 * DI) * DM;
    ushort_t* w_out_lo = w_out_hi + (size_t)DM * DI;
    ushort_t* w_xp_hi  = w_out_lo + (size_t)DM * DI;
    ushort_t* w_xp_lo  = w_xp_hi + (size_t)96 * DI;

    // 0) split+transpose w_in; fused zero of xdbl+pooled (contiguous region)
    split_tr_kernel<<<dim3(2 * DI / 32, DM / 32), 256, 0, stream>>>(
        w_in, w_in_hi, w_in_lo, DM, 2 * DI,
        (float4*)xdbl, (BT * 96 + 4096) / 4);
    // 0b) split+transpose w_out
    split_tr_kernel<<<dim3(DM / 32, DI / 32), 256, 0, stream>>>(
        w_out, w_out_hi, w_out_lo, DI, DM, nullptr, 0);
    // 0c) split+transpose w_xproj (1024,96) -> [96][1024]
    split_tr_kernel<<<dim3(96 / 32, DI / 32), 256, 0, stream>>>(
        w_xprj, w_xp_hi, w_xp_lo, DI, 96, nullptr, 0);
    // 1) h0 = x @ w_proj + b_proj
    gemm64<1,0><<<dim3(DM / 64, BT / 64), 256, 0, stream>>>(
        x, NM, w_proj, b_proj, h0, BT, DM, NM);
    // 2) xn_pk = pack(rmsnorm(h0) * rms_w); pooled += rowsum(h0)/DM
    rms_kernel<<<BT, 256, 0, stream>>>(h0, rms_w, xn_pk, pooled);
    // 3) xr_bf = bf16(xn @ w_in)    (single-pass bf16 MFMA, 8-wave blocks)
    gemm_mfma_big<<<dim3(2 * DI / 128, BT / 128), 512, 0, stream>>>(
        xn_pk, DM, w_in_hi, xr_bf, 2 * DI, DM);
    // 4) xp_bf = bf16(silu(causal_dwconv(xr[:, :DI])))^T ; res_bf = xr[:, DI:]^T
    conv_tr_kernel<<<dim3(DI / 64, Tt / 64, Bb), 256, 0, stream>>>(
        xr_bf, conv_w, conv_b, xp_bf, res_bf);
    // 5) xdbl += xp @ w_xproj   (single-pass bf16 MFMA, split-K=8, atomics)
    gemm_mfma_x<<<dim3(1, BT / 64, 8), 256, 0, stream>>>(
        xp_bf, w_xp_hi, xdbl, DI, DI / 8);
    // 6) deltaT = softplus(dt @ w_dt + b_dt)^T
    gemm64<2,1><<<dim3(DI / 64, BT / 64), 256, 0, stream>>>(
        xdbl, 96, w_dt, b_dt, deltaT, BT, DI, DR);
    // 7) fused single-pass selective scan (h in registers across chunks)
    scan_fused<<<Bb * (DI / 8), 256, 0, stream>>>(
        deltaT, xdbl, xp_bf, res_bf, A_log, Dvec, y_pk);
    // 8) pooled += rowsum(y @ w_out)/DM   (2-pass MFMA + split-K=4 + mean-pool)
    gemm_mfma_pool<<<dim3(DM / 64, BT / 64, 4), 256, 0, stream>>>(
        y_pk, DI, w_out_hi, pooled, 1.0f / DM, DM, DI, DI / 4);
    // 9) out = pooled @ w_cls + b_cls
    cls_kernel<<<(Bb * NC + 255) / 256, 256, 0, stream>>>(pooled, w_cls, b_cls, out);
}

// Round 17
// 231.340 us; speedup vs baseline: 1.6096x; 1.0481x over previous
//
#include <hip/hip_runtime.h>
#include <hip/hip_bf16.h>
#include <cstddef>

#define Bb 8
#define Tt 512
#define NM 128
#define DM 512
#define DI 1024
#define DS 32
#define DR 32
#define DC 4
#define NC 100
#define BT (Bb*Tt)     // 4096
#define NCH 8          // scan chunks
#define CL  64         // chunk length

typedef unsigned short ushort_t;
typedef unsigned int uint_t;
typedef __attribute__((ext_vector_type(8))) short bf8;    // 8 bf16 in 4 VGPRs
typedef __attribute__((ext_vector_type(4))) float f4;

__device__ __forceinline__ float softplus_f(float x) {
    return fmaxf(x, 0.f) + log1pf(expf(-fabsf(x)));
}
__device__ __forceinline__ float silu_fast(float x) {
    return __fdividef(x, 1.f + __expf(-x));
}
__device__ __forceinline__ ushort_t bf16_rne(float x) {
    uint_t u = __float_as_uint(x);
    uint_t r = u + 0x7FFFu + ((u >> 16) & 1u);
    return (ushort_t)(r >> 16);
}
__device__ __forceinline__ float bf16_tof(ushort_t h) {
    return __uint_as_float(((uint_t)h) << 16);
}
// pack fp32 -> {hi bf16 in [31:16], lo bf16 in [15:0]}
__device__ __forceinline__ uint_t packf(float v) {
    ushort_t h = bf16_rne(v);
    ushort_t l = bf16_rne(v - bf16_tof(h));
    return ((uint_t)h << 16) | (uint_t)l;
}
// cross-lane: quad_perm DPP (VALU pipe) and ds_swizzle (DS pipe)
template<int CTRL>
__device__ __forceinline__ float qperm(float x) {
    return __int_as_float(__builtin_amdgcn_mov_dpp(__float_as_int(x), CTRL, 0xF, 0xF, true));
}
template<int PAT>
__device__ __forceinline__ float swz(float x) {
    return __int_as_float(__builtin_amdgcn_ds_swizzle(__float_as_int(x), PAT));
}

// ===== unified prep: all weight splits + x pack + zero-init, ONE launch =======
// blocks: [0,1024) w_in | [1024,1536) w_out | [1536,1632) w_xp |
//         [1632,1696) w_proj | [1696,1728) w_dt | [1728,3776) x pack + zero
__global__ __launch_bounds__(256) void prep_kernel(
    const float* __restrict__ x, const float* __restrict__ w_in,
    const float* __restrict__ w_out, const float* __restrict__ w_xp,
    const float* __restrict__ w_pj, const float* __restrict__ w_dt,
    uint_t* __restrict__ x_pk,
    ushort_t* __restrict__ w_in_hi, ushort_t* __restrict__ w_in_lo,
    ushort_t* __restrict__ w_out_hi, ushort_t* __restrict__ w_out_lo,
    ushort_t* __restrict__ w_xp_hi, ushort_t* __restrict__ w_xp_lo,
    ushort_t* __restrict__ w_pj_hi, ushort_t* __restrict__ w_pj_lo,
    ushort_t* __restrict__ w_dt_hi, ushort_t* __restrict__ w_dt_lo,
    float4* __restrict__ zbase, int zcount)
{
    __shared__ ushort_t th[32][34], tl[32][34];
    const int bid = blockIdx.x;
    const float* src;
    ushort_t *hi, *lo;
    int K, N, bx, by;
    if (bid < 1024)      { src = w_in;  hi = w_in_hi;  lo = w_in_lo;  K = DM; N = 2 * DI; bx = bid & 63; by = bid >> 6; }
    else if (bid < 1536) { const int i = bid - 1024; src = w_out; hi = w_out_hi; lo = w_out_lo; K = DI; N = DM; bx = i & 15; by = i >> 4; }
    else if (bid < 1632) { const int i = bid - 1536; src = w_xp;  hi = w_xp_hi;  lo = w_xp_lo;  K = DI; N = 96; bx = i % 3; by = i / 3; }
    else if (bid < 1696) { const int i = bid - 1632; src = w_pj;  hi = w_pj_hi;  lo = w_pj_lo;  K = NM; N = DM; bx = i & 15; by = i >> 4; }
    else if (bid < 1728) { const int i = bid - 1696; src = w_dt;  hi = w_dt_hi;  lo = w_dt_lo;  K = DR; N = DI; bx = i; by = 0; }
    else {
        const int e = (bid - 1728) * 256 + threadIdx.x;   // 2048*256 = 524288 = BT*NM
        x_pk[e] = packf(x[e]);
        if (e < zcount) zbase[e] = make_float4(0.f, 0.f, 0.f, 0.f);
        return;
    }
    const int k0 = by * 32, n0 = bx * 32;
    #pragma unroll
    for (int it = 0; it < 4; ++it) {
        const int idx = it * 256 + threadIdx.x;
        const int r = idx >> 5, c = idx & 31;
        const float v = src[(size_t)(k0 + r) * N + n0 + c];
        const ushort_t h = bf16_rne(v);
        th[c][r] = h;
        tl[c][r] = bf16_rne(v - bf16_tof(h));
    }
    __syncthreads();
    #pragma unroll
    for (int it = 0; it < 4; ++it) {
        const int idx = it * 256 + threadIdx.x;
        const int r = idx >> 5, c = idx & 31;
        hi[(size_t)(n0 + r) * K + k0 + c] = th[r][c];
        lo[(size_t)(n0 + r) * K + k0 + c] = tl[r][c];
    }
}

// ---- step1: h0 = x @ w_proj + b_proj (3-pass MFMA, 512 thr, 128x128 tile) ---
__global__ __launch_bounds__(512) void gemm_mfma_h0(
    const uint_t* __restrict__ Apk,                 // (BT, NM) packed
    const ushort_t* __restrict__ Bhi, const ushort_t* __restrict__ Blo,
    const float* __restrict__ bias, float* __restrict__ C)
{
    constexpr int BM = 128, BN = 128, FM = 2, FN = 4, K = NM, N = DM;
    __shared__ ushort_t sA[2][BM][40];
    __shared__ ushort_t sB[2][BN][40];
    const int tid = threadIdx.x;
    const int wid = tid >> 6, l = tid & 63, l15 = l & 15, g = l >> 4;
    const int wm = (wid >> 1) * 32, wn = (wid & 1) * 64;
    const int bm0 = blockIdx.y * BM, bn0 = blockIdx.x * BN;

    f4 acc[FM][FN] = {};
    uint4 aR[2], bRh, bRl;

    auto loadG = [&](int k0) {
        #pragma unroll
        for (int r = 0; r < 2; ++r) {
            const int idx = r * 2048 + tid * 4;
            const int m = idx >> 5, k = idx & 31;
            aR[r] = *(const uint4*)(Apk + (size_t)(bm0 + m) * K + k0 + k);
        }
        {
            const int idx = tid * 8;
            const int n = idx >> 5, k = idx & 31;
            const size_t o = (size_t)(bn0 + n) * K + k0 + k;
            bRh = *(const uint4*)(Bhi + o);
            bRl = *(const uint4*)(Blo + o);
        }
    };
    auto stoL = [&]() {
        #pragma unroll
        for (int r = 0; r < 2; ++r) {
            const int idx = r * 2048 + tid * 4;
            const int m = idx >> 5, k = idx & 31;
            uint2 hh, ll;
            hh.x = (aR[r].x >> 16) | (aR[r].y & 0xFFFF0000u);
            hh.y = (aR[r].z >> 16) | (aR[r].w & 0xFFFF0000u);
            ll.x = (aR[r].x & 0xFFFFu) | (aR[r].y << 16);
            ll.y = (aR[r].z & 0xFFFFu) | (aR[r].w << 16);
            *(uint2*)&sA[0][m][k] = hh;
            *(uint2*)&sA[1][m][k] = ll;
        }
        {
            const int idx = tid * 8;
            const int n = idx >> 5, k = idx & 31;
            *(uint4*)&sB[0][n][k] = bRh;
            *(uint4*)&sB[1][n][k] = bRl;
        }
    };

    loadG(0);
    for (int k0 = 0; k0 < K; k0 += 32) {
        stoL();
        __syncthreads();
        if (k0 + 32 < K) loadG(k0 + 32);
        bf8 ah[FM], al_[FM], bh[FN], bl_[FN];
        #pragma unroll
        for (int i = 0; i < FM; ++i) {
            ah[i]  = *(bf8*)&sA[0][wm + i * 16 + l15][g * 8];
            al_[i] = *(bf8*)&sA[1][wm + i * 16 + l15][g * 8];
        }
        #pragma unroll
        for (int j = 0; j < FN; ++j) {
            bh[j]  = *(bf8*)&sB[0][wn + j * 16 + l15][g * 8];
            bl_[j] = *(bf8*)&sB[1][wn + j * 16 + l15][g * 8];
        }
        #pragma unroll
        for (int i = 0; i < FM; ++i)
            #pragma unroll
            for (int j = 0; j < FN; ++j)
                acc[i][j] = __builtin_amdgcn_mfma_f32_16x16x32_bf16(ah[i], bh[j], acc[i][j], 0, 0, 0);
        #pragma unroll
        for (int i = 0; i < FM; ++i)
            #pragma unroll
            for (int j = 0; j < FN; ++j)
                acc[i][j] = __builtin_amdgcn_mfma_f32_16x16x32_bf16(al_[i], bh[j], acc[i][j], 0, 0, 0);
        #pragma unroll
        for (int i = 0; i < FM; ++i)
            #pragma unroll
            for (int j = 0; j < FN; ++j)
                acc[i][j] = __builtin_amdgcn_mfma_f32_16x16x32_bf16(ah[i], bl_[j], acc[i][j], 0, 0, 0);
        __syncthreads();
    }
    #pragma unroll
    for (int i = 0; i < FM; ++i)
        #pragma unroll
        for (int j = 0; j < FN; ++j)
            #pragma unroll
            for (int r = 0; r < 4; ++r) {
                const int m = bm0 + wm + i * 16 + g * 4 + r;
                const int n = bn0 + wn + j * 16 + l15;
                C[(size_t)m * N + n] = acc[i][j][r] + bias[n];
            }
}

// ---- step6: deltaT = softplus(xdbl[:, :32] @ w_dt + b_dt)^T  (one K step) ---
__global__ __launch_bounds__(256) void gemm_mfma_dt(
    const float* __restrict__ xdbl,                 // (BT, 96) cols 0..32
    const ushort_t* __restrict__ Bhi, const ushort_t* __restrict__ Blo, // (DI,32)
    const float* __restrict__ bias, float* __restrict__ dT)
{
    constexpr int FM = 2, FN = 2;
    __shared__ ushort_t sA[2][64][40];
    __shared__ ushort_t sB[2][64][40];
    const int tid = threadIdx.x;
    const int wid = tid >> 6, l = tid & 63, l15 = l & 15, g = l >> 4;
    const int wm = (wid >> 1) * 32, wn = (wid & 1) * 32;
    const int bm0 = blockIdx.y * 64, bn0 = blockIdx.x * 64;

    #pragma unroll
    for (int r = 0; r < 2; ++r) {
        const int idx = r * 1024 + tid * 4;
        const int m = idx >> 5, k = idx & 31;
        const float4 v = *(const float4*)(xdbl + (size_t)(bm0 + m) * 96 + k);
        const float vv[4] = {v.x, v.y, v.z, v.w};
        #pragma unroll
        for (int q = 0; q < 4; ++q) {
            const ushort_t h = bf16_rne(vv[q]);
            sA[0][m][k + q] = h;
            sA[1][m][k + q] = bf16_rne(vv[q] - bf16_tof(h));
        }
    }
    {
        const int idx = tid * 8;
        const int n = idx >> 5, k = idx & 31;
        *(uint4*)&sB[0][n][k] = *(const uint4*)(Bhi + (size_t)(bn0 + n) * 32 + k);
        *(uint4*)&sB[1][n][k] = *(const uint4*)(Blo + (size_t)(bn0 + n) * 32 + k);
    }
    __syncthreads();
    f4 acc[FM][FN] = {};
    bf8 ah[FM], al_[FM], bh[FN], bl_[FN];
    #pragma unroll
    for (int i = 0; i < FM; ++i) {
        ah[i]  = *(bf8*)&sA[0][wm + i * 16 + l15][g * 8];
        al_[i] = *(bf8*)&sA[1][wm + i * 16 + l15][g * 8];
    }
    #pragma unroll
    for (int j = 0; j < FN; ++j) {
        bh[j]  = *(bf8*)&sB[0][wn + j * 16 + l15][g * 8];
        bl_[j] = *(bf8*)&sB[1][wn + j * 16 + l15][g * 8];
    }
    #pragma unroll
    for (int i = 0; i < FM; ++i)
        #pragma unroll
        for (int j = 0; j < FN; ++j) {
            acc[i][j] = __builtin_amdgcn_mfma_f32_16x16x32_bf16(ah[i], bh[j], acc[i][j], 0, 0, 0);
            acc[i][j] = __builtin_amdgcn_mfma_f32_16x16x32_bf16(al_[i], bh[j], acc[i][j], 0, 0, 0);
            acc[i][j] = __builtin_amdgcn_mfma_f32_16x16x32_bf16(ah[i], bl_[j], acc[i][j], 0, 0, 0);
        }
    #pragma unroll
    for (int i = 0; i < FM; ++i)
        #pragma unroll
        for (int j = 0; j < FN; ++j) {
            const int n = bn0 + wn + j * 16 + l15;
            const int m0 = bm0 + wm + i * 16 + g * 4;
            const float bn = bias[n];
            float4 o;
            o.x = softplus_f(acc[i][j][0] + bn);
            o.y = softplus_f(acc[i][j][1] + bn);
            o.z = softplus_f(acc[i][j][2] + bn);
            o.w = softplus_f(acc[i][j][3] + bn);
            *(float4*)(dT + ((size_t)(m0 >> 9) * DI + n) * Tt + (m0 & 511)) = o;
        }
}

// ---- single-pass bf16 MFMA GEMM, 512 thr / 8 waves, 128x128 tile, bf16 C ----
__global__ __launch_bounds__(512) void gemm_mfma_big(
    const uint_t* __restrict__ Apk, int lda,
    const ushort_t* __restrict__ Bhi,
    ushort_t* __restrict__ C, int N, int K)
{
    constexpr int FM = 2, FN = 4;
    __shared__ ushort_t sA[128][40];
    __shared__ ushort_t sB[128][40];
    const int tid = threadIdx.x;
    const int wid = tid >> 6, l = tid & 63, l15 = l & 15, g = l >> 4;
    const int wm = (wid >> 1) * 32, wn = (wid & 1) * 64;
    const int bm0 = blockIdx.y * 128, bn0 = blockIdx.x * 128;

    f4 acc[FM][FN] = {};
    uint4 aR[2], bRh;

    auto loadG = [&](int k0) {
        #pragma unroll
        for (int r = 0; r < 2; ++r) {
            const int idx = r * 2048 + tid * 4;
            const int m = idx >> 5, k = idx & 31;
            aR[r] = *(const uint4*)(Apk + (size_t)(bm0 + m) * lda + k0 + k);
        }
        {
            const int idx = tid * 8;
            const int n = idx >> 5, k = idx & 31;
            bRh = *(const uint4*)(Bhi + (size_t)(bn0 + n) * K + k0 + k);
        }
    };
    auto stoL = [&]() {
        #pragma unroll
        for (int r = 0; r < 2; ++r) {
            const int idx = r * 2048 + tid * 4;
            const int m = idx >> 5, k = idx & 31;
            uint2 hh;
            hh.x = (aR[r].x >> 16) | (aR[r].y & 0xFFFF0000u);
            hh.y = (aR[r].z >> 16) | (aR[r].w & 0xFFFF0000u);
            *(uint2*)&sA[m][k] = hh;
        }
        {
            const int idx = tid * 8;
            const int n = idx >> 5, k = idx & 31;
            *(uint4*)&sB[n][k] = bRh;
        }
    };

    loadG(0);
    for (int k0 = 0; k0 < K; k0 += 32) {
        stoL();
        __syncthreads();
        if (k0 + 32 < K) loadG(k0 + 32);
        bf8 ah[FM], bh[FN];
        #pragma unroll
        for (int i = 0; i < FM; ++i)
            ah[i] = *(bf8*)&sA[wm + i * 16 + l15][g * 8];
        #pragma unroll
        for (int j = 0; j < FN; ++j)
            bh[j] = *(bf8*)&sB[wn + j * 16 + l15][g * 8];
        #pragma unroll
        for (int i = 0; i < FM; ++i)
            #pragma unroll
            for (int j = 0; j < FN; ++j)
                acc[i][j] = __builtin_amdgcn_mfma_f32_16x16x32_bf16(ah[i], bh[j], acc[i][j], 0, 0, 0);
        __syncthreads();
    }
    #pragma unroll
    for (int i = 0; i < FM; ++i)
        #pragma unroll
        for (int j = 0; j < FN; ++j)
            #pragma unroll
            for (int r = 0; r < 4; ++r) {
                const int m = bm0 + wm + i * 16 + g * 4 + r;
                const int n = bn0 + wn + j * 16 + l15;
                C[(size_t)m * N + n] = bf16_rne(acc[i][j][r]);
            }
}

// ---- step5: xdbl += xp_bf @ w_xproj  (single-pass bf16, split-K atomics) ----
__global__ __launch_bounds__(256) void gemm_mfma_x(
    const ushort_t* __restrict__ Abf,
    const ushort_t* __restrict__ Bhi,
    float* __restrict__ C, int K, int kseg)
{
    constexpr int FM = 2, FN = 3;
    __shared__ ushort_t sAx[64][40];
    __shared__ ushort_t sBx[96][40];
    const int tid = threadIdx.x;
    const int wid = tid >> 6, l = tid & 63, l15 = l & 15, g = l >> 4;
    const int wm = (wid >> 1) * 32, wn = (wid & 1) * 48;
    const int bm0 = blockIdx.y * 64;
    const int kbeg = blockIdx.z * kseg;

    f4 acc[FM][FN] = {};
    uint4 aR;
    uint2 bRh[3];

    auto loadG = [&](int k0) {
        {
            const int idx = tid * 8;
            const int m = idx >> 5, k = idx & 31;
            aR = *(const uint4*)(Abf + (size_t)(bm0 + m) * K + k0 + k);
        }
        #pragma unroll
        for (int r = 0; r < 3; ++r) {
            const int idx = r * 1024 + tid * 4;
            const int n = idx >> 5, k = idx & 31;
            bRh[r] = *(const uint2*)(Bhi + (size_t)n * K + k0 + k);
        }
    };
    auto stoL = [&]() {
        {
            const int idx = tid * 8;
            const int m = idx >> 5, k = idx & 31;
            *(uint4*)&sAx[m][k] = aR;
        }
        #pragma unroll
        for (int r = 0; r < 3; ++r) {
            const int idx = r * 1024 + tid * 4;
            const int n = idx >> 5, k = idx & 31;
            *(uint2*)&sBx[n][k] = bRh[r];
        }
    };

    loadG(kbeg);
    for (int k0 = kbeg; k0 < kbeg + kseg; k0 += 32) {
        stoL();
        __syncthreads();
        if (k0 + 32 < kbeg + kseg) loadG(k0 + 32);
        bf8 ah[FM], bh[FN];
        #pragma unroll
        for (int i = 0; i < FM; ++i)
            ah[i] = *(bf8*)&sAx[wm + i * 16 + l15][g * 8];
        #pragma unroll
        for (int j = 0; j < FN; ++j)
            bh[j] = *(bf8*)&sBx[wn + j * 16 + l15][g * 8];
        #pragma unroll
        for (int i = 0; i < FM; ++i)
            #pragma unroll
            for (int j = 0; j < FN; ++j)
                acc[i][j] = __builtin_amdgcn_mfma_f32_16x16x32_bf16(ah[i], bh[j], acc[i][j], 0, 0, 0);
        __syncthreads();
    }
    #pragma unroll
    for (int i = 0; i < FM; ++i)
        #pragma unroll
        for (int j = 0; j < FN; ++j)
            #pragma unroll
            for (int r = 0; r < 4; ++r) {
                const int m = bm0 + wm + i * 16 + g * 4 + r;
                const int n = wn + j * 16 + l15;
                unsafeAtomicAdd(&C[(size_t)m * 96 + n], acc[i][j][r]);
            }
}

// ---- 2-pass MFMA GEMM (A hi+lo, B hi), 64x64 tile, split-K, fused mean-pool -
__global__ __launch_bounds__(256) void gemm_mfma_pool(
    const uint_t* __restrict__ Apk, int lda,
    const ushort_t* __restrict__ Bhi,
    float* __restrict__ pooled, float pscale,
    int N, int K, int kseg)
{
    constexpr int FM = 2, FN = 2;
    __shared__ ushort_t sA[2][64][40];
    __shared__ ushort_t sB[64][40];
    const int tid = threadIdx.x;
    const int wid = tid >> 6, l = tid & 63, l15 = l & 15, g = l >> 4;
    const int wm = (wid >> 1) * 32, wn = (wid & 1) * 32;
    const int bm0 = blockIdx.y * 64, bn0 = blockIdx.x * 64;
    const int kbeg = blockIdx.z * kseg;

    f4 acc[FM][FN] = {};
    uint4 aR[2], bRh;

    auto loadG = [&](int k0) {
        #pragma unroll
        for (int r = 0; r < 2; ++r) {
            const int idx = r * 1024 + tid * 4;
            const int m = idx >> 5, k = idx & 31;
            aR[r] = *(const uint4*)(Apk + (size_t)(bm0 + m) * lda + k0 + k);
        }
        {
            const int idx = tid * 8;
            const int n = idx >> 5, k = idx & 31;
            bRh = *(const uint4*)(Bhi + (size_t)(bn0 + n) * K + k0 + k);
        }
    };
    auto stoL = [&]() {
        #pragma unroll
        for (int r = 0; r < 2; ++r) {
            const int idx = r * 1024 + tid * 4;
            const int m = idx >> 5, k = idx & 31;
            const uint_t u0 = aR[r].x, u1 = aR[r].y, u2 = aR[r].z, u3 = aR[r].w;
            uint2 hh, ll;
            hh.x = (u0 >> 16) | (u1 & 0xFFFF0000u);
            hh.y = (u2 >> 16) | (u3 & 0xFFFF0000u);
            ll.x = (u0 & 0xFFFFu) | (u1 << 16);
            ll.y = (u2 & 0xFFFFu) | (u3 << 16);
            *(uint2*)&sA[0][m][k] = hh;
            *(uint2*)&sA[1][m][k] = ll;
        }
        {
            const int idx = tid * 8;
            const int n = idx >> 5, k = idx & 31;
            *(uint4*)&sB[n][k] = bRh;
        }
    };

    loadG(kbeg);
    for (int k0 = kbeg; k0 < kbeg + kseg; k0 += 32) {
        stoL();
        __syncthreads();
        if (k0 + 32 < kbeg + kseg) loadG(k0 + 32);
        bf8 ah[FM], al_[FM], bh[FN];
        #pragma unroll
        for (int i = 0; i < FM; ++i) {
            ah[i]  = *(bf8*)&sA[0][wm + i * 16 + l15][g * 8];
            al_[i] = *(bf8*)&sA[1][wm + i * 16 + l15][g * 8];
        }
        #pragma unroll
        for (int j = 0; j < FN; ++j)
            bh[j] = *(bf8*)&sB[wn + j * 16 + l15][g * 8];
        #pragma unroll
        for (int i = 0; i < FM; ++i)
            #pragma unroll
            for (int j = 0; j < FN; ++j)
                acc[i][j] = __builtin_amdgcn_mfma_f32_16x16x32_bf16(ah[i], bh[j], acc[i][j], 0, 0, 0);
        #pragma unroll
        for (int i = 0; i < FM; ++i)
            #pragma unroll
            for (int j = 0; j < FN; ++j)
                acc[i][j] = __builtin_amdgcn_mfma_f32_16x16x32_bf16(al_[i], bh[j], acc[i][j], 0, 0, 0);
        __syncthreads();
    }
    #pragma unroll
    for (int i = 0; i < FM; ++i)
        #pragma unroll
        for (int r = 0; r < 4; ++r) {
            float sum = acc[i][0][r];
            #pragma unroll
            for (int j = 1; j < FN; ++j) sum += acc[i][j][r];
            sum += __shfl_xor(sum, 1);
            sum += __shfl_xor(sum, 2);
            sum += __shfl_xor(sum, 4);
            sum += __shfl_xor(sum, 8);
            if (l15 == 0)
                unsafeAtomicAdd(pooled + bm0 + wm + i * 16 + g * 4 + r, sum * pscale);
        }
}

// ------- RMSNorm: writes packed hi/lo bf16 xn; adds h0 row-sums to pooled -----
__global__ __launch_bounds__(256) void rms_kernel(
    const float* __restrict__ h0, const float* __restrict__ w,
    uint_t* __restrict__ xn_pk, float* __restrict__ pooled)
{
    const int row = blockIdx.x;
    const float* p = h0 + (size_t)row * DM;
    const int tid = threadIdx.x;
    float v0 = p[tid], v1 = p[tid + 256];
    float ss = v0 * v0 + v1 * v1;
    float sm = v0 + v1;
    #pragma unroll
    for (int m = 32; m; m >>= 1) {
        ss += __shfl_xor(ss, m);
        sm += __shfl_xor(sm, m);
    }
    __shared__ float wss[4], wsm[4];
    if ((tid & 63) == 0) { wss[tid >> 6] = ss; wsm[tid >> 6] = sm; }
    __syncthreads();
    const float tot = wss[0] + wss[1] + wss[2] + wss[3];
    if (tid == 0)
        unsafeAtomicAdd(pooled + row, (wsm[0] + wsm[1] + wsm[2] + wsm[3]) * (1.0f / DM));
    const float scale = rsqrtf(tot * (1.0f / DM) + 1e-5f);
    xn_pk[(size_t)row * DM + tid]       = packf(v0 * scale * w[tid]);
    xn_pk[(size_t)row * DM + tid + 256] = packf(v1 * scale * w[tid + 256]);
}

// -------- causal depthwise conv (DC=4) + SiLU, bf16 in / bf16 out, transposed -
__global__ __launch_bounds__(256) void conv_tr_kernel(
    const ushort_t* __restrict__ xr, const float* __restrict__ cw,
    const float* __restrict__ cb, ushort_t* __restrict__ xp_bf,
    ushort_t* __restrict__ res_bf)
{
    __shared__ float tp[64][65];
    __shared__ float tr[64][65];
    const int di0 = blockIdx.x * 64;
    const int t0  = blockIdx.y * 64;
    const int b   = blockIdx.z;
    const int c  = threadIdx.x & 63;
    const int r4 = threadIdx.x >> 6;
    const int di = di0 + c;
    const float bias = cb[di];
    float w0 = cw[di * DC + 0], w1 = cw[di * DC + 1],
          w2 = cw[di * DC + 2], w3 = cw[di * DC + 3];
    #pragma unroll
    for (int rr = 0; rr < 64; rr += 4) {
        const int t = t0 + rr + r4;
        const int bt = b * Tt + t;
        float acc = bias;
        if (t >= 3) {
            acc = fmaf(w0, bf16_tof(xr[(size_t)(bt - 3) * (2 * DI) + di]), acc);
            acc = fmaf(w1, bf16_tof(xr[(size_t)(bt - 2) * (2 * DI) + di]), acc);
            acc = fmaf(w2, bf16_tof(xr[(size_t)(bt - 1) * (2 * DI) + di]), acc);
        } else {
            if (t >= 1) acc = fmaf(w2, bf16_tof(xr[(size_t)(bt - 1) * (2 * DI) + di]), acc);
            if (t >= 2) acc = fmaf(w1, bf16_tof(xr[(size_t)(bt - 2) * (2 * DI) + di]), acc);
        }
        acc = fmaf(w3, bf16_tof(xr[(size_t)bt * (2 * DI) + di]), acc);
        tp[rr + r4][c] = silu_fast(acc);
        tr[rr + r4][c] = bf16_tof(xr[(size_t)bt * (2 * DI) + DI + di]);
    }
    __syncthreads();
    #pragma unroll
    for (int dd = 0; dd < 64; dd += 4) {
        const int dw = dd + r4;
        const size_t o = ((size_t)b * DI + di0 + dw) * Tt + t0 + c;
        xp_bf[o]  = bf16_rne(tp[c][dw]);
        res_bf[o] = bf16_rne(tr[c][dw]);
    }
}

// ============= fused single-pass selective scan (256 thr, 8 di/block) =========
__global__ __launch_bounds__(256) void scan_fused(
    const float* __restrict__ deltaT, const float* __restrict__ xdbl,
    const ushort_t* __restrict__ xp_bf, const ushort_t* __restrict__ res_bf,
    const float* __restrict__ A_log, const float* __restrict__ Dvec,
    uint_t* __restrict__ y_pk)
{
    __shared__ uint_t   sBC[2][DS][68];   // [buf][s][t]: {C bf16 hi | B bf16 lo}
    __shared__ float    sD [2][8][68];    // fp32 d (exponent path)
    __shared__ float    sDU[2][8][68];    // fp32 d*u
    __shared__ ushort_t sU [2][8][68];    // bf16 u (D-skip)
    __shared__ ushort_t sR [2][8][68];    // bf16 res (gate)
    __shared__ float ylds[CL][9];
    const int tid = threadIdx.x;
    const int grp = tid >> 5;            // 0..7 : di within block
    const int l5 = tid & 31;
    const int s = ((l5 & 1) << 4) | (l5 >> 1);   // lane remap: s^16 <-> l^1 (quad DPP)
    const int b = blockIdx.x >> 7;
    const int di0 = (blockIdx.x & 127) << 3;
    const int sd_r = tid >> 5;           // 0..7
    const int sd_t = (tid & 31) << 1;    // 0..62
    const int bc_t = tid >> 2;           // 0..63
    const int bc_s = (tid & 3) << 3;     // 0,8,16,24

    float2 rd2;
    uint_t ru, rr_;
    float4 rB[2], rC[2];
    auto stage_regs = [&](int c) {
        const size_t rb = ((size_t)(b * DI + di0 + sd_r)) * Tt + c * CL + sd_t;
        rd2 = *(const float2*)(deltaT + rb);
        ru  = *(const uint_t*)(xp_bf + rb);
        rr_ = *(const uint_t*)(res_bf + rb);
        const float* src = xdbl + ((size_t)b * Tt + c * CL + bc_t) * 96;
        rB[0] = *(const float4*)(src + 32 + bc_s);
        rB[1] = *(const float4*)(src + 32 + bc_s + 4);
        rC[0] = *(const float4*)(src + 64 + bc_s);
        rC[1] = *(const float4*)(src + 64 + bc_s + 4);
    };
    auto write_lds = [&](int bb) {
        *(float2*)&sD[bb][sd_r][sd_t] = rd2;
        const float u0 = bf16_tof((ushort_t)(ru & 0xFFFFu));
        const float u1 = bf16_tof((ushort_t)(ru >> 16));
        float2 du2;
        du2.x = rd2.x * u0;
        du2.y = rd2.y * u1;
        *(float2*)&sDU[bb][sd_r][sd_t] = du2;
        *(uint_t*)&sU[bb][sd_r][sd_t] = ru;
        *(uint_t*)&sR[bb][sd_r][sd_t] = rr_;
        const float bv[8] = {rB[0].x, rB[0].y, rB[0].z, rB[0].w,
                             rB[1].x, rB[1].y, rB[1].z, rB[1].w};
        const float cv[8] = {rC[0].x, rC[0].y, rC[0].z, rC[0].w,
                             rC[1].x, rC[1].y, rC[1].z, rC[1].w};
        #pragma unroll
        for (int j = 0; j < 8; ++j)
            sBC[bb][bc_s + j][bc_t] =
                ((uint_t)bf16_rne(cv[j]) << 16) | (uint_t)bf16_rne(bv[j]);
    };

    const bool s4b = (l5 & 1) != 0;
    const bool s0b = (l5 & 2) != 0;
    const bool s1b = (l5 & 4) != 0;
    const bool s2b = (l5 & 8) != 0;
    const bool s3b = (l5 & 16) != 0;
    const int di = di0 + grp;
    const float Ads2 = -expf(A_log[di * DS + s]) * 1.44269504f;
    const float Dv = Dvec[di];
    float h = 0.f;

    stage_regs(0);
    write_lds(0);
    #pragma unroll 1
    for (int c = 0; c < NCH; ++c) {
        const int bb = c & 1;
        __syncthreads();
        if (c < NCH - 1) stage_regs(c + 1);
        #pragma unroll 1
        for (int t0 = 0; t0 < CL; t0 += 32) {
            float buf[16] = {};
            uint4 bc_c = *(const uint4*)&sBC[bb][s][t0];
            float4 dv_c = *(const float4*)&sD[bb][grp][t0];
            float4 du_c = *(const float4*)&sDU[bb][grp][t0];
            #pragma unroll
            for (int tq = 0; tq < 8; ++tq) {
                uint4 bc_n;
                float4 dv_n, du_n;
                if (tq < 7) {
                    const int tb = t0 + tq * 4 + 4;
                    bc_n = *(const uint4*)&sBC[bb][s][tb];
                    dv_n = *(const float4*)&sD[bb][grp][tb];
                    du_n = *(const float4*)&sDU[bb][grp][tb];
                }
                const uint_t bcv[4] = {bc_c.x, bc_c.y, bc_c.z, bc_c.w};
                const float dv[4] = {dv_c.x, dv_c.y, dv_c.z, dv_c.w};
                const float duv[4] = {du_c.x, du_c.y, du_c.z, du_c.w};
                #pragma unroll
                for (int q = 0; q < 4; ++q) {
                    const int tl = tq * 4 + q;
                    const float Bq = __uint_as_float(bcv[q] << 16);
                    const float Cq = __uint_as_float(bcv[q] & 0xFFFF0000u);
                    h = fmaf(__builtin_amdgcn_exp2f(dv[q] * Ads2), h, duv[q] * Bq);
                    const float ps = h * Cq;
                    const float pr = ps + qperm<0xB1>(ps);
                    const bool keep = ((tl & 16) != 0) == s4b;
                    buf[tl & 15] = keep ? pr : buf[tl & 15];
                }
                if (tq < 7) { bc_c = bc_n; dv_c = dv_n; du_c = du_n; }
            }
            #pragma unroll
            for (int i = 0; i < 16; ++i) buf[i] += qperm<0x4E>(buf[i]);
            float r8[8];
            #pragma unroll
            for (int i = 0; i < 8; ++i) r8[i] = s0b ? buf[2 * i + 1] : buf[2 * i];
            #pragma unroll
            for (int i = 0; i < 8; ++i) r8[i] += swz<0x101F>(r8[i]);
            float w4[4];
            #pragma unroll
            for (int i = 0; i < 4; ++i) w4[i] = s1b ? r8[2 * i + 1] : r8[2 * i];
            #pragma unroll
            for (int i = 0; i < 4; ++i) w4[i] += swz<0x201F>(w4[i]);
            float v2[2];
            v2[0] = s2b ? w4[1] : w4[0];
            v2[1] = s2b ? w4[3] : w4[2];
            v2[0] += swz<0x401F>(v2[0]);
            v2[1] += swz<0x401F>(v2[1]);
            const float yv = s3b ? v2[1] : v2[0];
            const float uself = bf16_tof(sU[bb][grp][t0 + s]);
            const float rself = bf16_tof(sR[bb][grp][t0 + s]);
            ylds[t0 + s][grp] = fmaf(uself, Dv, yv) * silu_fast(rself);
        }
        __syncthreads();
        {
            const int row = tid >> 2;
            const int q2 = (tid & 3) << 1;
            uint2 o;
            o.x = packf(ylds[row][q2 + 0]);
            o.y = packf(ylds[row][q2 + 1]);
            *(uint2*)(y_pk + ((size_t)b * Tt + c * CL + row) * DI + di0 + q2) = o;
        }
        if (c < NCH - 1) write_lds(bb ^ 1);
    }
}

// ---------------- classifier ---------------------------------------------------
__global__ __launch_bounds__(256) void cls_kernel(
    const float* __restrict__ pooled, const float* __restrict__ w_cls,
    const float* __restrict__ b_cls, float* __restrict__ out)
{
    const int idx = blockIdx.x * 256 + threadIdx.x;
    if (idx >= Bb * NC) return;
    const int b = idx / NC, c = idx % NC;
    float acc = b_cls[c];
    for (int t = 0; t < DM; ++t)
        acc = fmaf(pooled[b * DM + t], w_cls[t * NC + c], acc);
    out[idx] = acc;
}

extern "C" void kernel_launch(void* const* d_in, const int* in_sizes, int n_in,
                              void* d_out, int out_size, void* d_ws, size_t ws_size,
                              hipStream_t stream) {
    const float* x      = (const float*)d_in[0];
    const float* w_proj = (const float*)d_in[1];
    const float* b_proj = (const float*)d_in[2];
    const float* rms_w  = (const float*)d_in[3];
    const float* w_in   = (const float*)d_in[4];
    const float* conv_w = (const float*)d_in[5];
    const float* conv_b = (const float*)d_in[6];
    const float* w_xprj = (const float*)d_in[7];
    const float* w_dt   = (const float*)d_in[8];
    const float* b_dt   = (const float*)d_in[9];
    const float* A_log  = (const float*)d_in[10];
    const float* Dvec   = (const float*)d_in[11];
    const float* w_out  = (const float*)d_in[12];
    const float* w_cls  = (const float*)d_in[13];
    const float* b_cls  = (const float*)d_in[14];
    float* out = (float*)d_out;

    float* ws = (float*)d_ws;
    float* h0     = ws;
    float* xn     = h0 + (size_t)BT * DM;          // holds xn_pk (uint)
    float* xr     = xn + (size_t)BT * DM;          // region: xr_bf16 -> deltaT, y_pk
    float* xpT    = xr + (size_t)BT * 2 * DI;      // holds xp_bf (ushort)
    float* resT   = xpT + (size_t)Bb * DI * Tt;    // holds res_bf (ushort)
    float* xdbl   = resT + (size_t)Bb * DI * Tt;
    float* pooled = xdbl + (size_t)BT * 96;
    float* wsplit = pooled + 4096;                 // weight-split scratch
    float* deltaT = xr;                            // alias: xr_bf dead after conv_tr
    uint_t* y_pk  = (uint_t*)(xr + (size_t)Bb * DI * Tt);  // upper half of xr region
    uint_t* xn_pk = (uint_t*)xn;
    ushort_t* xr_bf  = (ushort_t*)xr;
    ushort_t* xp_bf  = (ushort_t*)xpT;
    ushort_t* res_bf = (ushort_t*)resT;

    // weight splits (bf16 hi/lo, transposed to [n][k]) + packed x:
    ushort_t* w_in_hi  = (ushort_t*)wsplit;
    ushort_t* w_in_lo  = w_in_hi + (size_t)(2 * DI) * DM;
    ushort_t* w_out_hi = w_in_lo + (size_t)(2 * DI) * DM;
    ushort_t* w_out_lo = w_out_hi + (size_t)DM * DI;
    ushort_t* w_xp_hi  = w_out_lo + (size_t)DM * DI;
    ushort_t* w_xp_lo  = w_xp_hi + (size_t)96 * DI;
    ushort_t* w_pj_hi  = w_xp_lo + (size_t)96 * DI;
    ushort_t* w_pj_lo  = w_pj_hi + (size_t)DM * NM;
    ushort_t* w_dt_hi  = w_pj_lo + (size_t)DM * NM;
    ushort_t* w_dt_lo  = w_dt_hi + (size_t)DI * DR;
    uint_t*   x_pk     = (uint_t*)(w_dt_lo + (size_t)DI * DR);

    // 0) ONE prep launch: all splits + x pack + zero of xdbl+pooled
    prep_kernel<<<3776, 256, 0, stream>>>(
        x, w_in, w_out, w_xprj, w_proj, w_dt, x_pk,
        w_in_hi, w_in_lo, w_out_hi, w_out_lo, w_xp_hi, w_xp_lo,
        w_pj_hi, w_pj_lo, w_dt_hi, w_dt_lo,
        (float4*)xdbl, (BT * 96 + 4096) / 4);
    // 1) h0 = x @ w_proj + b_proj   (3-pass MFMA)
    gemm_mfma_h0<<<dim3(DM / 128, BT / 128), 512, 0, stream>>>(
        x_pk, w_pj_hi, w_pj_lo, b_proj, h0);
    // 2) xn_pk = pack(rmsnorm(h0) * rms_w); pooled += rowsum(h0)/DM
    rms_kernel<<<BT, 256, 0, stream>>>(h0, rms_w, xn_pk, pooled);
    // 3) xr_bf = bf16(xn @ w_in)    (single-pass bf16 MFMA, 8-wave blocks)
    gemm_mfma_big<<<dim3(2 * DI / 128, BT / 128), 512, 0, stream>>>(
        xn_pk, DM, w_in_hi, xr_bf, 2 * DI, DM);
    // 4) xp_bf = bf16(silu(causal_dwconv(xr[:, :DI])))^T ; res_bf = xr[:, DI:]^T
    conv_tr_kernel<<<dim3(DI / 64, Tt / 64, Bb), 256, 0, stream>>>(
        xr_bf, conv_w, conv_b, xp_bf, res_bf);
    // 5) xdbl += xp @ w_xproj   (single-pass bf16 MFMA, split-K=8, atomics)
    gemm_mfma_x<<<dim3(1, BT / 64, 8), 256, 0, stream>>>(
        xp_bf, w_xp_hi, xdbl, DI, DI / 8);
    // 6) deltaT = softplus(xdbl[:, :32] @ w_dt + b_dt)^T   (3-pass, one K step)
    gemm_mfma_dt<<<dim3(DI / 64, BT / 64), 256, 0, stream>>>(
        xdbl, w_dt_hi, w_dt_lo, b_dt, deltaT);
    // 7) fused single-pass selective scan (h in registers across chunks)
    scan_fused<<<Bb * (DI / 8), 256, 0, stream>>>(
        deltaT, xdbl, xp_bf, res_bf, A_log, Dvec, y_pk);
    // 8) pooled += rowsum(y @ w_out)/DM   (2-pass MFMA + split-K=4 + mean-pool)
    gemm_mfma_pool<<<dim3(DM / 64, BT / 64, 4), 256, 0, stream>>>(
        y_pk, DI, w_out_hi, pooled, 1.0f / DM, DM, DI, DI / 4);
    // 9) out = pooled @ w_cls + b_cls
    cls_kernel<<<(Bb * NC + 255) / 256, 256, 0, stream>>>(pooled, w_cls, b_cls, out);
}

// Round 18
// 222.630 us; speedup vs baseline: 1.6726x; 1.0391x over previous
//
#include <hip/hip_runtime.h>
#include <hip/hip_bf16.h>
#include <cstddef>

#define Bb 8
#define Tt 512
#define NM 128
#define DM 512
#define DI 1024
#define DS 32
#define DR 32
#define DC 4
#define NC 100
#define BT (Bb*Tt)     // 4096
#define NCH 8          // scan chunks
#define CL  64         // chunk length

typedef unsigned short ushort_t;
typedef unsigned int uint_t;
typedef __attribute__((ext_vector_type(8))) short bf8;    // 8 bf16 in 4 VGPRs
typedef __attribute__((ext_vector_type(4))) float f4;

__device__ __forceinline__ float softplus_f(float x) {
    return fmaxf(x, 0.f) + log1pf(expf(-fabsf(x)));
}
__device__ __forceinline__ float silu_fast(float x) {
    return __fdividef(x, 1.f + __expf(-x));
}
__device__ __forceinline__ ushort_t bf16_rne(float x) {
    uint_t u = __float_as_uint(x);
    uint_t r = u + 0x7FFFu + ((u >> 16) & 1u);
    return (ushort_t)(r >> 16);
}
__device__ __forceinline__ float bf16_tof(ushort_t h) {
    return __uint_as_float(((uint_t)h) << 16);
}
// pack fp32 -> {hi bf16 in [31:16], lo bf16 in [15:0]}
__device__ __forceinline__ uint_t packf(float v) {
    ushort_t h = bf16_rne(v);
    ushort_t l = bf16_rne(v - bf16_tof(h));
    return ((uint_t)h << 16) | (uint_t)l;
}
// cross-lane: quad_perm DPP (VALU pipe) and ds_swizzle (DS pipe)
template<int CTRL>
__device__ __forceinline__ float qperm(float x) {
    return __int_as_float(__builtin_amdgcn_mov_dpp(__float_as_int(x), CTRL, 0xF, 0xF, true));
}
template<int PAT>
__device__ __forceinline__ float swz(float x) {
    return __int_as_float(__builtin_amdgcn_ds_swizzle(__float_as_int(x), PAT));
}

// ===== unified prep: all weight splits + x pack + zero-init, ONE launch =======
__global__ __launch_bounds__(256) void prep_kernel(
    const float* __restrict__ x, const float* __restrict__ w_in,
    const float* __restrict__ w_out, const float* __restrict__ w_xp,
    const float* __restrict__ w_pj, const float* __restrict__ w_dt,
    uint_t* __restrict__ x_pk,
    ushort_t* __restrict__ w_in_hi, ushort_t* __restrict__ w_in_lo,
    ushort_t* __restrict__ w_out_hi, ushort_t* __restrict__ w_out_lo,
    ushort_t* __restrict__ w_xp_hi, ushort_t* __restrict__ w_xp_lo,
    ushort_t* __restrict__ w_pj_hi, ushort_t* __restrict__ w_pj_lo,
    ushort_t* __restrict__ w_dt_hi, ushort_t* __restrict__ w_dt_lo,
    float4* __restrict__ zbase, int zcount)
{
    __shared__ ushort_t th[32][34], tl[32][34];
    const int bid = blockIdx.x;
    const float* src;
    ushort_t *hi, *lo;
    int K, N, bx, by;
    if (bid < 1024)      { src = w_in;  hi = w_in_hi;  lo = w_in_lo;  K = DM; N = 2 * DI; bx = bid & 63; by = bid >> 6; }
    else if (bid < 1536) { const int i = bid - 1024; src = w_out; hi = w_out_hi; lo = w_out_lo; K = DI; N = DM; bx = i & 15; by = i >> 4; }
    else if (bid < 1632) { const int i = bid - 1536; src = w_xp;  hi = w_xp_hi;  lo = w_xp_lo;  K = DI; N = 96; bx = i % 3; by = i / 3; }
    else if (bid < 1696) { const int i = bid - 1632; src = w_pj;  hi = w_pj_hi;  lo = w_pj_lo;  K = NM; N = DM; bx = i & 15; by = i >> 4; }
    else if (bid < 1728) { const int i = bid - 1696; src = w_dt;  hi = w_dt_hi;  lo = w_dt_lo;  K = DR; N = DI; bx = i; by = 0; }
    else {
        const int e = (bid - 1728) * 256 + threadIdx.x;   // 2048*256 = BT*NM
        x_pk[e] = packf(x[e]);
        if (e < zcount) zbase[e] = make_float4(0.f, 0.f, 0.f, 0.f);
        return;
    }
    const int k0 = by * 32, n0 = bx * 32;
    #pragma unroll
    for (int it = 0; it < 4; ++it) {
        const int idx = it * 256 + threadIdx.x;
        const int r = idx >> 5, c = idx & 31;
        const float v = src[(size_t)(k0 + r) * N + n0 + c];
        const ushort_t h = bf16_rne(v);
        th[c][r] = h;
        tl[c][r] = bf16_rne(v - bf16_tof(h));
    }
    __syncthreads();
    #pragma unroll
    for (int it = 0; it < 4; ++it) {
        const int idx = it * 256 + threadIdx.x;
        const int r = idx >> 5, c = idx & 31;
        hi[(size_t)(n0 + r) * K + k0 + c] = th[r][c];
        lo[(size_t)(n0 + r) * K + k0 + c] = tl[r][c];
    }
}

// ---- step1: h0 = x @ w_proj + b_proj (3-pass MFMA, 512 thr, 128x128 tile) ---
__global__ __launch_bounds__(512) void gemm_mfma_h0(
    const uint_t* __restrict__ Apk,
    const ushort_t* __restrict__ Bhi, const ushort_t* __restrict__ Blo,
    const float* __restrict__ bias, float* __restrict__ C)
{
    constexpr int FM = 2, FN = 4;
    constexpr int K = NM, N = DM;
    __shared__ ushort_t sA[2][128][40];
    __shared__ ushort_t sB[2][128][40];
    const int tid = threadIdx.x;
    const int wid = tid >> 6, l = tid & 63, l15 = l & 15, g = l >> 4;
    const int wm = (wid >> 1) * 32, wn = (wid & 1) * 64;
    const int bm0 = blockIdx.y * 128, bn0 = blockIdx.x * 128;

    f4 acc[FM][FN] = {};
    uint4 aR[2], bRh, bRl;

    auto loadG = [&](int k0) {
        #pragma unroll
        for (int r = 0; r < 2; ++r) {
            const int idx = r * 2048 + tid * 4;
            const int m = idx >> 5, k = idx & 31;
            aR[r] = *(const uint4*)(Apk + (size_t)(bm0 + m) * K + k0 + k);
        }
        {
            const int idx = tid * 8;
            const int n = idx >> 5, k = idx & 31;
            const size_t o = (size_t)(bn0 + n) * K + k0 + k;
            bRh = *(const uint4*)(Bhi + o);
            bRl = *(const uint4*)(Blo + o);
        }
    };
    auto stoL = [&]() {
        #pragma unroll
        for (int r = 0; r < 2; ++r) {
            const int idx = r * 2048 + tid * 4;
            const int m = idx >> 5, k = idx & 31;
            uint2 hh, ll;
            hh.x = (aR[r].x >> 16) | (aR[r].y & 0xFFFF0000u);
            hh.y = (aR[r].z >> 16) | (aR[r].w & 0xFFFF0000u);
            ll.x = (aR[r].x & 0xFFFFu) | (aR[r].y << 16);
            ll.y = (aR[r].z & 0xFFFFu) | (aR[r].w << 16);
            *(uint2*)&sA[0][m][k] = hh;
            *(uint2*)&sA[1][m][k] = ll;
        }
        {
            const int idx = tid * 8;
            const int n = idx >> 5, k = idx & 31;
            *(uint4*)&sB[0][n][k] = bRh;
            *(uint4*)&sB[1][n][k] = bRl;
        }
    };

    loadG(0);
    for (int k0 = 0; k0 < K; k0 += 32) {
        stoL();
        __syncthreads();
        if (k0 + 32 < K) loadG(k0 + 32);
        bf8 ah[FM], al_[FM], bh[FN], bl_[FN];
        #pragma unroll
        for (int i = 0; i < FM; ++i) {
            ah[i]  = *(bf8*)&sA[0][wm + i * 16 + l15][g * 8];
            al_[i] = *(bf8*)&sA[1][wm + i * 16 + l15][g * 8];
        }
        #pragma unroll
        for (int j = 0; j < FN; ++j) {
            bh[j]  = *(bf8*)&sB[0][wn + j * 16 + l15][g * 8];
            bl_[j] = *(bf8*)&sB[1][wn + j * 16 + l15][g * 8];
        }
        #pragma unroll
        for (int i = 0; i < FM; ++i)
            #pragma unroll
            for (int j = 0; j < FN; ++j)
                acc[i][j] = __builtin_amdgcn_mfma_f32_16x16x32_bf16(ah[i], bh[j], acc[i][j], 0, 0, 0);
        #pragma unroll
        for (int i = 0; i < FM; ++i)
            #pragma unroll
            for (int j = 0; j < FN; ++j)
                acc[i][j] = __builtin_amdgcn_mfma_f32_16x16x32_bf16(al_[i], bh[j], acc[i][j], 0, 0, 0);
        #pragma unroll
        for (int i = 0; i < FM; ++i)
            #pragma unroll
            for (int j = 0; j < FN; ++j)
                acc[i][j] = __builtin_amdgcn_mfma_f32_16x16x32_bf16(ah[i], bl_[j], acc[i][j], 0, 0, 0);
        __syncthreads();
    }
    #pragma unroll
    for (int i = 0; i < FM; ++i)
        #pragma unroll
        for (int j = 0; j < FN; ++j)
            #pragma unroll
            for (int r = 0; r < 4; ++r) {
                const int m = bm0 + wm + i * 16 + g * 4 + r;
                const int n = bn0 + wn + j * 16 + l15;
                C[(size_t)m * N + n] = acc[i][j][r] + bias[n];
            }
}

// ---- step6: deltaT = softplus(xdbl[:, :32] @ w_dt + b_dt)^T  (one K step) ---
__global__ __launch_bounds__(256) void gemm_mfma_dt(
    const float* __restrict__ xdbl,
    const ushort_t* __restrict__ Bhi, const ushort_t* __restrict__ Blo,
    const float* __restrict__ bias, float* __restrict__ dT)
{
    constexpr int FM = 2, FN = 2;
    __shared__ ushort_t sA[2][64][40];
    __shared__ ushort_t sB[2][64][40];
    const int tid = threadIdx.x;
    const int wid = tid >> 6, l = tid & 63, l15 = l & 15, g = l >> 4;
    const int wm = (wid >> 1) * 32, wn = (wid & 1) * 32;
    const int bm0 = blockIdx.y * 64, bn0 = blockIdx.x * 64;

    #pragma unroll
    for (int r = 0; r < 2; ++r) {
        const int idx = r * 1024 + tid * 4;
        const int m = idx >> 5, k = idx & 31;
        const float4 v = *(const float4*)(xdbl + (size_t)(bm0 + m) * 96 + k);
        const float vv[4] = {v.x, v.y, v.z, v.w};
        #pragma unroll
        for (int q = 0; q < 4; ++q) {
            const ushort_t h = bf16_rne(vv[q]);
            sA[0][m][k + q] = h;
            sA[1][m][k + q] = bf16_rne(vv[q] - bf16_tof(h));
        }
    }
    {
        const int idx = tid * 8;
        const int n = idx >> 5, k = idx & 31;
        *(uint4*)&sB[0][n][k] = *(const uint4*)(Bhi + (size_t)(bn0 + n) * 32 + k);
        *(uint4*)&sB[1][n][k] = *(const uint4*)(Blo + (size_t)(bn0 + n) * 32 + k);
    }
    __syncthreads();
    f4 acc[FM][FN] = {};
    bf8 ah[FM], al_[FM], bh[FN], bl_[FN];
    #pragma unroll
    for (int i = 0; i < FM; ++i) {
        ah[i]  = *(bf8*)&sA[0][wm + i * 16 + l15][g * 8];
        al_[i] = *(bf8*)&sA[1][wm + i * 16 + l15][g * 8];
    }
    #pragma unroll
    for (int j = 0; j < FN; ++j) {
        bh[j]  = *(bf8*)&sB[0][wn + j * 16 + l15][g * 8];
        bl_[j] = *(bf8*)&sB[1][wn + j * 16 + l15][g * 8];
    }
    #pragma unroll
    for (int i = 0; i < FM; ++i)
        #pragma unroll
        for (int j = 0; j < FN; ++j) {
            acc[i][j] = __builtin_amdgcn_mfma_f32_16x16x32_bf16(ah[i], bh[j], acc[i][j], 0, 0, 0);
            acc[i][j] = __builtin_amdgcn_mfma_f32_16x16x32_bf16(al_[i], bh[j], acc[i][j], 0, 0, 0);
            acc[i][j] = __builtin_amdgcn_mfma_f32_16x16x32_bf16(ah[i], bl_[j], acc[i][j], 0, 0, 0);
        }
    #pragma unroll
    for (int i = 0; i < FM; ++i)
        #pragma unroll
        for (int j = 0; j < FN; ++j) {
            const int n = bn0 + wn + j * 16 + l15;
            const int m0 = bm0 + wm + i * 16 + g * 4;
            const float bn = bias[n];
            float4 o;
            o.x = softplus_f(acc[i][j][0] + bn);
            o.y = softplus_f(acc[i][j][1] + bn);
            o.z = softplus_f(acc[i][j][2] + bn);
            o.w = softplus_f(acc[i][j][3] + bn);
            *(float4*)(dT + ((size_t)(m0 >> 9) * DI + n) * Tt + (m0 & 511)) = o;
        }
}

// ---- single-pass bf16 MFMA GEMM, 512 thr / 8 waves, 128x128 tile, bf16 C ----
__global__ __launch_bounds__(512) void gemm_mfma_big(
    const uint_t* __restrict__ Apk, int lda,
    const ushort_t* __restrict__ Bhi,
    ushort_t* __restrict__ C, int N, int K)
{
    constexpr int FM = 2, FN = 4;
    __shared__ ushort_t sA[128][40];
    __shared__ ushort_t sB[128][40];
    const int tid = threadIdx.x;
    const int wid = tid >> 6, l = tid & 63, l15 = l & 15, g = l >> 4;
    const int wm = (wid >> 1) * 32, wn = (wid & 1) * 64;
    const int bm0 = blockIdx.y * 128, bn0 = blockIdx.x * 128;

    f4 acc[FM][FN] = {};
    uint4 aR[2], bRh;

    auto loadG = [&](int k0) {
        #pragma unroll
        for (int r = 0; r < 2; ++r) {
            const int idx = r * 2048 + tid * 4;
            const int m = idx >> 5, k = idx & 31;
            aR[r] = *(const uint4*)(Apk + (size_t)(bm0 + m) * lda + k0 + k);
        }
        {
            const int idx = tid * 8;
            const int n = idx >> 5, k = idx & 31;
            bRh = *(const uint4*)(Bhi + (size_t)(bn0 + n) * K + k0 + k);
        }
    };
    auto stoL = [&]() {
        #pragma unroll
        for (int r = 0; r < 2; ++r) {
            const int idx = r * 2048 + tid * 4;
            const int m = idx >> 5, k = idx & 31;
            uint2 hh;
            hh.x = (aR[r].x >> 16) | (aR[r].y & 0xFFFF0000u);
            hh.y = (aR[r].z >> 16) | (aR[r].w & 0xFFFF0000u);
            *(uint2*)&sA[m][k] = hh;
        }
        {
            const int idx = tid * 8;
            const int n = idx >> 5, k = idx & 31;
            *(uint4*)&sB[n][k] = bRh;
        }
    };

    loadG(0);
    for (int k0 = 0; k0 < K; k0 += 32) {
        stoL();
        __syncthreads();
        if (k0 + 32 < K) loadG(k0 + 32);
        bf8 ah[FM], bh[FN];
        #pragma unroll
        for (int i = 0; i < FM; ++i)
            ah[i] = *(bf8*)&sA[wm + i * 16 + l15][g * 8];
        #pragma unroll
        for (int j = 0; j < FN; ++j)
            bh[j] = *(bf8*)&sB[wn + j * 16 + l15][g * 8];
        #pragma unroll
        for (int i = 0; i < FM; ++i)
            #pragma unroll
            for (int j = 0; j < FN; ++j)
                acc[i][j] = __builtin_amdgcn_mfma_f32_16x16x32_bf16(ah[i], bh[j], acc[i][j], 0, 0, 0);
        __syncthreads();
    }
    #pragma unroll
    for (int i = 0; i < FM; ++i)
        #pragma unroll
        for (int j = 0; j < FN; ++j)
            #pragma unroll
            for (int r = 0; r < 4; ++r) {
                const int m = bm0 + wm + i * 16 + g * 4 + r;
                const int n = bn0 + wn + j * 16 + l15;
                C[(size_t)m * N + n] = bf16_rne(acc[i][j][r]);
            }
}

// ---- step5: xdbl += xp_bf @ w_xproj  (single-pass bf16, split-K atomics) ----
__global__ __launch_bounds__(256) void gemm_mfma_x(
    const ushort_t* __restrict__ Abf,
    const ushort_t* __restrict__ Bhi,
    float* __restrict__ C, int K, int kseg)
{
    constexpr int FM = 2, FN = 3;
    __shared__ ushort_t sAx[64][40];
    __shared__ ushort_t sBx[96][40];
    const int tid = threadIdx.x;
    const int wid = tid >> 6, l = tid & 63, l15 = l & 15, g = l >> 4;
    const int wm = (wid >> 1) * 32, wn = (wid & 1) * 48;
    const int bm0 = blockIdx.y * 64;
    const int kbeg = blockIdx.z * kseg;

    f4 acc[FM][FN] = {};
    uint4 aR;
    uint2 bRh[3];

    auto loadG = [&](int k0) {
        {
            const int idx = tid * 8;
            const int m = idx >> 5, k = idx & 31;
            aR = *(const uint4*)(Abf + (size_t)(bm0 + m) * K + k0 + k);
        }
        #pragma unroll
        for (int r = 0; r < 3; ++r) {
            const int idx = r * 1024 + tid * 4;
            const int n = idx >> 5, k = idx & 31;
            bRh[r] = *(const uint2*)(Bhi + (size_t)n * K + k0 + k);
        }
    };
    auto stoL = [&]() {
        {
            const int idx = tid * 8;
            const int m = idx >> 5, k = idx & 31;
            *(uint4*)&sAx[m][k] = aR;
        }
        #pragma unroll
        for (int r = 0; r < 3; ++r) {
            const int idx = r * 1024 + tid * 4;
            const int n = idx >> 5, k = idx & 31;
            *(uint2*)&sBx[n][k] = bRh[r];
        }
    };

    loadG(kbeg);
    for (int k0 = kbeg; k0 < kbeg + kseg; k0 += 32) {
        stoL();
        __syncthreads();
        if (k0 + 32 < kbeg + kseg) loadG(k0 + 32);
        bf8 ah[FM], bh[FN];
        #pragma unroll
        for (int i = 0; i < FM; ++i)
            ah[i] = *(bf8*)&sAx[wm + i * 16 + l15][g * 8];
        #pragma unroll
        for (int j = 0; j < FN; ++j)
            bh[j] = *(bf8*)&sBx[wn + j * 16 + l15][g * 8];
        #pragma unroll
        for (int i = 0; i < FM; ++i)
            #pragma unroll
            for (int j = 0; j < FN; ++j)
                acc[i][j] = __builtin_amdgcn_mfma_f32_16x16x32_bf16(ah[i], bh[j], acc[i][j], 0, 0, 0);
        __syncthreads();
    }
    #pragma unroll
    for (int i = 0; i < FM; ++i)
        #pragma unroll
        for (int j = 0; j < FN; ++j)
            #pragma unroll
            for (int r = 0; r < 4; ++r) {
                const int m = bm0 + wm + i * 16 + g * 4 + r;
                const int n = wn + j * 16 + l15;
                unsafeAtomicAdd(&C[(size_t)m * 96 + n], acc[i][j][r]);
            }
}

// ---- single-pass MFMA GEMM (A bf16 plain, B hi), split-K, fused mean-pool ---
__global__ __launch_bounds__(256) void gemm_mfma_pool(
    const ushort_t* __restrict__ Abf, int lda,
    const ushort_t* __restrict__ Bhi,
    float* __restrict__ pooled, float pscale,
    int N, int K, int kseg)
{
    constexpr int FM = 2, FN = 2;
    __shared__ ushort_t sA[64][40];
    __shared__ ushort_t sB[64][40];
    const int tid = threadIdx.x;
    const int wid = tid >> 6, l = tid & 63, l15 = l & 15, g = l >> 4;
    const int wm = (wid >> 1) * 32, wn = (wid & 1) * 32;
    const int bm0 = blockIdx.y * 64, bn0 = blockIdx.x * 64;
    const int kbeg = blockIdx.z * kseg;

    f4 acc[FM][FN] = {};
    uint4 aR, bRh;

    auto loadG = [&](int k0) {
        {
            const int idx = tid * 8;
            const int m = idx >> 5, k = idx & 31;
            aR = *(const uint4*)(Abf + (size_t)(bm0 + m) * lda + k0 + k);
        }
        {
            const int idx = tid * 8;
            const int n = idx >> 5, k = idx & 31;
            bRh = *(const uint4*)(Bhi + (size_t)(bn0 + n) * K + k0 + k);
        }
    };
    auto stoL = [&]() {
        {
            const int idx = tid * 8;
            const int m = idx >> 5, k = idx & 31;
            *(uint4*)&sA[m][k] = aR;
        }
        {
            const int idx = tid * 8;
            const int n = idx >> 5, k = idx & 31;
            *(uint4*)&sB[n][k] = bRh;
        }
    };

    loadG(kbeg);
    for (int k0 = kbeg; k0 < kbeg + kseg; k0 += 32) {
        stoL();
        __syncthreads();
        if (k0 + 32 < kbeg + kseg) loadG(k0 + 32);
        bf8 ah[FM], bh[FN];
        #pragma unroll
        for (int i = 0; i < FM; ++i)
            ah[i] = *(bf8*)&sA[wm + i * 16 + l15][g * 8];
        #pragma unroll
        for (int j = 0; j < FN; ++j)
            bh[j] = *(bf8*)&sB[wn + j * 16 + l15][g * 8];
        #pragma unroll
        for (int i = 0; i < FM; ++i)
            #pragma unroll
            for (int j = 0; j < FN; ++j)
                acc[i][j] = __builtin_amdgcn_mfma_f32_16x16x32_bf16(ah[i], bh[j], acc[i][j], 0, 0, 0);
        __syncthreads();
    }
    #pragma unroll
    for (int i = 0; i < FM; ++i)
        #pragma unroll
        for (int r = 0; r < 4; ++r) {
            float sum = acc[i][0][r];
            #pragma unroll
            for (int j = 1; j < FN; ++j) sum += acc[i][j][r];
            sum += __shfl_xor(sum, 1);
            sum += __shfl_xor(sum, 2);
            sum += __shfl_xor(sum, 4);
            sum += __shfl_xor(sum, 8);
            if (l15 == 0)
                unsafeAtomicAdd(pooled + bm0 + wm + i * 16 + g * 4 + r, sum * pscale);
        }
}

// ------- RMSNorm: writes packed hi/lo bf16 xn; adds h0 row-sums to pooled -----
__global__ __launch_bounds__(256) void rms_kernel(
    const float* __restrict__ h0, const float* __restrict__ w,
    uint_t* __restrict__ xn_pk, float* __restrict__ pooled)
{
    const int row = blockIdx.x;
    const float* p = h0 + (size_t)row * DM;
    const int tid = threadIdx.x;
    float v0 = p[tid], v1 = p[tid + 256];
    float ss = v0 * v0 + v1 * v1;
    float sm = v0 + v1;
    #pragma unroll
    for (int m = 32; m; m >>= 1) {
        ss += __shfl_xor(ss, m);
        sm += __shfl_xor(sm, m);
    }
    __shared__ float wss[4], wsm[4];
    if ((tid & 63) == 0) { wss[tid >> 6] = ss; wsm[tid >> 6] = sm; }
    __syncthreads();
    const float tot = wss[0] + wss[1] + wss[2] + wss[3];
    if (tid == 0)
        unsafeAtomicAdd(pooled + row, (wsm[0] + wsm[1] + wsm[2] + wsm[3]) * (1.0f / DM));
    const float scale = rsqrtf(tot * (1.0f / DM) + 1e-5f);
    xn_pk[(size_t)row * DM + tid]       = packf(v0 * scale * w[tid]);
    xn_pk[(size_t)row * DM + tid + 256] = packf(v1 * scale * w[tid + 256]);
}

// -------- causal depthwise conv (DC=4) + SiLU, vectorized di-pair version ----
// block: 128 di x 64 t; uint loads (2 di), bf16-packed LDS, uint stores (2 t).
__global__ __launch_bounds__(256) void conv_tr_kernel(
    const ushort_t* __restrict__ xr, const float* __restrict__ cw,
    const float* __restrict__ cb, ushort_t* __restrict__ xp_bf,
    ushort_t* __restrict__ res_bf)
{
    __shared__ uint_t sp[64][65];   // [t][di-pair]: silu(conv) bf16 x2
    __shared__ uint_t sg[64][65];   // gate bf16 x2
    const int di0 = blockIdx.x * 128;
    const int t0  = blockIdx.y * 64;
    const int b   = blockIdx.z;
    const int dp = threadIdx.x & 63;       // di-pair 0..63
    const int r4 = threadIdx.x >> 6;       // 0..3
    const int di = di0 + 2 * dp;
    const float b0 = cb[di], b1 = cb[di + 1];
    const float w00 = cw[di * 4 + 0], w01 = cw[di * 4 + 1],
                w02 = cw[di * 4 + 2], w03 = cw[di * 4 + 3];
    const float w10 = cw[(di + 1) * 4 + 0], w11 = cw[(di + 1) * 4 + 1],
                w12 = cw[(di + 1) * 4 + 2], w13 = cw[(di + 1) * 4 + 3];
    const uint_t* xru = (const uint_t*)xr;
    #pragma unroll
    for (int rr = 0; rr < 64; rr += 4) {
        const int t = t0 + rr + r4;
        const int bt = b * Tt + t;
        const size_t u3 = (size_t)bt * DI + (di0 >> 1) + dp;   // uint index
        const uint_t v3 = xru[u3];
        const uint_t v2 = (t >= 1) ? xru[u3 - DI] : 0u;
        const uint_t v1 = (t >= 2) ? xru[u3 - 2 * DI] : 0u;
        const uint_t v0 = (t >= 3) ? xru[u3 - 3 * DI] : 0u;
        const uint_t gg = xru[u3 + (DI >> 1)];
        float a0 = b0, a1 = b1;
        a0 = fmaf(w00, bf16_tof((ushort_t)v0), a0);
        a1 = fmaf(w10, bf16_tof((ushort_t)(v0 >> 16)), a1);
        a0 = fmaf(w01, bf16_tof((ushort_t)v1), a0);
        a1 = fmaf(w11, bf16_tof((ushort_t)(v1 >> 16)), a1);
        a0 = fmaf(w02, bf16_tof((ushort_t)v2), a0);
        a1 = fmaf(w12, bf16_tof((ushort_t)(v2 >> 16)), a1);
        a0 = fmaf(w03, bf16_tof((ushort_t)v3), a0);
        a1 = fmaf(w13, bf16_tof((ushort_t)(v3 >> 16)), a1);
        sp[rr + r4][dp] = (uint_t)bf16_rne(silu_fast(a0)) |
                          ((uint_t)bf16_rne(silu_fast(a1)) << 16);
        sg[rr + r4][dp] = gg;
    }
    __syncthreads();
    // transposed write: 128 di x 32 t-pairs, uint stores
    uint_t* xpo = (uint_t*)xp_bf;
    uint_t* rso = (uint_t*)res_bf;
    #pragma unroll
    for (int it = 0; it < 16; ++it) {
        const int idx = it * 256 + threadIdx.x;
        const int dl = idx >> 5;          // 0..127
        const int tp_ = idx & 31;         // t-pair
        const int sh = (dl & 1) << 4;
        const uint_t p0 = (sp[2 * tp_][dl >> 1] >> sh) & 0xFFFFu;
        const uint_t p1 = (sp[2 * tp_ + 1][dl >> 1] >> sh) & 0xFFFFu;
        const uint_t g0 = (sg[2 * tp_][dl >> 1] >> sh) & 0xFFFFu;
        const uint_t g1 = (sg[2 * tp_ + 1][dl >> 1] >> sh) & 0xFFFFu;
        const size_t o = (((size_t)b * DI + di0 + dl) * Tt + t0 + 2 * tp_) >> 1;
        xpo[o] = p0 | (p1 << 16);
        rso[o] = g0 | (g1 << 16);
    }
}

// ============= fused single-pass selective scan (256 thr, 8 di/block) =========
// y written as PLAIN bf16 (single RNE).
__global__ __launch_bounds__(256) void scan_fused(
    const float* __restrict__ deltaT, const float* __restrict__ xdbl,
    const ushort_t* __restrict__ xp_bf, const ushort_t* __restrict__ res_bf,
    const float* __restrict__ A_log, const float* __restrict__ Dvec,
    ushort_t* __restrict__ y_bf)
{
    __shared__ uint_t   sBC[2][DS][68];   // [buf][s][t]: {C bf16 hi | B bf16 lo}
    __shared__ float    sD [2][8][68];    // fp32 d (exponent path)
    __shared__ float    sDU[2][8][68];    // fp32 d*u
    __shared__ ushort_t sU [2][8][68];    // bf16 u (D-skip)
    __shared__ ushort_t sR [2][8][68];    // bf16 res (gate)
    __shared__ float ylds[CL][9];
    const int tid = threadIdx.x;
    const int grp = tid >> 5;            // 0..7 : di within block
    const int l5 = tid & 31;
    const int s = ((l5 & 1) << 4) | (l5 >> 1);   // lane remap: s^16 <-> l^1 (quad DPP)
    const int b = blockIdx.x >> 7;
    const int di0 = (blockIdx.x & 127) << 3;
    const int sd_r = tid >> 5;           // 0..7
    const int sd_t = (tid & 31) << 1;    // 0..62
    const int bc_t = tid >> 2;           // 0..63
    const int bc_s = (tid & 3) << 3;     // 0,8,16,24

    float2 rd2;
    uint_t ru, rr_;
    float4 rB[2], rC[2];
    auto stage_regs = [&](int c) {
        const size_t rb = ((size_t)(b * DI + di0 + sd_r)) * Tt + c * CL + sd_t;
        rd2 = *(const float2*)(deltaT + rb);
        ru  = *(const uint_t*)(xp_bf + rb);
        rr_ = *(const uint_t*)(res_bf + rb);
        const float* src = xdbl + ((size_t)b * Tt + c * CL + bc_t) * 96;
        rB[0] = *(const float4*)(src + 32 + bc_s);
        rB[1] = *(const float4*)(src + 32 + bc_s + 4);
        rC[0] = *(const float4*)(src + 64 + bc_s);
        rC[1] = *(const float4*)(src + 64 + bc_s + 4);
    };
    auto write_lds = [&](int bb) {
        *(float2*)&sD[bb][sd_r][sd_t] = rd2;
        const float u0 = bf16_tof((ushort_t)(ru & 0xFFFFu));
        const float u1 = bf16_tof((ushort_t)(ru >> 16));
        float2 du2;
        du2.x = rd2.x * u0;
        du2.y = rd2.y * u1;
        *(float2*)&sDU[bb][sd_r][sd_t] = du2;
        *(uint_t*)&sU[bb][sd_r][sd_t] = ru;
        *(uint_t*)&sR[bb][sd_r][sd_t] = rr_;
        const float bv[8] = {rB[0].x, rB[0].y, rB[0].z, rB[0].w,
                             rB[1].x, rB[1].y, rB[1].z, rB[1].w};
        const float cv[8] = {rC[0].x, rC[0].y, rC[0].z, rC[0].w,
                             rC[1].x, rC[1].y, rC[1].z, rC[1].w};
        #pragma unroll
        for (int j = 0; j < 8; ++j)
            sBC[bb][bc_s + j][bc_t] =
                ((uint_t)bf16_rne(cv[j]) << 16) | (uint_t)bf16_rne(bv[j]);
    };

    const bool s4b = (l5 & 1) != 0;
    const bool s0b = (l5 & 2) != 0;
    const bool s1b = (l5 & 4) != 0;
    const bool s2b = (l5 & 8) != 0;
    const bool s3b = (l5 & 16) != 0;
    const int di = di0 + grp;
    const float Ads2 = -expf(A_log[di * DS + s]) * 1.44269504f;
    const float Dv = Dvec[di];
    float h = 0.f;

    stage_regs(0);
    write_lds(0);
    #pragma unroll 1
    for (int c = 0; c < NCH; ++c) {
        const int bb = c & 1;
        __syncthreads();
        if (c < NCH - 1) stage_regs(c + 1);
        #pragma unroll 1
        for (int t0 = 0; t0 < CL; t0 += 32) {
            float buf[16] = {};
            uint4 bc_c = *(const uint4*)&sBC[bb][s][t0];
            float4 dv_c = *(const float4*)&sD[bb][grp][t0];
            float4 du_c = *(const float4*)&sDU[bb][grp][t0];
            #pragma unroll
            for (int tq = 0; tq < 8; ++tq) {
                uint4 bc_n;
                float4 dv_n, du_n;
                if (tq < 7) {
                    const int tb = t0 + tq * 4 + 4;
                    bc_n = *(const uint4*)&sBC[bb][s][tb];
                    dv_n = *(const float4*)&sD[bb][grp][tb];
                    du_n = *(const float4*)&sDU[bb][grp][tb];
                }
                const uint_t bcv[4] = {bc_c.x, bc_c.y, bc_c.z, bc_c.w};
                const float dv[4] = {dv_c.x, dv_c.y, dv_c.z, dv_c.w};
                const float duv[4] = {du_c.x, du_c.y, du_c.z, du_c.w};
                #pragma unroll
                for (int q = 0; q < 4; ++q) {
                    const int tl = tq * 4 + q;
                    const float Bq = __uint_as_float(bcv[q] << 16);
                    const float Cq = __uint_as_float(bcv[q] & 0xFFFF0000u);
                    h = fmaf(__builtin_amdgcn_exp2f(dv[q] * Ads2), h, duv[q] * Bq);
                    const float ps = h * Cq;
                    const float pr = ps + qperm<0xB1>(ps);
                    const bool keep = ((tl & 16) != 0) == s4b;
                    buf[tl & 15] = keep ? pr : buf[tl & 15];
                }
                if (tq < 7) { bc_c = bc_n; dv_c = dv_n; du_c = du_n; }
            }
            #pragma unroll
            for (int i = 0; i < 16; ++i) buf[i] += qperm<0x4E>(buf[i]);
            float r8[8];
            #pragma unroll
            for (int i = 0; i < 8; ++i) r8[i] = s0b ? buf[2 * i + 1] : buf[2 * i];
            #pragma unroll
            for (int i = 0; i < 8; ++i) r8[i] += swz<0x101F>(r8[i]);
            float w4[4];
            #pragma unroll
            for (int i = 0; i < 4; ++i) w4[i] = s1b ? r8[2 * i + 1] : r8[2 * i];
            #pragma unroll
            for (int i = 0; i < 4; ++i) w4[i] += swz<0x201F>(w4[i]);
            float v2[2];
            v2[0] = s2b ? w4[1] : w4[0];
            v2[1] = s2b ? w4[3] : w4[2];
            v2[0] += swz<0x401F>(v2[0]);
            v2[1] += swz<0x401F>(v2[1]);
            const float yv = s3b ? v2[1] : v2[0];
            const float uself = bf16_tof(sU[bb][grp][t0 + s]);
            const float rself = bf16_tof(sR[bb][grp][t0 + s]);
            ylds[t0 + s][grp] = fmaf(uself, Dv, yv) * silu_fast(rself);
        }
        __syncthreads();
        {
            const int row = tid >> 2;
            const int q2 = (tid & 3) << 1;
            const uint_t o = (uint_t)bf16_rne(ylds[row][q2]) |
                             ((uint_t)bf16_rne(ylds[row][q2 + 1]) << 16);
            *(uint_t*)(y_bf + ((size_t)b * Tt + c * CL + row) * DI + di0 + q2) = o;
        }
        if (c < NCH - 1) write_lds(bb ^ 1);
    }
}

// ---------------- classifier ---------------------------------------------------
__global__ __launch_bounds__(256) void cls_kernel(
    const float* __restrict__ pooled, const float* __restrict__ w_cls,
    const float* __restrict__ b_cls, float* __restrict__ out)
{
    const int idx = blockIdx.x * 256 + threadIdx.x;
    if (idx >= Bb * NC) return;
    const int b = idx / NC, c = idx % NC;
    float acc = b_cls[c];
    for (int t = 0; t < DM; ++t)
        acc = fmaf(pooled[b * DM + t], w_cls[t * NC + c], acc);
    out[idx] = acc;
}

extern "C" void kernel_launch(void* const* d_in, const int* in_sizes, int n_in,
                              void* d_out, int out_size, void* d_ws, size_t ws_size,
                              hipStream_t stream) {
    const float* x      = (const float*)d_in[0];
    const float* w_proj = (const float*)d_in[1];
    const float* b_proj = (const float*)d_in[2];
    const float* rms_w  = (const float*)d_in[3];
    const float* w_in   = (const float*)d_in[4];
    const float* conv_w = (const float*)d_in[5];
    const float* conv_b = (const float*)d_in[6];
    const float* w_xprj = (const float*)d_in[7];
    const float* w_dt   = (const float*)d_in[8];
    const float* b_dt   = (const float*)d_in[9];
    const float* A_log  = (const float*)d_in[10];
    const float* Dvec   = (const float*)d_in[11];
    const float* w_out  = (const float*)d_in[12];
    const float* w_cls  = (const float*)d_in[13];
    const float* b_cls  = (const float*)d_in[14];
    float* out = (float*)d_out;

    float* ws = (float*)d_ws;
    float* h0     = ws;
    float* xn     = h0 + (size_t)BT * DM;          // holds xn_pk (uint)
    float* xr     = xn + (size_t)BT * DM;          // region: xr_bf16 -> deltaT, y_bf
    float* xpT    = xr + (size_t)BT * 2 * DI;      // holds xp_bf (ushort)
    float* resT   = xpT + (size_t)Bb * DI * Tt;    // holds res_bf (ushort)
    float* xdbl   = resT + (size_t)Bb * DI * Tt;
    float* pooled = xdbl + (size_t)BT * 96;
    float* wsplit = pooled + 4096;                 // weight-split scratch
    float* deltaT = xr;                            // alias: xr_bf dead after conv_tr
    ushort_t* y_bf = (ushort_t*)(xr + (size_t)Bb * DI * Tt);  // upper half of xr region
    uint_t* xn_pk = (uint_t*)xn;
    ushort_t* xr_bf  = (ushort_t*)xr;
    ushort_t* xp_bf  = (ushort_t*)xpT;
    ushort_t* res_bf = (ushort_t*)resT;

    // weight splits (bf16 hi/lo, transposed to [n][k]) + packed x:
    ushort_t* w_in_hi  = (ushort_t*)wsplit;
    ushort_t* w_in_lo  = w_in_hi + (size_t)(2 * DI) * DM;
    ushort_t* w_out_hi = w_in_lo + (size_t)(2 * DI) * DM;
    ushort_t* w_out_lo = w_out_hi + (size_t)DM * DI;
    ushort_t* w_xp_hi  = w_out_lo + (size_t)DM * DI;
    ushort_t* w_xp_lo  = w_xp_hi + (size_t)96 * DI;
    ushort_t* w_pj_hi  = w_xp_lo + (size_t)96 * DI;
    ushort_t* w_pj_lo  = w_pj_hi + (size_t)DM * NM;
    ushort_t* w_dt_hi  = w_pj_lo + (size_t)DM * NM;
    ushort_t* w_dt_lo  = w_dt_hi + (size_t)DI * DR;
    uint_t*   x_pk     = (uint_t*)(w_dt_lo + (size_t)DI * DR);

    // 0) ONE prep launch: all splits + x pack + zero of xdbl+pooled
    prep_kernel<<<3776, 256, 0, stream>>>(
        x, w_in, w_out, w_xprj, w_proj, w_dt, x_pk,
        w_in_hi, w_in_lo, w_out_hi, w_out_lo, w_xp_hi, w_xp_lo,
        w_pj_hi, w_pj_lo, w_dt_hi, w_dt_lo,
        (float4*)xdbl, (BT * 96 + 4096) / 4);
    // 1) h0 = x @ w_proj + b_proj   (3-pass MFMA)
    gemm_mfma_h0<<<dim3(DM / 128, BT / 128), 512, 0, stream>>>(
        x_pk, w_pj_hi, w_pj_lo, b_proj, h0);
    // 2) xn_pk = pack(rmsnorm(h0) * rms_w); pooled += rowsum(h0)/DM
    rms_kernel<<<BT, 256, 0, stream>>>(h0, rms_w, xn_pk, pooled);
    // 3) xr_bf = bf16(xn @ w_in)    (single-pass bf16 MFMA, 8-wave blocks)
    gemm_mfma_big<<<dim3(2 * DI / 128, BT / 128), 512, 0, stream>>>(
        xn_pk, DM, w_in_hi, xr_bf, 2 * DI, DM);
    // 4) xp_bf = bf16(silu(dwconv))^T ; res_bf = gate^T  (vectorized)
    conv_tr_kernel<<<dim3(DI / 128, Tt / 64, Bb), 256, 0, stream>>>(
        xr_bf, conv_w, conv_b, xp_bf, res_bf);
    // 5) xdbl += xp @ w_xproj   (single-pass bf16 MFMA, split-K=8, atomics)
    gemm_mfma_x<<<dim3(1, BT / 64, 8), 256, 0, stream>>>(
        xp_bf, w_xp_hi, xdbl, DI, DI / 8);
    // 6) deltaT = softplus(xdbl[:, :32] @ w_dt + b_dt)^T   (3-pass, one K step)
    gemm_mfma_dt<<<dim3(DI / 64, BT / 64), 256, 0, stream>>>(
        xdbl, w_dt_hi, w_dt_lo, b_dt, deltaT);
    // 7) fused single-pass selective scan (h in registers across chunks)
    scan_fused<<<Bb * (DI / 8), 256, 0, stream>>>(
        deltaT, xdbl, xp_bf, res_bf, A_log, Dvec, y_bf);
    // 8) pooled += rowsum(y @ w_out)/DM   (single-pass MFMA + split-K=4)
    gemm_mfma_pool<<<dim3(DM / 64, BT / 64, 4), 256, 0, stream>>>(
        y_bf, DI, w_out_hi, pooled, 1.0f / DM, DM, DI, DI / 4);
    // 9) out = pooled @ w_cls + b_cls
    cls_kernel<<<(Bb * NC + 255) / 256, 256, 0, stream>>>(pooled, w_cls, b_cls, out);
}